// Round 11
// baseline (6078.351 us; speedup 1.0000x reference)
//
#include <hip/hip_runtime.h>
#include <math.h>

#define D 64
#define EPS 1e-12f
#define LN_EPS 1e-5f
#define NT 64    // nodes per block in node_linears

// bf16 round-to-nearest-even packing helpers
__device__ __forceinline__ unsigned int f2bf_bits(float x) {
    unsigned int u = __float_as_uint(x);
    return (u + 0x7fffu + ((u >> 16) & 1u)) >> 16;
}
__device__ __forceinline__ float bf_lo(unsigned int p) {  // low 16 bits -> float
    return __uint_as_float(p << 16);
}
__device__ __forceinline__ float bf_hi(unsigned int p) {  // high 16 bits -> float
    return __uint_as_float(p & 0xffff0000u);
}

// ---------------------------------------------------------------------------
// Kernel A: per-node linears, tile-parallel (verified R8-R10, verbatim).
//   P1[n*64+d]  = {B1h, sigmaQ} f32x2   (gathered by src)
//   P2[n*64+d]  = {B2h, sigmaK} f32x2   (loaded once per node, dst side)
//   P3u[n*64+d] = packed bf16 {vh, C2p} (gathered by src; vh also epilogue)
//   C1p -> p_out region (read back in epilogue)
// ---------------------------------------------------------------------------
__global__ void __launch_bounds__(256, 2)
node_linears(const float* __restrict__ h, const float* __restrict__ p,
             const float* __restrict__ WK, const float* __restrict__ bK,
             const float* __restrict__ WV, const float* __restrict__ bV,
             const float* __restrict__ WB1, const float* __restrict__ bB1,
             const float* __restrict__ WB2, const float* __restrict__ bB2,
             const float* __restrict__ WC1, const float* __restrict__ bC1,
             const float* __restrict__ WC2, const float* __restrict__ bC2,
             float2* __restrict__ P1, float2* __restrict__ P2,
             unsigned int* __restrict__ P3u, float* __restrict__ C1pOut,
             int N)
{
    __shared__ float xs[NT * 128];    // [n][k], k<64 = h, k>=64 = p
    __shared__ float wsm[64 * 128];   // phase weight buffer, f4-swizzled

    const int t = threadIdx.x;
    const int lane = t & 63;
    const int wid = t >> 6;
    const int n0 = blockIdx.x * NT;

    float4* xs4 = (float4*)xs;
    float4* wsm4 = (float4*)wsm;

    {
        const float4* h4 = (const float4*)h;
        const float4* p4 = (const float4*)p;
        for (int i = t; i < NT * 32; i += 256) {
            int n = i >> 5, kq = i & 31;
            int ng = n0 + n;
            float4 v = make_float4(0.f, 0.f, 0.f, 0.f);
            if (ng < N) v = (kq < 16) ? h4[(size_t)ng * 16 + kq]
                                      : p4[(size_t)ng * 16 + (kq - 16)];
            xs4[n * 32 + kq] = v;
        }
    }
    __syncthreads();

#define STAGE_W128(W)                                                    \
    {                                                                    \
        const float4* w4 = (const float4*)(W);                           \
        for (int i = t; i < 64 * 32; i += 256) {                         \
            int d = i >> 5, j = i & 31;                                  \
            wsm4[d * 32 + (j ^ (d & 31))] = w4[i];                       \
        }                                                                \
    }                                                                    \
    __syncthreads();

#define LOAD_ROW128(wreg)                                                \
    _Pragma("unroll")                                                    \
    for (int j = 0; j < 32; ++j) wreg[j] = wsm4[lane * 32 + (j ^ (lane & 31))];

    // ---- WK phase: sigmaQ -> P1.y, sigmaK -> P2.y ----
    {
        STAGE_W128(WK);
        float4 w[32];
        LOAD_ROW128(w);
        float bk = bK[lane];
#pragma unroll 1
        for (int i = 0; i < 16; ++i) {
            int n = wid * 16 + i;
            const float4* xv = (const float4*)&xs[n * 128];
            float a0 = 0.f, a1 = 0.f, a2 = 0.f, a3 = 0.f;
#pragma unroll
            for (int j = 0; j < 32; j += 4) {
                float4 x0 = xv[j + 0], x1 = xv[j + 1], x2 = xv[j + 2], x3 = xv[j + 3];
                a0 += w[j+0].x*x0.x + w[j+0].y*x0.y + w[j+0].z*x0.z + w[j+0].w*x0.w;
                a1 += w[j+1].x*x1.x + w[j+1].y*x1.y + w[j+1].z*x1.z + w[j+1].w*x1.w;
                a2 += w[j+2].x*x2.x + w[j+2].y*x2.y + w[j+2].z*x2.z + w[j+2].w*x2.w;
                a3 += w[j+3].x*x3.x + w[j+3].y*x3.y + w[j+3].z*x3.z + w[j+3].w*x3.w;
            }
            float aq = bk + (a0 + a1) + (a2 + a3);
            int ng = n0 + n;
            if (ng < N) {
                size_t o = (size_t)ng * 64 + lane;
                P1[o].y = expf(tanhf(aq));
                P2[o].y = expf(1.f / (1.f + expf(-aq)));
            }
        }
        __syncthreads();
    }

#define STAGE_W64x2(WA, WB)                                              \
    {                                                                    \
        for (int i = t; i < 2048; i += 256) {                            \
            int m = i >> 10;                                             \
            int r = i & 1023;                                            \
            int d = r >> 4, j = r & 15;                                  \
            const float4* w4 = m ? (const float4*)(WB) : (const float4*)(WA); \
            wsm4[m * 1024 + d * 16 + (j ^ (d & 15))] = w4[r];            \
        }                                                                \
    }                                                                    \
    __syncthreads();

    // ---- WB1/WB2 phase (input h): B1h -> P1.x, B2h -> P2.x ----
    {
        STAGE_W64x2(WB1, WB2);
        float4 w1[16], w2[16];
#pragma unroll
        for (int j = 0; j < 16; ++j) {
            w1[j] = wsm4[lane * 16 + (j ^ (lane & 15))];
            w2[j] = wsm4[1024 + lane * 16 + (j ^ (lane & 15))];
        }
        float b1 = bB1[lane], b2 = bB2[lane];
#pragma unroll 1
        for (int i = 0; i < 16; ++i) {
            int n = wid * 16 + i;
            const float4* xv = (const float4*)&xs[n * 128];
            float a0 = 0.f, a1 = 0.f, c0 = 0.f, c1 = 0.f;
#pragma unroll
            for (int j = 0; j < 16; j += 2) {
                float4 x0 = xv[j], x1 = xv[j + 1];
                a0 += w1[j].x*x0.x + w1[j].y*x0.y + w1[j].z*x0.z + w1[j].w*x0.w;
                a1 += w1[j+1].x*x1.x + w1[j+1].y*x1.y + w1[j+1].z*x1.z + w1[j+1].w*x1.w;
                c0 += w2[j].x*x0.x + w2[j].y*x0.y + w2[j].z*x0.z + w2[j].w*x0.w;
                c1 += w2[j+1].x*x1.x + w2[j+1].y*x1.y + w2[j+1].z*x1.z + w2[j+1].w*x1.w;
            }
            int ng = n0 + n;
            if (ng < N) {
                size_t o = (size_t)ng * 64 + lane;
                P1[o].x = b1 + a0 + a1;
                P2[o].x = b2 + c0 + c1;
            }
        }
        __syncthreads();
    }

    // ---- WV phase: vh -> xs h-slot (dead after WB; lockstep-safe) ----
    {
        STAGE_W128(WV);
        float4 w[32];
        LOAD_ROW128(w);
        float bv = bV[lane];
#pragma unroll 1
        for (int i = 0; i < 16; ++i) {
            int n = wid * 16 + i;
            const float4* xv = (const float4*)&xs[n * 128];
            float a0 = 0.f, a1 = 0.f, a2 = 0.f, a3 = 0.f;
#pragma unroll
            for (int j = 0; j < 32; j += 4) {
                float4 x0 = xv[j + 0], x1 = xv[j + 1], x2 = xv[j + 2], x3 = xv[j + 3];
                a0 += w[j+0].x*x0.x + w[j+0].y*x0.y + w[j+0].z*x0.z + w[j+0].w*x0.w;
                a1 += w[j+1].x*x1.x + w[j+1].y*x1.y + w[j+1].z*x1.z + w[j+1].w*x1.w;
                a2 += w[j+2].x*x2.x + w[j+2].y*x2.y + w[j+2].z*x2.z + w[j+2].w*x2.w;
                a3 += w[j+3].x*x3.x + w[j+3].y*x3.y + w[j+3].z*x3.z + w[j+3].w*x3.w;
            }
            float av = bv + (a0 + a1) + (a2 + a3);
            xs[n * 128 + lane] = av;
        }
        __syncthreads();
    }

    // ---- WC1/WC2 phase (input p): C1p -> p_out region, pack P3u ----
    {
        STAGE_W64x2(WC1, WC2);
        float4 w1[16], w2[16];
#pragma unroll
        for (int j = 0; j < 16; ++j) {
            w1[j] = wsm4[lane * 16 + (j ^ (lane & 15))];
            w2[j] = wsm4[1024 + lane * 16 + (j ^ (lane & 15))];
        }
        float b1 = bC1[lane], b2 = bC2[lane];
#pragma unroll 1
        for (int i = 0; i < 16; ++i) {
            int n = wid * 16 + i;
            const float4* xv = (const float4*)&xs[n * 128 + 64];
            float a0 = 0.f, a1 = 0.f, c0 = 0.f, c1 = 0.f;
#pragma unroll
            for (int j = 0; j < 16; j += 2) {
                float4 x0 = xv[j], x1 = xv[j + 1];
                a0 += w1[j].x*x0.x + w1[j].y*x0.y + w1[j].z*x0.z + w1[j].w*x0.w;
                a1 += w1[j+1].x*x1.x + w1[j+1].y*x1.y + w1[j+1].z*x1.z + w1[j+1].w*x1.w;
                c0 += w2[j].x*x0.x + w2[j].y*x0.y + w2[j].z*x0.z + w2[j].w*x0.w;
                c1 += w2[j+1].x*x1.x + w2[j+1].y*x1.y + w2[j+1].z*x1.z + w2[j+1].w*x1.w;
            }
            int ng = n0 + n;
            if (ng < N) {
                size_t o = (size_t)ng * 64 + lane;
                C1pOut[o] = b1 + a0 + a1;
                float c2 = b2 + c0 + c1;
                float vh = xs[n * 128 + lane];
                P3u[o] = f2bf_bits(vh) | (f2bf_bits(c2) << 16);
            }
        }
    }
}

// ---------------------------------------------------------------------------
// dst-bucketing pipeline (int atomics only; verified R4-R10).
// ---------------------------------------------------------------------------
__global__ void hist_kernel(const int* __restrict__ dst, int* __restrict__ cnt, int E) {
    int i = blockIdx.x * blockDim.x + threadIdx.x;
    if (i < E) atomicAdd(&cnt[dst[i]], 1);
}

__global__ void chunksum_kernel(const int* __restrict__ cnt, int* __restrict__ csum, int N) {
    __shared__ int sc[256];
    int t = threadIdx.x;
    int i = blockIdx.x * 256 + t;
    sc[t] = (i < N) ? cnt[i] : 0;
    __syncthreads();
    for (int off = 128; off > 0; off >>= 1) {
        if (t < off) sc[t] += sc[t + off];
        __syncthreads();
    }
    if (t == 0) csum[blockIdx.x] = sc[0];
}

__global__ void scanchunk_kernel(int* __restrict__ csum, int nch) {
    __shared__ int sc[256];
    int t = threadIdx.x;
    int v = (t < nch) ? csum[t] : 0;
    sc[t] = v;
    __syncthreads();
    for (int off = 1; off < 256; off <<= 1) {
        int y = (t >= off) ? sc[t - off] : 0;
        __syncthreads();
        sc[t] += y;
        __syncthreads();
    }
    if (t < nch) csum[t] = sc[t] - v;   // exclusive prefix
}

__global__ void offsets_kernel(const int* __restrict__ cnt, const int* __restrict__ csum,
                               int* __restrict__ offs, int N) {
    __shared__ int sc[256];
    int t = threadIdx.x;
    int i = blockIdx.x * 256 + t;
    int v = (i < N) ? cnt[i] : 0;
    sc[t] = v;
    __syncthreads();
    for (int off = 1; off < 256; off <<= 1) {
        int y = (t >= off) ? sc[t - off] : 0;
        __syncthreads();
        sc[t] += y;
        __syncthreads();
    }
    if (i < N) offs[i] = csum[blockIdx.x] + sc[t] - v;  // global exclusive prefix
}

__global__ void scatter_kernel(const int* __restrict__ dst, int* __restrict__ offs,
                               int* __restrict__ bucket, int E) {
    int i = blockIdx.x * blockDim.x + threadIdx.x;
    if (i < E) {
        int pos = atomicAdd(&offs[dst[i]], 1);
        bucket[pos] = i;
    }
}

// ---------------------------------------------------------------------------
// Kernel B: he_b3 v2 -- EDGE-PER-LANE tiles. Block = 4 waves = 1 tile of 64
// edges. Stage e-rows to LDS coalesced; each lane holds ITS edge's row in 16
// float4 VGPRs (statically indexed); wave w computes output dims 16w..16w+15.
// W-row addresses are wave-UNIFORM -> scalar s_load + v_fmac with SGPR
// operand (no VGPRs for W, no per-lane W gathers -- the R10 pathology).
// Results transposed through LDS for coalesced 16B stores.
// ---------------------------------------------------------------------------
__global__ void __launch_bounds__(256, 4)
he_b3(const float* __restrict__ e,
      const float* __restrict__ WB3, const float* __restrict__ bB3,
      float* __restrict__ he_out, int E)
{
    __shared__ float4 xs[64 * 17];    // 64 rows, padded to 17 f4 (272B)

    const int t = threadIdx.x;
    const int lane = t & 63;
    const int wid = t >> 6;           // wave's output-dim block: 16*wid..+15

    const int ntile = (E + 63) >> 6;

    for (int tile = blockIdx.x; tile < ntile; tile += gridDim.x) {
        const int e0 = tile << 6;
        const int nrow = min(64, E - e0);

        __syncthreads();   // xs reuse: prior iteration's readers done
        {
            const float4* e4 = (const float4*)(e + (size_t)e0 * D);
#pragma unroll
            for (int q = 0; q < 4; ++q) {
                int idx = t + q * 256;          // 0..1023
                int r = idx >> 4, j = idx & 15;
                float4 v = make_float4(0.f, 0.f, 0.f, 0.f);
                if (r < nrow) v = e4[(size_t)r * 16 + j];
                xs[r * 17 + j] = v;
            }
        }
        __syncthreads();

        // each lane: its edge-row into registers (statically indexed)
        float4 x4[16];
#pragma unroll
        for (int j = 0; j < 16; ++j) x4[j] = xs[lane * 17 + j];
        __syncthreads();   // all waves read xs before we overwrite with out

        // wave computes its 16 output dims; W loads are wave-uniform
#pragma unroll
        for (int dq = 0; dq < 4; ++dq) {
            float4 o4;
            float* op = (float*)&o4;
#pragma unroll
            for (int di = 0; di < 4; ++di) {
                const int d = (wid << 4) + (dq << 2) + di;
                const float4* w4 = (const float4*)(WB3 + (size_t)d * D);
                float acc = bB3[d];
#pragma unroll
                for (int j = 0; j < 16; ++j) {
                    float4 wv = w4[j];
                    acc += wv.x*x4[j].x + wv.y*x4[j].y + wv.z*x4[j].z + wv.w*x4[j].w;
                }
                op[di] = acc;
            }
            xs[lane * 17 + (wid << 2) + dq] = o4;   // out[row=lane][f4 wid*4+dq]
        }
        __syncthreads();

        // coalesced store of 64 rows
        {
            float4* o4g = (float4*)(he_out + (size_t)e0 * D);
#pragma unroll
            for (int q = 0; q < 4; ++q) {
                int idx = t + q * 256;
                int r = idx >> 4, j = idx & 15;
                if (r < nrow) o4g[(size_t)r * 16 + j] = xs[r * 17 + j];
            }
        }
    }
}

// ---------------------------------------------------------------------------
// Kernel C: MERGED edge finish + gather + finalize (verified R10, verbatim).
// ---------------------------------------------------------------------------
__global__ void __launch_bounds__(256, 3)
edge_gather_finalize(const int* __restrict__ bucket, const int* __restrict__ offs_end,
                     const int* __restrict__ cnt, const int* __restrict__ src,
                     const float2* __restrict__ P1, const float2* __restrict__ P2,
                     const unsigned int* __restrict__ P3u,
                     const float* __restrict__ ln_g, const float* __restrict__ ln_b,
                     float* __restrict__ he_eout, float* __restrict__ h_out,
                     float* __restrict__ p_out, int N)
{
    const int lane = threadIdx.x & 63;
    const int wid = threadIdx.x >> 6;
    const int wpb = blockDim.x >> 6;
    const float lg = ln_g[lane], lb = ln_b[lane];

    for (int n = blockIdx.x * wpb + wid; n < N; n += gridDim.x * wpb) {
        const int end = offs_end[n];
        const int deg = cnt[n];
        const int start = end - deg;
        const size_t o = (size_t)n * D + lane;

        const float2 p2n = P2[o];   // {B2h, sigmaK}, hoisted per node

        float asig = 0.f, av = 0.f, ap = 0.f;

        int k = start;
        for (; k + 3 < end; k += 4) {
            int eid[4], s[4];
#pragma unroll
            for (int i = 0; i < 4; ++i)
                eid[i] = __builtin_amdgcn_readfirstlane(bucket[k + i]);
#pragma unroll
            for (int i = 0; i < 4; ++i)
                s[i] = __builtin_amdgcn_readfirstlane(src[eid[i]]);

            float2 p1[4]; unsigned int p3[4]; float hb[4];
#pragma unroll
            for (int i = 0; i < 4; ++i) {
                p1[i] = P1[(size_t)s[i] * D + lane];        // {B1h, sigmaQ}
                p3[i] = P3u[(size_t)s[i] * D + lane];       // bf16 {vh, C2p}
                hb[i] = he_eout[(size_t)eid[i] * D + lane]; // B3e partial
            }

            float sg[4], pr[4];
#pragma unroll
            for (int i = 0; i < 4; ++i) {
                float he = hb[i] + p1[i].x + p2n.x;
                he_eout[(size_t)eid[i] * D + lane] = fmaxf(he, 0.f);
                sg[i] = 1.f / (1.f + expf(-he));
                pr[i] = p1[i].y * p2n.y;
            }
#pragma unroll
            for (int off = 32; off > 0; off >>= 1) {
#pragma unroll
                for (int i = 0; i < 4; ++i) pr[i] += __shfl_xor(pr[i], off);
            }
#pragma unroll
            for (int i = 0; i < 4; ++i) {
                asig += sg[i];
                av   += sg[i] * pr[i] * bf_lo(p3[i]);
                ap   += sg[i] * bf_hi(p3[i]);
            }
        }
        for (; k < end; ++k) {
            int e0 = __builtin_amdgcn_readfirstlane(bucket[k]);
            int s0 = __builtin_amdgcn_readfirstlane(src[e0]);
            size_t eo0 = (size_t)e0 * D + lane;
            float2 p10 = P1[(size_t)s0 * D + lane];
            unsigned int p30 = P3u[(size_t)s0 * D + lane];
            float he0 = he_eout[eo0] + p10.x + p2n.x;
            he_eout[eo0] = fmaxf(he0, 0.f);
            float sg0 = 1.f / (1.f + expf(-he0));
            float pr0 = p10.y * p2n.y;
#pragma unroll
            for (int off = 32; off > 0; off >>= 1) pr0 += __shfl_xor(pr0, off);
            asig += sg0;
            av   += sg0 * pr0 * bf_lo(p30);
            ap   += sg0 * bf_hi(p30);
        }

        // fused epilogue (verified R9/R10)
        float denom = asig + EPS;
        float vh = bf_lo(P3u[o]);
        float hv = vh + av / denom;
        hv = fmaxf(hv, 0.f);
        float su = hv;
#pragma unroll
        for (int off = 32; off > 0; off >>= 1) su += __shfl_xor(su, off);
        float mu = su * (1.f / 64.f);
        float dv = hv - mu;
        float s2 = dv * dv;
#pragma unroll
        for (int off = 32; off > 0; off >>= 1) s2 += __shfl_xor(s2, off);
        float var = s2 * (1.f / 64.f);
        h_out[o] = dv * rsqrtf(var + LN_EPS) * lg + lb;

        float pv = p_out[o] + ap / denom;   // p_out holds C1p
        p_out[o] = tanhf(pv);
    }
}

extern "C" void kernel_launch(void* const* d_in, const int* in_sizes, int n_in,
                              void* d_out, int out_size, void* d_ws, size_t ws_size,
                              hipStream_t stream) {
    const float* h    = (const float*)d_in[0];
    const float* e    = (const float*)d_in[1];
    const float* p    = (const float*)d_in[2];
    const float* WK   = (const float*)d_in[3];
    const float* bK   = (const float*)d_in[4];
    const float* WV   = (const float*)d_in[5];
    const float* bV   = (const float*)d_in[6];
    const float* WB1  = (const float*)d_in[7];
    const float* bB1  = (const float*)d_in[8];
    const float* WB2  = (const float*)d_in[9];
    const float* bB2  = (const float*)d_in[10];
    const float* WB3  = (const float*)d_in[11];
    const float* bB3  = (const float*)d_in[12];
    const float* WC1  = (const float*)d_in[13];
    const float* bC1  = (const float*)d_in[14];
    const float* WC2  = (const float*)d_in[15];
    const float* bC2  = (const float*)d_in[16];
    const float* ln_g = (const float*)d_in[17];
    const float* ln_b = (const float*)d_in[18];
    const int*   src  = (const int*)d_in[19];
    const int*   dst  = (const int*)d_in[20];

    const int N = in_sizes[0] / D;
    const int E = in_sizes[1] / D;
    const size_t ND = (size_t)N * D;

    float* out   = (float*)d_out;
    float* h_out = out;
    float* e_out = out + ND;                  // B3e partial, then relu(he)
    float* p_out = out + ND + (size_t)E * D;  // C1p, then tanh(...)

    // ws: P1 2ND + P2 2ND (f32) + P3u ND (u32)
    //   + cnt N + offs N + bucket E + csum (int)  ~= 68 MB
    float*        ws    = (float*)d_ws;
    float2*       P1    = (float2*)(ws);                // 2*ND floats
    float2*       P2    = (float2*)(ws + 2 * ND);       // 2*ND floats
    unsigned int* P3u   = (unsigned int*)(ws + 4 * ND); // ND u32
    int*          cnt   = (int*)(ws + 5 * ND);          // N ints
    int*          offs  = cnt + N;                      // N ints
    int*          bucket= offs + N;                     // E ints
    int*          csum  = bucket + E;                   // nchunk ints (<=256)

    const int nchunk = (N + 255) / 256;

    hipMemsetAsync(cnt, 0, (size_t)N * sizeof(int), stream);

    node_linears<<<(N + NT - 1) / NT, 256, 0, stream>>>(
        h, p, WK, bK, WV, bV, WB1, bB1, WB2, bB2, WC1, bC1, WC2, bC2,
        P1, P2, P3u, p_out, N);

    hist_kernel<<<(E + 255) / 256, 256, 0, stream>>>(dst, cnt, E);
    chunksum_kernel<<<nchunk, 256, 0, stream>>>(cnt, csum, N);
    scanchunk_kernel<<<1, 256, 0, stream>>>(csum, nchunk);
    offsets_kernel<<<nchunk, 256, 0, stream>>>(cnt, csum, offs, N);
    scatter_kernel<<<(E + 255) / 256, 256, 0, stream>>>(dst, offs, bucket, E);

    he_b3<<<4096, 256, 0, stream>>>(e, WB3, bB3, e_out, E);

    edge_gather_finalize<<<(N + 3) / 4, 256, 0, stream>>>(
        bucket, offs, cnt, src, P1, P2, P3u, ln_g, ln_b,
        e_out, h_out, p_out, N);
}

// Round 12
// 580.712 us; speedup vs baseline: 10.4671x; 10.4671x over previous
//
#include <hip/hip_runtime.h>
#include <math.h>

#define D 64
#define EPS 1e-12f
#define LN_EPS 1e-5f
#define NT 64    // nodes per block in node_linears

// bf16 round-to-nearest-even packing helpers
__device__ __forceinline__ unsigned int f2bf_bits(float x) {
    unsigned int u = __float_as_uint(x);
    return (u + 0x7fffu + ((u >> 16) & 1u)) >> 16;
}
__device__ __forceinline__ float bf_lo(unsigned int p) {  // low 16 bits -> float
    return __uint_as_float(p << 16);
}
__device__ __forceinline__ float bf_hi(unsigned int p) {  // high 16 bits -> float
    return __uint_as_float(p & 0xffff0000u);
}

// ---------------------------------------------------------------------------
// Kernel A: per-node linears, tile-parallel (verified R8-R10, verbatim).
//   P1[n*64+d]  = {B1h, sigmaQ} f32x2   (gathered by src)
//   P2[n*64+d]  = {B2h, sigmaK} f32x2   (loaded once per node, dst side)
//   P3u[n*64+d] = packed bf16 {vh, C2p} (gathered by src; vh also epilogue)
//   C1p -> p_out region (read back in epilogue)
// ---------------------------------------------------------------------------
__global__ void __launch_bounds__(256, 2)
node_linears(const float* __restrict__ h, const float* __restrict__ p,
             const float* __restrict__ WK, const float* __restrict__ bK,
             const float* __restrict__ WV, const float* __restrict__ bV,
             const float* __restrict__ WB1, const float* __restrict__ bB1,
             const float* __restrict__ WB2, const float* __restrict__ bB2,
             const float* __restrict__ WC1, const float* __restrict__ bC1,
             const float* __restrict__ WC2, const float* __restrict__ bC2,
             float2* __restrict__ P1, float2* __restrict__ P2,
             unsigned int* __restrict__ P3u, float* __restrict__ C1pOut,
             int N)
{
    __shared__ float xs[NT * 128];    // [n][k], k<64 = h, k>=64 = p
    __shared__ float wsm[64 * 128];   // phase weight buffer, f4-swizzled

    const int t = threadIdx.x;
    const int lane = t & 63;
    const int wid = t >> 6;
    const int n0 = blockIdx.x * NT;

    float4* xs4 = (float4*)xs;
    float4* wsm4 = (float4*)wsm;

    {
        const float4* h4 = (const float4*)h;
        const float4* p4 = (const float4*)p;
        for (int i = t; i < NT * 32; i += 256) {
            int n = i >> 5, kq = i & 31;
            int ng = n0 + n;
            float4 v = make_float4(0.f, 0.f, 0.f, 0.f);
            if (ng < N) v = (kq < 16) ? h4[(size_t)ng * 16 + kq]
                                      : p4[(size_t)ng * 16 + (kq - 16)];
            xs4[n * 32 + kq] = v;
        }
    }
    __syncthreads();

#define STAGE_W128(W)                                                    \
    {                                                                    \
        const float4* w4 = (const float4*)(W);                           \
        for (int i = t; i < 64 * 32; i += 256) {                         \
            int d = i >> 5, j = i & 31;                                  \
            wsm4[d * 32 + (j ^ (d & 31))] = w4[i];                       \
        }                                                                \
    }                                                                    \
    __syncthreads();

#define LOAD_ROW128(wreg)                                                \
    _Pragma("unroll")                                                    \
    for (int j = 0; j < 32; ++j) wreg[j] = wsm4[lane * 32 + (j ^ (lane & 31))];

    // ---- WK phase: sigmaQ -> P1.y, sigmaK -> P2.y ----
    {
        STAGE_W128(WK);
        float4 w[32];
        LOAD_ROW128(w);
        float bk = bK[lane];
#pragma unroll 1
        for (int i = 0; i < 16; ++i) {
            int n = wid * 16 + i;
            const float4* xv = (const float4*)&xs[n * 128];
            float a0 = 0.f, a1 = 0.f, a2 = 0.f, a3 = 0.f;
#pragma unroll
            for (int j = 0; j < 32; j += 4) {
                float4 x0 = xv[j + 0], x1 = xv[j + 1], x2 = xv[j + 2], x3 = xv[j + 3];
                a0 += w[j+0].x*x0.x + w[j+0].y*x0.y + w[j+0].z*x0.z + w[j+0].w*x0.w;
                a1 += w[j+1].x*x1.x + w[j+1].y*x1.y + w[j+1].z*x1.z + w[j+1].w*x1.w;
                a2 += w[j+2].x*x2.x + w[j+2].y*x2.y + w[j+2].z*x2.z + w[j+2].w*x2.w;
                a3 += w[j+3].x*x3.x + w[j+3].y*x3.y + w[j+3].z*x3.z + w[j+3].w*x3.w;
            }
            float aq = bk + (a0 + a1) + (a2 + a3);
            int ng = n0 + n;
            if (ng < N) {
                size_t o = (size_t)ng * 64 + lane;
                P1[o].y = expf(tanhf(aq));
                P2[o].y = expf(1.f / (1.f + expf(-aq)));
            }
        }
        __syncthreads();
    }

#define STAGE_W64x2(WA, WB)                                              \
    {                                                                    \
        for (int i = t; i < 2048; i += 256) {                            \
            int m = i >> 10;                                             \
            int r = i & 1023;                                            \
            int d = r >> 4, j = r & 15;                                  \
            const float4* w4 = m ? (const float4*)(WB) : (const float4*)(WA); \
            wsm4[m * 1024 + d * 16 + (j ^ (d & 15))] = w4[r];            \
        }                                                                \
    }                                                                    \
    __syncthreads();

    // ---- WB1/WB2 phase (input h): B1h -> P1.x, B2h -> P2.x ----
    {
        STAGE_W64x2(WB1, WB2);
        float4 w1[16], w2[16];
#pragma unroll
        for (int j = 0; j < 16; ++j) {
            w1[j] = wsm4[lane * 16 + (j ^ (lane & 15))];
            w2[j] = wsm4[1024 + lane * 16 + (j ^ (lane & 15))];
        }
        float b1 = bB1[lane], b2 = bB2[lane];
#pragma unroll 1
        for (int i = 0; i < 16; ++i) {
            int n = wid * 16 + i;
            const float4* xv = (const float4*)&xs[n * 128];
            float a0 = 0.f, a1 = 0.f, c0 = 0.f, c1 = 0.f;
#pragma unroll
            for (int j = 0; j < 16; j += 2) {
                float4 x0 = xv[j], x1 = xv[j + 1];
                a0 += w1[j].x*x0.x + w1[j].y*x0.y + w1[j].z*x0.z + w1[j].w*x0.w;
                a1 += w1[j+1].x*x1.x + w1[j+1].y*x1.y + w1[j+1].z*x1.z + w1[j+1].w*x1.w;
                c0 += w2[j].x*x0.x + w2[j].y*x0.y + w2[j].z*x0.z + w2[j].w*x0.w;
                c1 += w2[j+1].x*x1.x + w2[j+1].y*x1.y + w2[j+1].z*x1.z + w2[j+1].w*x1.w;
            }
            int ng = n0 + n;
            if (ng < N) {
                size_t o = (size_t)ng * 64 + lane;
                P1[o].x = b1 + a0 + a1;
                P2[o].x = b2 + c0 + c1;
            }
        }
        __syncthreads();
    }

    // ---- WV phase: vh -> xs h-slot (dead after WB; lockstep-safe) ----
    {
        STAGE_W128(WV);
        float4 w[32];
        LOAD_ROW128(w);
        float bv = bV[lane];
#pragma unroll 1
        for (int i = 0; i < 16; ++i) {
            int n = wid * 16 + i;
            const float4* xv = (const float4*)&xs[n * 128];
            float a0 = 0.f, a1 = 0.f, a2 = 0.f, a3 = 0.f;
#pragma unroll
            for (int j = 0; j < 32; j += 4) {
                float4 x0 = xv[j + 0], x1 = xv[j + 1], x2 = xv[j + 2], x3 = xv[j + 3];
                a0 += w[j+0].x*x0.x + w[j+0].y*x0.y + w[j+0].z*x0.z + w[j+0].w*x0.w;
                a1 += w[j+1].x*x1.x + w[j+1].y*x1.y + w[j+1].z*x1.z + w[j+1].w*x1.w;
                a2 += w[j+2].x*x2.x + w[j+2].y*x2.y + w[j+2].z*x2.z + w[j+2].w*x2.w;
                a3 += w[j+3].x*x3.x + w[j+3].y*x3.y + w[j+3].z*x3.z + w[j+3].w*x3.w;
            }
            float av = bv + (a0 + a1) + (a2 + a3);
            xs[n * 128 + lane] = av;
        }
        __syncthreads();
    }

    // ---- WC1/WC2 phase (input p): C1p -> p_out region, pack P3u ----
    {
        STAGE_W64x2(WC1, WC2);
        float4 w1[16], w2[16];
#pragma unroll
        for (int j = 0; j < 16; ++j) {
            w1[j] = wsm4[lane * 16 + (j ^ (lane & 15))];
            w2[j] = wsm4[1024 + lane * 16 + (j ^ (lane & 15))];
        }
        float b1 = bC1[lane], b2 = bC2[lane];
#pragma unroll 1
        for (int i = 0; i < 16; ++i) {
            int n = wid * 16 + i;
            const float4* xv = (const float4*)&xs[n * 128 + 64];
            float a0 = 0.f, a1 = 0.f, c0 = 0.f, c1 = 0.f;
#pragma unroll
            for (int j = 0; j < 16; j += 2) {
                float4 x0 = xv[j], x1 = xv[j + 1];
                a0 += w1[j].x*x0.x + w1[j].y*x0.y + w1[j].z*x0.z + w1[j].w*x0.w;
                a1 += w1[j+1].x*x1.x + w1[j+1].y*x1.y + w1[j+1].z*x1.z + w1[j+1].w*x1.w;
                c0 += w2[j].x*x0.x + w2[j].y*x0.y + w2[j].z*x0.z + w2[j].w*x0.w;
                c1 += w2[j+1].x*x1.x + w2[j+1].y*x1.y + w2[j+1].z*x1.z + w2[j+1].w*x1.w;
            }
            int ng = n0 + n;
            if (ng < N) {
                size_t o = (size_t)ng * 64 + lane;
                C1pOut[o] = b1 + a0 + a1;
                float c2 = b2 + c0 + c1;
                float vh = xs[n * 128 + lane];
                P3u[o] = f2bf_bits(vh) | (f2bf_bits(c2) << 16);
            }
        }
    }
}

// ---------------------------------------------------------------------------
// dst-bucketing pipeline (int atomics only; verified R4-R10).
// ---------------------------------------------------------------------------
__global__ void hist_kernel(const int* __restrict__ dst, int* __restrict__ cnt, int E) {
    int i = blockIdx.x * blockDim.x + threadIdx.x;
    if (i < E) atomicAdd(&cnt[dst[i]], 1);
}

__global__ void chunksum_kernel(const int* __restrict__ cnt, int* __restrict__ csum, int N) {
    __shared__ int sc[256];
    int t = threadIdx.x;
    int i = blockIdx.x * 256 + t;
    sc[t] = (i < N) ? cnt[i] : 0;
    __syncthreads();
    for (int off = 128; off > 0; off >>= 1) {
        if (t < off) sc[t] += sc[t + off];
        __syncthreads();
    }
    if (t == 0) csum[blockIdx.x] = sc[0];
}

__global__ void scanchunk_kernel(int* __restrict__ csum, int nch) {
    __shared__ int sc[256];
    int t = threadIdx.x;
    int v = (t < nch) ? csum[t] : 0;
    sc[t] = v;
    __syncthreads();
    for (int off = 1; off < 256; off <<= 1) {
        int y = (t >= off) ? sc[t - off] : 0;
        __syncthreads();
        sc[t] += y;
        __syncthreads();
    }
    if (t < nch) csum[t] = sc[t] - v;   // exclusive prefix
}

__global__ void offsets_kernel(const int* __restrict__ cnt, const int* __restrict__ csum,
                               int* __restrict__ offs, int N) {
    __shared__ int sc[256];
    int t = threadIdx.x;
    int i = blockIdx.x * 256 + t;
    int v = (i < N) ? cnt[i] : 0;
    sc[t] = v;
    __syncthreads();
    for (int off = 1; off < 256; off <<= 1) {
        int y = (t >= off) ? sc[t - off] : 0;
        __syncthreads();
        sc[t] += y;
        __syncthreads();
    }
    if (i < N) offs[i] = csum[blockIdx.x] + sc[t] - v;  // global exclusive prefix
}

__global__ void scatter_kernel(const int* __restrict__ dst, int* __restrict__ offs,
                               int* __restrict__ bucket, int E) {
    int i = blockIdx.x * blockDim.x + threadIdx.x;
    if (i < E) {
        int pos = atomicAdd(&offs[dst[i]], 1);
        bucket[pos] = i;
    }
}

// ---------------------------------------------------------------------------
// Kernel B: he_b3 v3 -- EXACT node_linears phase structure (the one shape
// where a 64-VGPR weight row provably stays register-resident at
// __launch_bounds__(256,2)). Block = one tile of 64 edges:
//   stage WB3 f4-swizzled in LDS; lane loads ITS output-row w[16];
//   stage 64 e-rows coalesced in LDS; each wave sweeps 16 edges with
//   broadcast ds_read_b128 + 4-way ILP accumulators; coalesced 256B store
//   of he row per edge. No address-taken locals, no dynamic indexing.
// ---------------------------------------------------------------------------
__global__ void __launch_bounds__(256, 2)
he_b3(const float* __restrict__ e,
      const float* __restrict__ WB3, const float* __restrict__ bB3,
      float* __restrict__ he_out, int E)
{
    __shared__ float xs[64 * 64];     // 64 e-rows
    __shared__ float wsm[64 * 64];    // WB3, f4-swizzled

    const int t = threadIdx.x;
    const int lane = t & 63;
    const int wid = t >> 6;

    float4* xs4 = (float4*)xs;
    float4* wsm4 = (float4*)wsm;

    // stage WB3 swizzled (same pattern as STAGE_W64x2)
    {
        const float4* w4 = (const float4*)WB3;
        for (int i = t; i < 1024; i += 256) {
            int d = i >> 4, j = i & 15;
            wsm4[d * 16 + (j ^ (d & 15))] = w4[i];
        }
    }

    const int e0 = blockIdx.x << 6;
    const int nrow = min(64, E - e0);

    // stage e-rows coalesced
    {
        const float4* e4 = (const float4*)(e + (size_t)e0 * D);
        for (int i = t; i < 1024; i += 256) {
            int r = i >> 4;
            float4 v = make_float4(0.f, 0.f, 0.f, 0.f);
            if (r < nrow) v = e4[i];
            xs4[i] = v;
        }
    }
    __syncthreads();

    // lane's WB3 output-row into registers (proven-resident pattern)
    float4 w[16];
#pragma unroll
    for (int j = 0; j < 16; ++j) w[j] = wsm4[lane * 16 + (j ^ (lane & 15))];
    const float bb = bB3[lane];

    // wave wid sweeps edges wid*16 .. wid*16+15
#pragma unroll 1
    for (int i = 0; i < 16; ++i) {
        int n = wid * 16 + i;
        const float4* xv = (const float4*)&xs[n * 64];
        float a0 = 0.f, a1 = 0.f, a2 = 0.f, a3 = 0.f;
#pragma unroll
        for (int j = 0; j < 16; j += 4) {
            float4 x0 = xv[j + 0], x1 = xv[j + 1], x2 = xv[j + 2], x3 = xv[j + 3];
            a0 += w[j+0].x*x0.x + w[j+0].y*x0.y + w[j+0].z*x0.z + w[j+0].w*x0.w;
            a1 += w[j+1].x*x1.x + w[j+1].y*x1.y + w[j+1].z*x1.z + w[j+1].w*x1.w;
            a2 += w[j+2].x*x2.x + w[j+2].y*x2.y + w[j+2].z*x2.z + w[j+2].w*x2.w;
            a3 += w[j+3].x*x3.x + w[j+3].y*x3.y + w[j+3].z*x3.z + w[j+3].w*x3.w;
        }
        float he = bb + (a0 + a1) + (a2 + a3);
        if (n < nrow) he_out[(size_t)(e0 + n) * D + lane] = he;
    }
}

// ---------------------------------------------------------------------------
// Kernel C: MERGED edge finish + gather + finalize (verified R10, verbatim).
// ---------------------------------------------------------------------------
__global__ void __launch_bounds__(256, 3)
edge_gather_finalize(const int* __restrict__ bucket, const int* __restrict__ offs_end,
                     const int* __restrict__ cnt, const int* __restrict__ src,
                     const float2* __restrict__ P1, const float2* __restrict__ P2,
                     const unsigned int* __restrict__ P3u,
                     const float* __restrict__ ln_g, const float* __restrict__ ln_b,
                     float* __restrict__ he_eout, float* __restrict__ h_out,
                     float* __restrict__ p_out, int N)
{
    const int lane = threadIdx.x & 63;
    const int wid = threadIdx.x >> 6;
    const int wpb = blockDim.x >> 6;
    const float lg = ln_g[lane], lb = ln_b[lane];

    for (int n = blockIdx.x * wpb + wid; n < N; n += gridDim.x * wpb) {
        const int end = offs_end[n];
        const int deg = cnt[n];
        const int start = end - deg;
        const size_t o = (size_t)n * D + lane;

        const float2 p2n = P2[o];   // {B2h, sigmaK}, hoisted per node

        float asig = 0.f, av = 0.f, ap = 0.f;

        int k = start;
        for (; k + 3 < end; k += 4) {
            int eid[4], s[4];
#pragma unroll
            for (int i = 0; i < 4; ++i)
                eid[i] = __builtin_amdgcn_readfirstlane(bucket[k + i]);
#pragma unroll
            for (int i = 0; i < 4; ++i)
                s[i] = __builtin_amdgcn_readfirstlane(src[eid[i]]);

            float2 p1[4]; unsigned int p3[4]; float hb[4];
#pragma unroll
            for (int i = 0; i < 4; ++i) {
                p1[i] = P1[(size_t)s[i] * D + lane];        // {B1h, sigmaQ}
                p3[i] = P3u[(size_t)s[i] * D + lane];       // bf16 {vh, C2p}
                hb[i] = he_eout[(size_t)eid[i] * D + lane]; // B3e partial
            }

            float sg[4], pr[4];
#pragma unroll
            for (int i = 0; i < 4; ++i) {
                float he = hb[i] + p1[i].x + p2n.x;
                he_eout[(size_t)eid[i] * D + lane] = fmaxf(he, 0.f);
                sg[i] = 1.f / (1.f + expf(-he));
                pr[i] = p1[i].y * p2n.y;
            }
#pragma unroll
            for (int off = 32; off > 0; off >>= 1) {
#pragma unroll
                for (int i = 0; i < 4; ++i) pr[i] += __shfl_xor(pr[i], off);
            }
#pragma unroll
            for (int i = 0; i < 4; ++i) {
                asig += sg[i];
                av   += sg[i] * pr[i] * bf_lo(p3[i]);
                ap   += sg[i] * bf_hi(p3[i]);
            }
        }
        for (; k < end; ++k) {
            int e0 = __builtin_amdgcn_readfirstlane(bucket[k]);
            int s0 = __builtin_amdgcn_readfirstlane(src[e0]);
            size_t eo0 = (size_t)e0 * D + lane;
            float2 p10 = P1[(size_t)s0 * D + lane];
            unsigned int p30 = P3u[(size_t)s0 * D + lane];
            float he0 = he_eout[eo0] + p10.x + p2n.x;
            he_eout[eo0] = fmaxf(he0, 0.f);
            float sg0 = 1.f / (1.f + expf(-he0));
            float pr0 = p10.y * p2n.y;
#pragma unroll
            for (int off = 32; off > 0; off >>= 1) pr0 += __shfl_xor(pr0, off);
            asig += sg0;
            av   += sg0 * pr0 * bf_lo(p30);
            ap   += sg0 * bf_hi(p30);
        }

        // fused epilogue (verified R9/R10)
        float denom = asig + EPS;
        float vh = bf_lo(P3u[o]);
        float hv = vh + av / denom;
        hv = fmaxf(hv, 0.f);
        float su = hv;
#pragma unroll
        for (int off = 32; off > 0; off >>= 1) su += __shfl_xor(su, off);
        float mu = su * (1.f / 64.f);
        float dv = hv - mu;
        float s2 = dv * dv;
#pragma unroll
        for (int off = 32; off > 0; off >>= 1) s2 += __shfl_xor(s2, off);
        float var = s2 * (1.f / 64.f);
        h_out[o] = dv * rsqrtf(var + LN_EPS) * lg + lb;

        float pv = p_out[o] + ap / denom;   // p_out holds C1p
        p_out[o] = tanhf(pv);
    }
}

extern "C" void kernel_launch(void* const* d_in, const int* in_sizes, int n_in,
                              void* d_out, int out_size, void* d_ws, size_t ws_size,
                              hipStream_t stream) {
    const float* h    = (const float*)d_in[0];
    const float* e    = (const float*)d_in[1];
    const float* p    = (const float*)d_in[2];
    const float* WK   = (const float*)d_in[3];
    const float* bK   = (const float*)d_in[4];
    const float* WV   = (const float*)d_in[5];
    const float* bV   = (const float*)d_in[6];
    const float* WB1  = (const float*)d_in[7];
    const float* bB1  = (const float*)d_in[8];
    const float* WB2  = (const float*)d_in[9];
    const float* bB2  = (const float*)d_in[10];
    const float* WB3  = (const float*)d_in[11];
    const float* bB3  = (const float*)d_in[12];
    const float* WC1  = (const float*)d_in[13];
    const float* bC1  = (const float*)d_in[14];
    const float* WC2  = (const float*)d_in[15];
    const float* bC2  = (const float*)d_in[16];
    const float* ln_g = (const float*)d_in[17];
    const float* ln_b = (const float*)d_in[18];
    const int*   src  = (const int*)d_in[19];
    const int*   dst  = (const int*)d_in[20];

    const int N = in_sizes[0] / D;
    const int E = in_sizes[1] / D;
    const size_t ND = (size_t)N * D;

    float* out   = (float*)d_out;
    float* h_out = out;
    float* e_out = out + ND;                  // B3e partial, then relu(he)
    float* p_out = out + ND + (size_t)E * D;  // C1p, then tanh(...)

    // ws: P1 2ND + P2 2ND (f32) + P3u ND (u32)
    //   + cnt N + offs N + bucket E + csum (int)  ~= 68 MB
    float*        ws    = (float*)d_ws;
    float2*       P1    = (float2*)(ws);                // 2*ND floats
    float2*       P2    = (float2*)(ws + 2 * ND);       // 2*ND floats
    unsigned int* P3u   = (unsigned int*)(ws + 4 * ND); // ND u32
    int*          cnt   = (int*)(ws + 5 * ND);          // N ints
    int*          offs  = cnt + N;                      // N ints
    int*          bucket= offs + N;                     // E ints
    int*          csum  = bucket + E;                   // nchunk ints (<=256)

    const int nchunk = (N + 255) / 256;

    hipMemsetAsync(cnt, 0, (size_t)N * sizeof(int), stream);

    node_linears<<<(N + NT - 1) / NT, 256, 0, stream>>>(
        h, p, WK, bK, WV, bV, WB1, bB1, WB2, bB2, WC1, bC1, WC2, bC2,
        P1, P2, P3u, p_out, N);

    hist_kernel<<<(E + 255) / 256, 256, 0, stream>>>(dst, cnt, E);
    chunksum_kernel<<<nchunk, 256, 0, stream>>>(cnt, csum, N);
    scanchunk_kernel<<<1, 256, 0, stream>>>(csum, nchunk);
    offsets_kernel<<<nchunk, 256, 0, stream>>>(cnt, csum, offs, N);
    scatter_kernel<<<(E + 255) / 256, 256, 0, stream>>>(dst, offs, bucket, E);

    he_b3<<<(E + 63) / 64, 256, 0, stream>>>(e, WB3, bB3, e_out, E);

    edge_gather_finalize<<<(N + 3) / 4, 256, 0, stream>>>(
        bucket, offs, cnt, src, P1, P2, P3u, ln_g, ln_b,
        e_out, h_out, p_out, N);
}

// Round 13
// 502.329 us; speedup vs baseline: 12.1003x; 1.1560x over previous
//
#include <hip/hip_runtime.h>
#include <math.h>

#define D 64
#define EPS 1e-12f
#define LN_EPS 1e-5f
#define NT 64    // nodes per block in node_linears

typedef __attribute__((ext_vector_type(8))) short short8;
typedef __attribute__((ext_vector_type(4))) float float4v;

// bf16 round-to-nearest-even packing helpers
__device__ __forceinline__ unsigned int f2bf_bits(float x) {
    unsigned int u = __float_as_uint(x);
    return (u + 0x7fffu + ((u >> 16) & 1u)) >> 16;
}
__device__ __forceinline__ float bf_lo(unsigned int p) {  // low 16 bits -> float
    return __uint_as_float(p << 16);
}
__device__ __forceinline__ float bf_hi(unsigned int p) {  // high 16 bits -> float
    return __uint_as_float(p & 0xffff0000u);
}

// ---------------------------------------------------------------------------
// Kernel A: per-node linears, tile-parallel (verified R8-R12, verbatim).
// ---------------------------------------------------------------------------
__global__ void __launch_bounds__(256, 2)
node_linears(const float* __restrict__ h, const float* __restrict__ p,
             const float* __restrict__ WK, const float* __restrict__ bK,
             const float* __restrict__ WV, const float* __restrict__ bV,
             const float* __restrict__ WB1, const float* __restrict__ bB1,
             const float* __restrict__ WB2, const float* __restrict__ bB2,
             const float* __restrict__ WC1, const float* __restrict__ bC1,
             const float* __restrict__ WC2, const float* __restrict__ bC2,
             float2* __restrict__ P1, float2* __restrict__ P2,
             unsigned int* __restrict__ P3u, float* __restrict__ C1pOut,
             int N)
{
    __shared__ float xs[NT * 128];    // [n][k], k<64 = h, k>=64 = p
    __shared__ float wsm[64 * 128];   // phase weight buffer, f4-swizzled

    const int t = threadIdx.x;
    const int lane = t & 63;
    const int wid = t >> 6;
    const int n0 = blockIdx.x * NT;

    float4* xs4 = (float4*)xs;
    float4* wsm4 = (float4*)wsm;

    {
        const float4* h4 = (const float4*)h;
        const float4* p4 = (const float4*)p;
        for (int i = t; i < NT * 32; i += 256) {
            int n = i >> 5, kq = i & 31;
            int ng = n0 + n;
            float4 v = make_float4(0.f, 0.f, 0.f, 0.f);
            if (ng < N) v = (kq < 16) ? h4[(size_t)ng * 16 + kq]
                                      : p4[(size_t)ng * 16 + (kq - 16)];
            xs4[n * 32 + kq] = v;
        }
    }
    __syncthreads();

#define STAGE_W128(W)                                                    \
    {                                                                    \
        const float4* w4 = (const float4*)(W);                           \
        for (int i = t; i < 64 * 32; i += 256) {                         \
            int d = i >> 5, j = i & 31;                                  \
            wsm4[d * 32 + (j ^ (d & 31))] = w4[i];                       \
        }                                                                \
    }                                                                    \
    __syncthreads();

#define LOAD_ROW128(wreg)                                                \
    _Pragma("unroll")                                                    \
    for (int j = 0; j < 32; ++j) wreg[j] = wsm4[lane * 32 + (j ^ (lane & 31))];

    // ---- WK phase: sigmaQ -> P1.y, sigmaK -> P2.y ----
    {
        STAGE_W128(WK);
        float4 w[32];
        LOAD_ROW128(w);
        float bk = bK[lane];
#pragma unroll 1
        for (int i = 0; i < 16; ++i) {
            int n = wid * 16 + i;
            const float4* xv = (const float4*)&xs[n * 128];
            float a0 = 0.f, a1 = 0.f, a2 = 0.f, a3 = 0.f;
#pragma unroll
            for (int j = 0; j < 32; j += 4) {
                float4 x0 = xv[j + 0], x1 = xv[j + 1], x2 = xv[j + 2], x3 = xv[j + 3];
                a0 += w[j+0].x*x0.x + w[j+0].y*x0.y + w[j+0].z*x0.z + w[j+0].w*x0.w;
                a1 += w[j+1].x*x1.x + w[j+1].y*x1.y + w[j+1].z*x1.z + w[j+1].w*x1.w;
                a2 += w[j+2].x*x2.x + w[j+2].y*x2.y + w[j+2].z*x2.z + w[j+2].w*x2.w;
                a3 += w[j+3].x*x3.x + w[j+3].y*x3.y + w[j+3].z*x3.z + w[j+3].w*x3.w;
            }
            float aq = bk + (a0 + a1) + (a2 + a3);
            int ng = n0 + n;
            if (ng < N) {
                size_t o = (size_t)ng * 64 + lane;
                P1[o].y = expf(tanhf(aq));
                P2[o].y = expf(1.f / (1.f + expf(-aq)));
            }
        }
        __syncthreads();
    }

#define STAGE_W64x2(WA, WB)                                              \
    {                                                                    \
        for (int i = t; i < 2048; i += 256) {                            \
            int m = i >> 10;                                             \
            int r = i & 1023;                                            \
            int d = r >> 4, j = r & 15;                                  \
            const float4* w4 = m ? (const float4*)(WB) : (const float4*)(WA); \
            wsm4[m * 1024 + d * 16 + (j ^ (d & 15))] = w4[r];            \
        }                                                                \
    }                                                                    \
    __syncthreads();

    // ---- WB1/WB2 phase (input h): B1h -> P1.x, B2h -> P2.x ----
    {
        STAGE_W64x2(WB1, WB2);
        float4 w1[16], w2[16];
#pragma unroll
        for (int j = 0; j < 16; ++j) {
            w1[j] = wsm4[lane * 16 + (j ^ (lane & 15))];
            w2[j] = wsm4[1024 + lane * 16 + (j ^ (lane & 15))];
        }
        float b1 = bB1[lane], b2 = bB2[lane];
#pragma unroll 1
        for (int i = 0; i < 16; ++i) {
            int n = wid * 16 + i;
            const float4* xv = (const float4*)&xs[n * 128];
            float a0 = 0.f, a1 = 0.f, c0 = 0.f, c1 = 0.f;
#pragma unroll
            for (int j = 0; j < 16; j += 2) {
                float4 x0 = xv[j], x1 = xv[j + 1];
                a0 += w1[j].x*x0.x + w1[j].y*x0.y + w1[j].z*x0.z + w1[j].w*x0.w;
                a1 += w1[j+1].x*x1.x + w1[j+1].y*x1.y + w1[j+1].z*x1.z + w1[j+1].w*x1.w;
                c0 += w2[j].x*x0.x + w2[j].y*x0.y + w2[j].z*x0.z + w2[j].w*x0.w;
                c1 += w2[j+1].x*x1.x + w2[j+1].y*x1.y + w2[j+1].z*x1.z + w2[j+1].w*x1.w;
            }
            int ng = n0 + n;
            if (ng < N) {
                size_t o = (size_t)ng * 64 + lane;
                P1[o].x = b1 + a0 + a1;
                P2[o].x = b2 + c0 + c1;
            }
        }
        __syncthreads();
    }

    // ---- WV phase: vh -> xs h-slot (dead after WB; lockstep-safe) ----
    {
        STAGE_W128(WV);
        float4 w[32];
        LOAD_ROW128(w);
        float bv = bV[lane];
#pragma unroll 1
        for (int i = 0; i < 16; ++i) {
            int n = wid * 16 + i;
            const float4* xv = (const float4*)&xs[n * 128];
            float a0 = 0.f, a1 = 0.f, a2 = 0.f, a3 = 0.f;
#pragma unroll
            for (int j = 0; j < 32; j += 4) {
                float4 x0 = xv[j + 0], x1 = xv[j + 1], x2 = xv[j + 2], x3 = xv[j + 3];
                a0 += w[j+0].x*x0.x + w[j+0].y*x0.y + w[j+0].z*x0.z + w[j+0].w*x0.w;
                a1 += w[j+1].x*x1.x + w[j+1].y*x1.y + w[j+1].z*x1.z + w[j+1].w*x1.w;
                a2 += w[j+2].x*x2.x + w[j+2].y*x2.y + w[j+2].z*x2.z + w[j+2].w*x2.w;
                a3 += w[j+3].x*x3.x + w[j+3].y*x3.y + w[j+3].z*x3.z + w[j+3].w*x3.w;
            }
            float av = bv + (a0 + a1) + (a2 + a3);
            xs[n * 128 + lane] = av;
        }
        __syncthreads();
    }

    // ---- WC1/WC2 phase (input p): C1p -> p_out region, pack P3u ----
    {
        STAGE_W64x2(WC1, WC2);
        float4 w1[16], w2[16];
#pragma unroll
        for (int j = 0; j < 16; ++j) {
            w1[j] = wsm4[lane * 16 + (j ^ (lane & 15))];
            w2[j] = wsm4[1024 + lane * 16 + (j ^ (lane & 15))];
        }
        float b1 = bC1[lane], b2 = bC2[lane];
#pragma unroll 1
        for (int i = 0; i < 16; ++i) {
            int n = wid * 16 + i;
            const float4* xv = (const float4*)&xs[n * 128 + 64];
            float a0 = 0.f, a1 = 0.f, c0 = 0.f, c1 = 0.f;
#pragma unroll
            for (int j = 0; j < 16; j += 2) {
                float4 x0 = xv[j], x1 = xv[j + 1];
                a0 += w1[j].x*x0.x + w1[j].y*x0.y + w1[j].z*x0.z + w1[j].w*x0.w;
                a1 += w1[j+1].x*x1.x + w1[j+1].y*x1.y + w1[j+1].z*x1.z + w1[j+1].w*x1.w;
                c0 += w2[j].x*x0.x + w2[j].y*x0.y + w2[j].z*x0.z + w2[j].w*x0.w;
                c1 += w2[j+1].x*x1.x + w2[j+1].y*x1.y + w2[j+1].z*x1.z + w2[j+1].w*x1.w;
            }
            int ng = n0 + n;
            if (ng < N) {
                size_t o = (size_t)ng * 64 + lane;
                C1pOut[o] = b1 + a0 + a1;
                float c2 = b2 + c0 + c1;
                float vh = xs[n * 128 + lane];
                P3u[o] = f2bf_bits(vh) | (f2bf_bits(c2) << 16);
            }
        }
    }
}

// ---------------------------------------------------------------------------
// dst-bucketing pipeline (int atomics only; verified R4-R12).
// ---------------------------------------------------------------------------
__global__ void hist_kernel(const int* __restrict__ dst, int* __restrict__ cnt, int E) {
    int i = blockIdx.x * blockDim.x + threadIdx.x;
    if (i < E) atomicAdd(&cnt[dst[i]], 1);
}

__global__ void chunksum_kernel(const int* __restrict__ cnt, int* __restrict__ csum, int N) {
    __shared__ int sc[256];
    int t = threadIdx.x;
    int i = blockIdx.x * 256 + t;
    sc[t] = (i < N) ? cnt[i] : 0;
    __syncthreads();
    for (int off = 128; off > 0; off >>= 1) {
        if (t < off) sc[t] += sc[t + off];
        __syncthreads();
    }
    if (t == 0) csum[blockIdx.x] = sc[0];
}

__global__ void scanchunk_kernel(int* __restrict__ csum, int nch) {
    __shared__ int sc[256];
    int t = threadIdx.x;
    int v = (t < nch) ? csum[t] : 0;
    sc[t] = v;
    __syncthreads();
    for (int off = 1; off < 256; off <<= 1) {
        int y = (t >= off) ? sc[t - off] : 0;
        __syncthreads();
        sc[t] += y;
        __syncthreads();
    }
    if (t < nch) csum[t] = sc[t] - v;   // exclusive prefix
}

__global__ void offsets_kernel(const int* __restrict__ cnt, const int* __restrict__ csum,
                               int* __restrict__ offs, int N) {
    __shared__ int sc[256];
    int t = threadIdx.x;
    int i = blockIdx.x * 256 + t;
    int v = (i < N) ? cnt[i] : 0;
    sc[t] = v;
    __syncthreads();
    for (int off = 1; off < 256; off <<= 1) {
        int y = (t >= off) ? sc[t - off] : 0;
        __syncthreads();
        sc[t] += y;
        __syncthreads();
    }
    if (i < N) offs[i] = csum[blockIdx.x] + sc[t] - v;  // global exclusive prefix
}

__global__ void scatter_kernel(const int* __restrict__ dst, int* __restrict__ offs,
                               int* __restrict__ bucket, int E) {
    int i = blockIdx.x * blockDim.x + threadIdx.x;
    if (i < E) {
        int pos = atomicAdd(&offs[dst[i]], 1);
        bucket[pos] = i;
    }
}

// ---------------------------------------------------------------------------
// Kernel B: he_b3 v4 -- MFMA. OUT[E][64] = E · WB3^T + bB3 is a pure dense
// GEMM; run it on the matrix pipe instead of VALU+LDS (v3's 195us was the
// structural floor of the fp32 path: 16 ds_read_b128 + 64 v_fma per edge).
// Block = 64 edges. E-tile + WB3 staged as bf16 in LDS, rows padded to 72
// elems (144B -> banks rotate 4/row, <=2-way). Wave w: A = edges w*16..+15
// (lane: row=l&15, k=8*(l>>4)+j), loops 4 d-tiles: B = WB3 rows d0+(l&15),
// same k-runs; 2x mfma_f32_16x16x32_bf16 (K=64); C init = bias (col-only).
// C/D layout per verified m89 mapping: col=lane&15, row=4*(lane>>4)+reg.
// bf16 operand rounding: abs err ~0.004 on b3 (threshold 0.129).
// ---------------------------------------------------------------------------
__global__ void __launch_bounds__(256, 2)
he_b3_mfma(const float* __restrict__ e,
           const float* __restrict__ WB3, const float* __restrict__ bB3,
           float* __restrict__ he_out, int E)
{
    __shared__ __align__(16) unsigned short Ebf[64 * 72];
    __shared__ __align__(16) unsigned short Wbf[64 * 72];

    const int t = threadIdx.x;
    const int lane = t & 63;
    const int wid = t >> 6;

    const int e0 = blockIdx.x << 6;
    const int nrow = min(64, E - e0);

    // ---- stage WB3 as bf16 (thread t: row r=t>>2, 16-elem seg s=t&3) ----
    {
        const int r = t >> 2, s = t & 3;
        const float4* src = (const float4*)(WB3 + (size_t)r * 64 + s * 16);
        float4 v0 = src[0], v1 = src[1], v2 = src[2], v3 = src[3];
        uint4 w0, w1;
        w0.x = f2bf_bits(v0.x) | (f2bf_bits(v0.y) << 16);
        w0.y = f2bf_bits(v0.z) | (f2bf_bits(v0.w) << 16);
        w0.z = f2bf_bits(v1.x) | (f2bf_bits(v1.y) << 16);
        w0.w = f2bf_bits(v1.z) | (f2bf_bits(v1.w) << 16);
        w1.x = f2bf_bits(v2.x) | (f2bf_bits(v2.y) << 16);
        w1.y = f2bf_bits(v2.z) | (f2bf_bits(v2.w) << 16);
        w1.z = f2bf_bits(v3.x) | (f2bf_bits(v3.y) << 16);
        w1.w = f2bf_bits(v3.z) | (f2bf_bits(v3.w) << 16);
        *(uint4*)(&Wbf[r * 72 + s * 16]) = w0;
        *(uint4*)(&Wbf[r * 72 + s * 16 + 8]) = w1;
    }
    // ---- stage E tile as bf16 ----
    {
        const int r = t >> 2, s = t & 3;
        uint4 w0 = make_uint4(0, 0, 0, 0), w1 = make_uint4(0, 0, 0, 0);
        if (r < nrow) {
            const float4* src = (const float4*)(e + (size_t)(e0 + r) * 64 + s * 16);
            float4 v0 = src[0], v1 = src[1], v2 = src[2], v3 = src[3];
            w0.x = f2bf_bits(v0.x) | (f2bf_bits(v0.y) << 16);
            w0.y = f2bf_bits(v0.z) | (f2bf_bits(v0.w) << 16);
            w0.z = f2bf_bits(v1.x) | (f2bf_bits(v1.y) << 16);
            w0.w = f2bf_bits(v1.z) | (f2bf_bits(v1.w) << 16);
            w1.x = f2bf_bits(v2.x) | (f2bf_bits(v2.y) << 16);
            w1.y = f2bf_bits(v2.z) | (f2bf_bits(v2.w) << 16);
            w1.z = f2bf_bits(v3.x) | (f2bf_bits(v3.y) << 16);
            w1.w = f2bf_bits(v3.z) | (f2bf_bits(v3.w) << 16);
        }
        *(uint4*)(&Ebf[r * 72 + s * 16]) = w0;
        *(uint4*)(&Ebf[r * 72 + s * 16 + 8]) = w1;
    }
    __syncthreads();

    // ---- A fragments: wave wid owns edges e0+wid*16 .. +15 ----
    const int arow = (wid << 4) + (lane & 15);
    const int krun = (lane >> 4) << 3;   // 0,8,16,24
    short8 a0 = *(const short8*)(&Ebf[arow * 72 + krun]);        // k 0..31
    short8 a1 = *(const short8*)(&Ebf[arow * 72 + krun + 32]);   // k 32..63

    const int erow0 = e0 + (wid << 4) + ((lane >> 4) << 2);

    // ---- 4 d-tiles of 16 output dims each ----
#pragma unroll
    for (int dt = 0; dt < 4; ++dt) {
        const int d0 = dt << 4;
        const int dcol = d0 + (lane & 15);
        short8 b0 = *(const short8*)(&Wbf[dcol * 72 + krun]);
        short8 b1 = *(const short8*)(&Wbf[dcol * 72 + krun + 32]);
        float bias = bB3[dcol];
        float4v acc = {bias, bias, bias, bias};
        acc = __builtin_amdgcn_mfma_f32_16x16x32_bf16(a0, b0, acc, 0, 0, 0);
        acc = __builtin_amdgcn_mfma_f32_16x16x32_bf16(a1, b1, acc, 0, 0, 0);
#pragma unroll
        for (int r = 0; r < 4; ++r) {
            int er = erow0 + r;
            if (er < E) he_out[(size_t)er * 64 + dcol] = acc[r];
        }
    }
}

// ---------------------------------------------------------------------------
// Kernel C: MERGED edge finish + gather + finalize (verified R10-R12, verbatim).
// ---------------------------------------------------------------------------
__global__ void __launch_bounds__(256, 3)
edge_gather_finalize(const int* __restrict__ bucket, const int* __restrict__ offs_end,
                     const int* __restrict__ cnt, const int* __restrict__ src,
                     const float2* __restrict__ P1, const float2* __restrict__ P2,
                     const unsigned int* __restrict__ P3u,
                     const float* __restrict__ ln_g, const float* __restrict__ ln_b,
                     float* __restrict__ he_eout, float* __restrict__ h_out,
                     float* __restrict__ p_out, int N)
{
    const int lane = threadIdx.x & 63;
    const int wid = threadIdx.x >> 6;
    const int wpb = blockDim.x >> 6;
    const float lg = ln_g[lane], lb = ln_b[lane];

    for (int n = blockIdx.x * wpb + wid; n < N; n += gridDim.x * wpb) {
        const int end = offs_end[n];
        const int deg = cnt[n];
        const int start = end - deg;
        const size_t o = (size_t)n * D + lane;

        const float2 p2n = P2[o];   // {B2h, sigmaK}, hoisted per node

        float asig = 0.f, av = 0.f, ap = 0.f;

        int k = start;
        for (; k + 3 < end; k += 4) {
            int eid[4], s[4];
#pragma unroll
            for (int i = 0; i < 4; ++i)
                eid[i] = __builtin_amdgcn_readfirstlane(bucket[k + i]);
#pragma unroll
            for (int i = 0; i < 4; ++i)
                s[i] = __builtin_amdgcn_readfirstlane(src[eid[i]]);

            float2 p1[4]; unsigned int p3[4]; float hb[4];
#pragma unroll
            for (int i = 0; i < 4; ++i) {
                p1[i] = P1[(size_t)s[i] * D + lane];        // {B1h, sigmaQ}
                p3[i] = P3u[(size_t)s[i] * D + lane];       // bf16 {vh, C2p}
                hb[i] = he_eout[(size_t)eid[i] * D + lane]; // B3e partial
            }

            float sg[4], pr[4];
#pragma unroll
            for (int i = 0; i < 4; ++i) {
                float he = hb[i] + p1[i].x + p2n.x;
                he_eout[(size_t)eid[i] * D + lane] = fmaxf(he, 0.f);
                sg[i] = 1.f / (1.f + expf(-he));
                pr[i] = p1[i].y * p2n.y;
            }
#pragma unroll
            for (int off = 32; off > 0; off >>= 1) {
#pragma unroll
                for (int i = 0; i < 4; ++i) pr[i] += __shfl_xor(pr[i], off);
            }
#pragma unroll
            for (int i = 0; i < 4; ++i) {
                asig += sg[i];
                av   += sg[i] * pr[i] * bf_lo(p3[i]);
                ap   += sg[i] * bf_hi(p3[i]);
            }
        }
        for (; k < end; ++k) {
            int e0 = __builtin_amdgcn_readfirstlane(bucket[k]);
            int s0 = __builtin_amdgcn_readfirstlane(src[e0]);
            size_t eo0 = (size_t)e0 * D + lane;
            float2 p10 = P1[(size_t)s0 * D + lane];
            unsigned int p30 = P3u[(size_t)s0 * D + lane];
            float he0 = he_eout[eo0] + p10.x + p2n.x;
            he_eout[eo0] = fmaxf(he0, 0.f);
            float sg0 = 1.f / (1.f + expf(-he0));
            float pr0 = p10.y * p2n.y;
#pragma unroll
            for (int off = 32; off > 0; off >>= 1) pr0 += __shfl_xor(pr0, off);
            asig += sg0;
            av   += sg0 * pr0 * bf_lo(p30);
            ap   += sg0 * bf_hi(p30);
        }

        // fused epilogue (verified R9-R12)
        float denom = asig + EPS;
        float vh = bf_lo(P3u[o]);
        float hv = vh + av / denom;
        hv = fmaxf(hv, 0.f);
        float su = hv;
#pragma unroll
        for (int off = 32; off > 0; off >>= 1) su += __shfl_xor(su, off);
        float mu = su * (1.f / 64.f);
        float dv = hv - mu;
        float s2 = dv * dv;
#pragma unroll
        for (int off = 32; off > 0; off >>= 1) s2 += __shfl_xor(s2, off);
        float var = s2 * (1.f / 64.f);
        h_out[o] = dv * rsqrtf(var + LN_EPS) * lg + lb;

        float pv = p_out[o] + ap / denom;   // p_out holds C1p
        p_out[o] = tanhf(pv);
    }
}

extern "C" void kernel_launch(void* const* d_in, const int* in_sizes, int n_in,
                              void* d_out, int out_size, void* d_ws, size_t ws_size,
                              hipStream_t stream) {
    const float* h    = (const float*)d_in[0];
    const float* e    = (const float*)d_in[1];
    const float* p    = (const float*)d_in[2];
    const float* WK   = (const float*)d_in[3];
    const float* bK   = (const float*)d_in[4];
    const float* WV   = (const float*)d_in[5];
    const float* bV   = (const float*)d_in[6];
    const float* WB1  = (const float*)d_in[7];
    const float* bB1  = (const float*)d_in[8];
    const float* WB2  = (const float*)d_in[9];
    const float* bB2  = (const float*)d_in[10];
    const float* WB3  = (const float*)d_in[11];
    const float* bB3  = (const float*)d_in[12];
    const float* WC1  = (const float*)d_in[13];
    const float* bC1  = (const float*)d_in[14];
    const float* WC2  = (const float*)d_in[15];
    const float* bC2  = (const float*)d_in[16];
    const float* ln_g = (const float*)d_in[17];
    const float* ln_b = (const float*)d_in[18];
    const int*   src  = (const int*)d_in[19];
    const int*   dst  = (const int*)d_in[20];

    const int N = in_sizes[0] / D;
    const int E = in_sizes[1] / D;
    const size_t ND = (size_t)N * D;

    float* out   = (float*)d_out;
    float* h_out = out;
    float* e_out = out + ND;                  // B3e partial, then relu(he)
    float* p_out = out + ND + (size_t)E * D;  // C1p, then tanh(...)

    // ws: P1 2ND + P2 2ND (f32) + P3u ND (u32)
    //   + cnt N + offs N + bucket E + csum (int)  ~= 68 MB
    float*        ws    = (float*)d_ws;
    float2*       P1    = (float2*)(ws);                // 2*ND floats
    float2*       P2    = (float2*)(ws + 2 * ND);       // 2*ND floats
    unsigned int* P3u   = (unsigned int*)(ws + 4 * ND); // ND u32
    int*          cnt   = (int*)(ws + 5 * ND);          // N ints
    int*          offs  = cnt + N;                      // N ints
    int*          bucket= offs + N;                     // E ints
    int*          csum  = bucket + E;                   // nchunk ints (<=256)

    const int nchunk = (N + 255) / 256;

    hipMemsetAsync(cnt, 0, (size_t)N * sizeof(int), stream);

    node_linears<<<(N + NT - 1) / NT, 256, 0, stream>>>(
        h, p, WK, bK, WV, bV, WB1, bB1, WB2, bB2, WC1, bC1, WC2, bC2,
        P1, P2, P3u, p_out, N);

    hist_kernel<<<(E + 255) / 256, 256, 0, stream>>>(dst, cnt, E);
    chunksum_kernel<<<nchunk, 256, 0, stream>>>(cnt, csum, N);
    scanchunk_kernel<<<1, 256, 0, stream>>>(csum, nchunk);
    offsets_kernel<<<nchunk, 256, 0, stream>>>(cnt, csum, offs, N);
    scatter_kernel<<<(E + 255) / 256, 256, 0, stream>>>(dst, offs, bucket, E);

    he_b3_mfma<<<(E + 63) / 64, 256, 0, stream>>>(e, WB3, bB3, e_out, E);

    edge_gather_finalize<<<(N + 3) / 4, 256, 0, stream>>>(
        bucket, offs, cnt, src, P1, P2, P3u, ln_g, ln_b,
        e_out, h_out, p_out, N);
}

// Round 14
// 409.712 us; speedup vs baseline: 14.8357x; 1.2261x over previous
//
#include <hip/hip_runtime.h>
#include <math.h>

#define D 64
#define EPS 1e-12f
#define LN_EPS 1e-5f

typedef __attribute__((ext_vector_type(8))) short short8;
typedef __attribute__((ext_vector_type(4))) float float4v;

// bf16 round-to-nearest-even packing helpers
__device__ __forceinline__ unsigned int f2bf_bits(float x) {
    unsigned int u = __float_as_uint(x);
    return (u + 0x7fffu + ((u >> 16) & 1u)) >> 16;
}
__device__ __forceinline__ float bf_lo(unsigned int p) {  // low 16 bits -> float
    return __uint_as_float(p << 16);
}
__device__ __forceinline__ float bf_hi(unsigned int p) {  // high 16 bits -> float
    return __uint_as_float(p & 0xffff0000u);
}
__device__ __forceinline__ uint4 pack8(float4 u, float4 v) {
    uint4 w;
    w.x = f2bf_bits(u.x) | (f2bf_bits(u.y) << 16);
    w.y = f2bf_bits(u.z) | (f2bf_bits(u.w) << 16);
    w.z = f2bf_bits(v.x) | (f2bf_bits(v.y) << 16);
    w.w = f2bf_bits(v.z) | (f2bf_bits(v.w) << 16);
    return w;
}

// ---------------------------------------------------------------------------
// Kernel A v2: node linears on the MATRIX pipe, reusing the fragment recipe
// verified in he_b3_mfma (R13): A row=lane&15 / krun=(lane>>4)*8; B col-row;
// C/D col=lane&15, row=4*(lane>>4)+r; bias preloaded into C.
// Block = 64 nodes. X=[64][128] bf16 in LDS (cols 0-63 h, 64-127 p), one
// weight tile staged bf16 per phase (136-pad = verified bank rotation).
// Phases: WK(K=128)->sigmaQ/sigmaK, WB1|WB2(K=64 dual-acc)->B1h/B2h,
// WV(K=128)->vh (LDS stash), WC1|WC2(K=64)->C1p + P3u pack.
//   P1[n*64+d]  = {B1h, sigmaQ}   P2 = {B2h, sigmaK}
//   P3u         = packed bf16 {vh, C2p}    C1p -> p_out region
// ---------------------------------------------------------------------------
__global__ void __launch_bounds__(256, 2)
node_linears_mfma(const float* __restrict__ h, const float* __restrict__ p,
                  const float* __restrict__ WK, const float* __restrict__ bK,
                  const float* __restrict__ WV, const float* __restrict__ bV,
                  const float* __restrict__ WB1, const float* __restrict__ bB1,
                  const float* __restrict__ WB2, const float* __restrict__ bB2,
                  const float* __restrict__ WC1, const float* __restrict__ bC1,
                  const float* __restrict__ WC2, const float* __restrict__ bC2,
                  float2* __restrict__ P1, float2* __restrict__ P2,
                  unsigned int* __restrict__ P3u, float* __restrict__ C1pOut,
                  int N)
{
    __shared__ __align__(16) unsigned short Xbf[64 * 136];
    __shared__ __align__(16) unsigned short Wbf[64 * 136];
    __shared__ float Vf[64 * 68];

    const int t = threadIdx.x;
    const int lane = t & 63;
    const int wid = t >> 6;
    const int n0 = blockIdx.x << 6;
    const int nrow = min(64, N - n0);

    const int r_ = t >> 2, s_ = t & 3;   // staging: row r_, 32-col segment s_

    // ---- stage X (h|p) and WK before first barrier ----
    {
        uint4 w0 = {0,0,0,0}, w1 = {0,0,0,0}, w2 = {0,0,0,0}, w3 = {0,0,0,0};
        if (r_ < nrow) {
            const float* srcp = (s_ < 2) ? (h + (size_t)(n0 + r_) * 64 + s_ * 32)
                                         : (p + (size_t)(n0 + r_) * 64 + (s_ - 2) * 32);
            const float4* s4 = (const float4*)srcp;
            w0 = pack8(s4[0], s4[1]); w1 = pack8(s4[2], s4[3]);
            w2 = pack8(s4[4], s4[5]); w3 = pack8(s4[6], s4[7]);
        }
        uint4* dst = (uint4*)&Xbf[r_ * 136 + s_ * 32];
        dst[0] = w0; dst[1] = w1; dst[2] = w2; dst[3] = w3;
    }
    {
        const float4* s4 = (const float4*)(WK + (size_t)r_ * 128 + s_ * 32);
        uint4* dst = (uint4*)&Wbf[r_ * 136 + s_ * 32];
        dst[0] = pack8(s4[0], s4[1]); dst[1] = pack8(s4[2], s4[3]);
        dst[2] = pack8(s4[4], s4[5]); dst[3] = pack8(s4[6], s4[7]);
    }
    __syncthreads();

    // ---- A fragments (held in VGPRs across all phases; 16 VGPR) ----
    const int arow = (wid << 4) + (lane & 15);
    const int krun = (lane >> 4) << 3;
    const short8 a0 = *(const short8*)&Xbf[arow * 136 + krun];        // h k0..31
    const short8 a1 = *(const short8*)&Xbf[arow * 136 + krun + 32];   // h k32..63
    const short8 a2 = *(const short8*)&Xbf[arow * 136 + krun + 64];   // p k0..31
    const short8 a3 = *(const short8*)&Xbf[arow * 136 + krun + 96];   // p k32..63
    const int nodeb = (wid << 4) + ((lane >> 4) << 2);

    // ---- WK phase (K=128): sigmaQ -> P1.y, sigmaK -> P2.y ----
#pragma unroll
    for (int dt = 0; dt < 4; ++dt) {
        const int dcol = (dt << 4) + (lane & 15);
        short8 b0 = *(const short8*)&Wbf[dcol * 136 + krun];
        short8 b1 = *(const short8*)&Wbf[dcol * 136 + krun + 32];
        short8 b2 = *(const short8*)&Wbf[dcol * 136 + krun + 64];
        short8 b3 = *(const short8*)&Wbf[dcol * 136 + krun + 96];
        float bias = bK[dcol];
        float4v acc = {bias, bias, bias, bias};
        acc = __builtin_amdgcn_mfma_f32_16x16x32_bf16(a0, b0, acc, 0, 0, 0);
        acc = __builtin_amdgcn_mfma_f32_16x16x32_bf16(a1, b1, acc, 0, 0, 0);
        acc = __builtin_amdgcn_mfma_f32_16x16x32_bf16(a2, b2, acc, 0, 0, 0);
        acc = __builtin_amdgcn_mfma_f32_16x16x32_bf16(a3, b3, acc, 0, 0, 0);
#pragma unroll
        for (int r = 0; r < 4; ++r) {
            int node = nodeb + r;
            if (node < nrow) {
                size_t o = (size_t)(n0 + node) * 64 + dcol;
                float aq = acc[r];
                P1[o].y = expf(tanhf(aq));
                P2[o].y = expf(1.f / (1.f + expf(-aq)));
            }
        }
    }
    __syncthreads();

    // ---- stage WB1|WB2 (cols 0-63 / 64-127) ----
    {
        const float* srcp = (s_ < 2) ? (WB1 + (size_t)r_ * 64 + s_ * 32)
                                     : (WB2 + (size_t)r_ * 64 + (s_ - 2) * 32);
        const float4* s4 = (const float4*)srcp;
        uint4* dst = (uint4*)&Wbf[r_ * 136 + s_ * 32];
        dst[0] = pack8(s4[0], s4[1]); dst[1] = pack8(s4[2], s4[3]);
        dst[2] = pack8(s4[4], s4[5]); dst[3] = pack8(s4[6], s4[7]);
    }
    __syncthreads();

    // ---- WB phase (K=64, input h): B1h -> P1.x, B2h -> P2.x ----
#pragma unroll
    for (int dt = 0; dt < 4; ++dt) {
        const int dcol = (dt << 4) + (lane & 15);
        short8 c0 = *(const short8*)&Wbf[dcol * 136 + krun];
        short8 c1 = *(const short8*)&Wbf[dcol * 136 + krun + 32];
        short8 d0 = *(const short8*)&Wbf[dcol * 136 + krun + 64];
        short8 d1 = *(const short8*)&Wbf[dcol * 136 + krun + 96];
        float bb1 = bB1[dcol], bb2 = bB2[dcol];
        float4v acc1 = {bb1, bb1, bb1, bb1};
        float4v acc2 = {bb2, bb2, bb2, bb2};
        acc1 = __builtin_amdgcn_mfma_f32_16x16x32_bf16(a0, c0, acc1, 0, 0, 0);
        acc1 = __builtin_amdgcn_mfma_f32_16x16x32_bf16(a1, c1, acc1, 0, 0, 0);
        acc2 = __builtin_amdgcn_mfma_f32_16x16x32_bf16(a0, d0, acc2, 0, 0, 0);
        acc2 = __builtin_amdgcn_mfma_f32_16x16x32_bf16(a1, d1, acc2, 0, 0, 0);
#pragma unroll
        for (int r = 0; r < 4; ++r) {
            int node = nodeb + r;
            if (node < nrow) {
                size_t o = (size_t)(n0 + node) * 64 + dcol;
                P1[o].x = acc1[r];
                P2[o].x = acc2[r];
            }
        }
    }
    __syncthreads();

    // ---- stage WV ----
    {
        const float4* s4 = (const float4*)(WV + (size_t)r_ * 128 + s_ * 32);
        uint4* dst = (uint4*)&Wbf[r_ * 136 + s_ * 32];
        dst[0] = pack8(s4[0], s4[1]); dst[1] = pack8(s4[2], s4[3]);
        dst[2] = pack8(s4[4], s4[5]); dst[3] = pack8(s4[6], s4[7]);
    }
    __syncthreads();

    // ---- WV phase (K=128): vh -> Vf LDS stash ----
#pragma unroll
    for (int dt = 0; dt < 4; ++dt) {
        const int dcol = (dt << 4) + (lane & 15);
        short8 b0 = *(const short8*)&Wbf[dcol * 136 + krun];
        short8 b1 = *(const short8*)&Wbf[dcol * 136 + krun + 32];
        short8 b2 = *(const short8*)&Wbf[dcol * 136 + krun + 64];
        short8 b3 = *(const short8*)&Wbf[dcol * 136 + krun + 96];
        float bias = bV[dcol];
        float4v acc = {bias, bias, bias, bias};
        acc = __builtin_amdgcn_mfma_f32_16x16x32_bf16(a0, b0, acc, 0, 0, 0);
        acc = __builtin_amdgcn_mfma_f32_16x16x32_bf16(a1, b1, acc, 0, 0, 0);
        acc = __builtin_amdgcn_mfma_f32_16x16x32_bf16(a2, b2, acc, 0, 0, 0);
        acc = __builtin_amdgcn_mfma_f32_16x16x32_bf16(a3, b3, acc, 0, 0, 0);
#pragma unroll
        for (int r = 0; r < 4; ++r) {
            int node = nodeb + r;
            Vf[node * 68 + dcol] = acc[r];
        }
    }
    __syncthreads();

    // ---- stage WC1|WC2 ----
    {
        const float* srcp = (s_ < 2) ? (WC1 + (size_t)r_ * 64 + s_ * 32)
                                     : (WC2 + (size_t)r_ * 64 + (s_ - 2) * 32);
        const float4* s4 = (const float4*)srcp;
        uint4* dst = (uint4*)&Wbf[r_ * 136 + s_ * 32];
        dst[0] = pack8(s4[0], s4[1]); dst[1] = pack8(s4[2], s4[3]);
        dst[2] = pack8(s4[4], s4[5]); dst[3] = pack8(s4[6], s4[7]);
    }
    __syncthreads();

    // ---- WC phase (K=64, input p): C1p -> C1pOut, pack P3u = {vh, C2p} ----
#pragma unroll
    for (int dt = 0; dt < 4; ++dt) {
        const int dcol = (dt << 4) + (lane & 15);
        short8 c0 = *(const short8*)&Wbf[dcol * 136 + krun];
        short8 c1 = *(const short8*)&Wbf[dcol * 136 + krun + 32];
        short8 d0 = *(const short8*)&Wbf[dcol * 136 + krun + 64];
        short8 d1 = *(const short8*)&Wbf[dcol * 136 + krun + 96];
        float bc1 = bC1[dcol], bc2 = bC2[dcol];
        float4v acc1 = {bc1, bc1, bc1, bc1};
        float4v acc2 = {bc2, bc2, bc2, bc2};
        acc1 = __builtin_amdgcn_mfma_f32_16x16x32_bf16(a2, c0, acc1, 0, 0, 0);
        acc1 = __builtin_amdgcn_mfma_f32_16x16x32_bf16(a3, c1, acc1, 0, 0, 0);
        acc2 = __builtin_amdgcn_mfma_f32_16x16x32_bf16(a2, d0, acc2, 0, 0, 0);
        acc2 = __builtin_amdgcn_mfma_f32_16x16x32_bf16(a3, d1, acc2, 0, 0, 0);
#pragma unroll
        for (int r = 0; r < 4; ++r) {
            int node = nodeb + r;
            if (node < nrow) {
                size_t o = (size_t)(n0 + node) * 64 + dcol;
                C1pOut[o] = acc1[r];
                float vh = Vf[node * 68 + dcol];
                P3u[o] = f2bf_bits(vh) | (f2bf_bits(acc2[r]) << 16);
            }
        }
    }
}

// ---------------------------------------------------------------------------
// dst-bucketing pipeline (int atomics only; verified R4-R13).
// ---------------------------------------------------------------------------
__global__ void hist_kernel(const int* __restrict__ dst, int* __restrict__ cnt, int E) {
    int i = blockIdx.x * blockDim.x + threadIdx.x;
    if (i < E) atomicAdd(&cnt[dst[i]], 1);
}

__global__ void chunksum_kernel(const int* __restrict__ cnt, int* __restrict__ csum, int N) {
    __shared__ int sc[256];
    int t = threadIdx.x;
    int i = blockIdx.x * 256 + t;
    sc[t] = (i < N) ? cnt[i] : 0;
    __syncthreads();
    for (int off = 128; off > 0; off >>= 1) {
        if (t < off) sc[t] += sc[t + off];
        __syncthreads();
    }
    if (t == 0) csum[blockIdx.x] = sc[0];
}

__global__ void scanchunk_kernel(int* __restrict__ csum, int nch) {
    __shared__ int sc[256];
    int t = threadIdx.x;
    int v = (t < nch) ? csum[t] : 0;
    sc[t] = v;
    __syncthreads();
    for (int off = 1; off < 256; off <<= 1) {
        int y = (t >= off) ? sc[t - off] : 0;
        __syncthreads();
        sc[t] += y;
        __syncthreads();
    }
    if (t < nch) csum[t] = sc[t] - v;   // exclusive prefix
}

__global__ void offsets_kernel(const int* __restrict__ cnt, const int* __restrict__ csum,
                               int* __restrict__ offs, int N) {
    __shared__ int sc[256];
    int t = threadIdx.x;
    int i = blockIdx.x * 256 + t;
    int v = (i < N) ? cnt[i] : 0;
    sc[t] = v;
    __syncthreads();
    for (int off = 1; off < 256; off <<= 1) {
        int y = (t >= off) ? sc[t - off] : 0;
        __syncthreads();
        sc[t] += y;
        __syncthreads();
    }
    if (i < N) offs[i] = csum[blockIdx.x] + sc[t] - v;  // global exclusive prefix
}

__global__ void scatter_kernel(const int* __restrict__ dst, int* __restrict__ offs,
                               int* __restrict__ bucket, int E) {
    int i = blockIdx.x * blockDim.x + threadIdx.x;
    if (i < E) {
        int pos = atomicAdd(&offs[dst[i]], 1);
        bucket[pos] = i;
    }
}

// ---------------------------------------------------------------------------
// Kernel B: he_b3 MFMA (verified R13, verbatim).
// ---------------------------------------------------------------------------
__global__ void __launch_bounds__(256, 2)
he_b3_mfma(const float* __restrict__ e,
           const float* __restrict__ WB3, const float* __restrict__ bB3,
           float* __restrict__ he_out, int E)
{
    __shared__ __align__(16) unsigned short Ebf[64 * 72];
    __shared__ __align__(16) unsigned short Wbf[64 * 72];

    const int t = threadIdx.x;
    const int lane = t & 63;
    const int wid = t >> 6;

    const int e0 = blockIdx.x << 6;
    const int nrow = min(64, E - e0);

    {
        const int r = t >> 2, s = t & 3;
        const float4* src = (const float4*)(WB3 + (size_t)r * 64 + s * 16);
        float4 v0 = src[0], v1 = src[1], v2 = src[2], v3 = src[3];
        *(uint4*)(&Wbf[r * 72 + s * 16]) = pack8(v0, v1);
        *(uint4*)(&Wbf[r * 72 + s * 16 + 8]) = pack8(v2, v3);
    }
    {
        const int r = t >> 2, s = t & 3;
        uint4 w0 = make_uint4(0, 0, 0, 0), w1 = make_uint4(0, 0, 0, 0);
        if (r < nrow) {
            const float4* src = (const float4*)(e + (size_t)(e0 + r) * 64 + s * 16);
            float4 v0 = src[0], v1 = src[1], v2 = src[2], v3 = src[3];
            w0 = pack8(v0, v1);
            w1 = pack8(v2, v3);
        }
        *(uint4*)(&Ebf[r * 72 + s * 16]) = w0;
        *(uint4*)(&Ebf[r * 72 + s * 16 + 8]) = w1;
    }
    __syncthreads();

    const int arow = (wid << 4) + (lane & 15);
    const int krun = (lane >> 4) << 3;
    short8 a0 = *(const short8*)(&Ebf[arow * 72 + krun]);
    short8 a1 = *(const short8*)(&Ebf[arow * 72 + krun + 32]);

    const int erow0 = e0 + (wid << 4) + ((lane >> 4) << 2);

#pragma unroll
    for (int dt = 0; dt < 4; ++dt) {
        const int d0 = dt << 4;
        const int dcol = d0 + (lane & 15);
        short8 b0 = *(const short8*)(&Wbf[dcol * 72 + krun]);
        short8 b1 = *(const short8*)(&Wbf[dcol * 72 + krun + 32]);
        float bias = bB3[dcol];
        float4v acc = {bias, bias, bias, bias};
        acc = __builtin_amdgcn_mfma_f32_16x16x32_bf16(a0, b0, acc, 0, 0, 0);
        acc = __builtin_amdgcn_mfma_f32_16x16x32_bf16(a1, b1, acc, 0, 0, 0);
#pragma unroll
        for (int r = 0; r < 4; ++r) {
            int er = erow0 + r;
            if (er < E) he_out[(size_t)er * 64 + dcol] = acc[r];
        }
    }
}

// ---------------------------------------------------------------------------
// Kernel C: MERGED edge finish + gather + finalize (verified R10-R13, verbatim).
// ---------------------------------------------------------------------------
__global__ void __launch_bounds__(256, 3)
edge_gather_finalize(const int* __restrict__ bucket, const int* __restrict__ offs_end,
                     const int* __restrict__ cnt, const int* __restrict__ src,
                     const float2* __restrict__ P1, const float2* __restrict__ P2,
                     const unsigned int* __restrict__ P3u,
                     const float* __restrict__ ln_g, const float* __restrict__ ln_b,
                     float* __restrict__ he_eout, float* __restrict__ h_out,
                     float* __restrict__ p_out, int N)
{
    const int lane = threadIdx.x & 63;
    const int wid = threadIdx.x >> 6;
    const int wpb = blockDim.x >> 6;
    const float lg = ln_g[lane], lb = ln_b[lane];

    for (int n = blockIdx.x * wpb + wid; n < N; n += gridDim.x * wpb) {
        const int end = offs_end[n];
        const int deg = cnt[n];
        const int start = end - deg;
        const size_t o = (size_t)n * D + lane;

        const float2 p2n = P2[o];   // {B2h, sigmaK}, hoisted per node

        float asig = 0.f, av = 0.f, ap = 0.f;

        int k = start;
        for (; k + 3 < end; k += 4) {
            int eid[4], s[4];
#pragma unroll
            for (int i = 0; i < 4; ++i)
                eid[i] = __builtin_amdgcn_readfirstlane(bucket[k + i]);
#pragma unroll
            for (int i = 0; i < 4; ++i)
                s[i] = __builtin_amdgcn_readfirstlane(src[eid[i]]);

            float2 p1[4]; unsigned int p3[4]; float hb[4];
#pragma unroll
            for (int i = 0; i < 4; ++i) {
                p1[i] = P1[(size_t)s[i] * D + lane];        // {B1h, sigmaQ}
                p3[i] = P3u[(size_t)s[i] * D + lane];       // bf16 {vh, C2p}
                hb[i] = he_eout[(size_t)eid[i] * D + lane]; // B3e partial
            }

            float sg[4], pr[4];
#pragma unroll
            for (int i = 0; i < 4; ++i) {
                float he = hb[i] + p1[i].x + p2n.x;
                he_eout[(size_t)eid[i] * D + lane] = fmaxf(he, 0.f);
                sg[i] = 1.f / (1.f + expf(-he));
                pr[i] = p1[i].y * p2n.y;
            }
#pragma unroll
            for (int off = 32; off > 0; off >>= 1) {
#pragma unroll
                for (int i = 0; i < 4; ++i) pr[i] += __shfl_xor(pr[i], off);
            }
#pragma unroll
            for (int i = 0; i < 4; ++i) {
                asig += sg[i];
                av   += sg[i] * pr[i] * bf_lo(p3[i]);
                ap   += sg[i] * bf_hi(p3[i]);
            }
        }
        for (; k < end; ++k) {
            int e0 = __builtin_amdgcn_readfirstlane(bucket[k]);
            int s0 = __builtin_amdgcn_readfirstlane(src[e0]);
            size_t eo0 = (size_t)e0 * D + lane;
            float2 p10 = P1[(size_t)s0 * D + lane];
            unsigned int p30 = P3u[(size_t)s0 * D + lane];
            float he0 = he_eout[eo0] + p10.x + p2n.x;
            he_eout[eo0] = fmaxf(he0, 0.f);
            float sg0 = 1.f / (1.f + expf(-he0));
            float pr0 = p10.y * p2n.y;
#pragma unroll
            for (int off = 32; off > 0; off >>= 1) pr0 += __shfl_xor(pr0, off);
            asig += sg0;
            av   += sg0 * pr0 * bf_lo(p30);
            ap   += sg0 * bf_hi(p30);
        }

        // fused epilogue (verified R9-R13)
        float denom = asig + EPS;
        float vh = bf_lo(P3u[o]);
        float hv = vh + av / denom;
        hv = fmaxf(hv, 0.f);
        float su = hv;
#pragma unroll
        for (int off = 32; off > 0; off >>= 1) su += __shfl_xor(su, off);
        float mu = su * (1.f / 64.f);
        float dv = hv - mu;
        float s2 = dv * dv;
#pragma unroll
        for (int off = 32; off > 0; off >>= 1) s2 += __shfl_xor(s2, off);
        float var = s2 * (1.f / 64.f);
        h_out[o] = dv * rsqrtf(var + LN_EPS) * lg + lb;

        float pv = p_out[o] + ap / denom;   // p_out holds C1p
        p_out[o] = tanhf(pv);
    }
}

extern "C" void kernel_launch(void* const* d_in, const int* in_sizes, int n_in,
                              void* d_out, int out_size, void* d_ws, size_t ws_size,
                              hipStream_t stream) {
    const float* h    = (const float*)d_in[0];
    const float* e    = (const float*)d_in[1];
    const float* p    = (const float*)d_in[2];
    const float* WK   = (const float*)d_in[3];
    const float* bK   = (const float*)d_in[4];
    const float* WV   = (const float*)d_in[5];
    const float* bV   = (const float*)d_in[6];
    const float* WB1  = (const float*)d_in[7];
    const float* bB1  = (const float*)d_in[8];
    const float* WB2  = (const float*)d_in[9];
    const float* bB2  = (const float*)d_in[10];
    const float* WB3  = (const float*)d_in[11];
    const float* bB3  = (const float*)d_in[12];
    const float* WC1  = (const float*)d_in[13];
    const float* bC1  = (const float*)d_in[14];
    const float* WC2  = (const float*)d_in[15];
    const float* bC2  = (const float*)d_in[16];
    const float* ln_g = (const float*)d_in[17];
    const float* ln_b = (const float*)d_in[18];
    const int*   src  = (const int*)d_in[19];
    const int*   dst  = (const int*)d_in[20];

    const int N = in_sizes[0] / D;
    const int E = in_sizes[1] / D;
    const size_t ND = (size_t)N * D;

    float* out   = (float*)d_out;
    float* h_out = out;
    float* e_out = out + ND;                  // B3e partial, then relu(he)
    float* p_out = out + ND + (size_t)E * D;  // C1p, then tanh(...)

    // ws: P1 2ND + P2 2ND (f32) + P3u ND (u32)
    //   + cnt N + offs N + bucket E + csum (int)  ~= 68 MB
    float*        ws    = (float*)d_ws;
    float2*       P1    = (float2*)(ws);                // 2*ND floats
    float2*       P2    = (float2*)(ws + 2 * ND);       // 2*ND floats
    unsigned int* P3u   = (unsigned int*)(ws + 4 * ND); // ND u32
    int*          cnt   = (int*)(ws + 5 * ND);          // N ints
    int*          offs  = cnt + N;                      // N ints
    int*          bucket= offs + N;                     // E ints
    int*          csum  = bucket + E;                   // nchunk ints (<=256)

    const int nchunk = (N + 255) / 256;

    hipMemsetAsync(cnt, 0, (size_t)N * sizeof(int), stream);

    node_linears_mfma<<<(N + 63) / 64, 256, 0, stream>>>(
        h, p, WK, bK, WV, bV, WB1, bB1, WB2, bB2, WC1, bC1, WC2, bC2,
        P1, P2, P3u, p_out, N);

    hist_kernel<<<(E + 255) / 256, 256, 0, stream>>>(dst, cnt, E);
    chunksum_kernel<<<nchunk, 256, 0, stream>>>(cnt, csum, N);
    scanchunk_kernel<<<1, 256, 0, stream>>>(csum, nchunk);
    offsets_kernel<<<nchunk, 256, 0, stream>>>(cnt, csum, offs, N);
    scatter_kernel<<<(E + 255) / 256, 256, 0, stream>>>(dst, offs, bucket, E);

    he_b3_mfma<<<(E + 63) / 64, 256, 0, stream>>>(e, WB3, bB3, e_out, E);

    edge_gather_finalize<<<(N + 3) / 4, 256, 0, stream>>>(
        bucket, offs, cnt, src, P1, P2, P3u, ln_g, ln_b,
        e_out, h_out, p_out, N);
}

// Round 15
// 387.280 us; speedup vs baseline: 15.6950x; 1.0579x over previous
//
#include <hip/hip_runtime.h>
#include <math.h>

#define D 64
#define EPS 1e-12f
#define LN_EPS 1e-5f

typedef __attribute__((ext_vector_type(8))) short short8;
typedef __attribute__((ext_vector_type(4))) float float4v;

// bf16 round-to-nearest-even packing helpers
__device__ __forceinline__ unsigned int f2bf_bits(float x) {
    unsigned int u = __float_as_uint(x);
    return (u + 0x7fffu + ((u >> 16) & 1u)) >> 16;
}
__device__ __forceinline__ float bf_lo(unsigned int p) {  // low 16 bits -> float
    return __uint_as_float(p << 16);
}
__device__ __forceinline__ float bf_hi(unsigned int p) {  // high 16 bits -> float
    return __uint_as_float(p & 0xffff0000u);
}
__device__ __forceinline__ uint4 pack8(float4 u, float4 v) {
    uint4 w;
    w.x = f2bf_bits(u.x) | (f2bf_bits(u.y) << 16);
    w.y = f2bf_bits(u.z) | (f2bf_bits(u.w) << 16);
    w.z = f2bf_bits(v.x) | (f2bf_bits(v.y) << 16);
    w.w = f2bf_bits(v.z) | (f2bf_bits(v.w) << 16);
    return w;
}

// ---------------------------------------------------------------------------
// Kernel A: node linears on the matrix pipe (verified R14). Change vs R14:
// P1 is now bf16-packed u32 {B1h, sigmaQ} (halves EGF's hottest gather).
// sigmaQ is stashed in LDS (SQf) during the WK phase and packed with B1h in
// the WB phase. P2 stays f32x2 (per-node hoist in EGF, not BW-critical).
// ---------------------------------------------------------------------------
__global__ void __launch_bounds__(256, 2)
node_linears_mfma(const float* __restrict__ h, const float* __restrict__ p,
                  const float* __restrict__ WK, const float* __restrict__ bK,
                  const float* __restrict__ WV, const float* __restrict__ bV,
                  const float* __restrict__ WB1, const float* __restrict__ bB1,
                  const float* __restrict__ WB2, const float* __restrict__ bB2,
                  const float* __restrict__ WC1, const float* __restrict__ bC1,
                  const float* __restrict__ WC2, const float* __restrict__ bC2,
                  unsigned int* __restrict__ P1u, float2* __restrict__ P2,
                  unsigned int* __restrict__ P3u, float* __restrict__ C1pOut,
                  int N)
{
    __shared__ __align__(16) unsigned short Xbf[64 * 136];
    __shared__ __align__(16) unsigned short Wbf[64 * 136];
    __shared__ float Vf[64 * 68];
    __shared__ float SQf[64 * 68];

    const int t = threadIdx.x;
    const int lane = t & 63;
    const int wid = t >> 6;
    const int n0 = blockIdx.x << 6;
    const int nrow = min(64, N - n0);

    const int r_ = t >> 2, s_ = t & 3;   // staging: row r_, 32-col segment s_

    // ---- stage X (h|p) and WK ----
    {
        uint4 w0 = {0,0,0,0}, w1 = {0,0,0,0}, w2 = {0,0,0,0}, w3 = {0,0,0,0};
        if (r_ < nrow) {
            const float* srcp = (s_ < 2) ? (h + (size_t)(n0 + r_) * 64 + s_ * 32)
                                         : (p + (size_t)(n0 + r_) * 64 + (s_ - 2) * 32);
            const float4* s4 = (const float4*)srcp;
            w0 = pack8(s4[0], s4[1]); w1 = pack8(s4[2], s4[3]);
            w2 = pack8(s4[4], s4[5]); w3 = pack8(s4[6], s4[7]);
        }
        uint4* dst = (uint4*)&Xbf[r_ * 136 + s_ * 32];
        dst[0] = w0; dst[1] = w1; dst[2] = w2; dst[3] = w3;
    }
    {
        const float4* s4 = (const float4*)(WK + (size_t)r_ * 128 + s_ * 32);
        uint4* dst = (uint4*)&Wbf[r_ * 136 + s_ * 32];
        dst[0] = pack8(s4[0], s4[1]); dst[1] = pack8(s4[2], s4[3]);
        dst[2] = pack8(s4[4], s4[5]); dst[3] = pack8(s4[6], s4[7]);
    }
    __syncthreads();

    // ---- A fragments (held in VGPRs across all phases) ----
    const int arow = (wid << 4) + (lane & 15);
    const int krun = (lane >> 4) << 3;
    const short8 a0 = *(const short8*)&Xbf[arow * 136 + krun];        // h k0..31
    const short8 a1 = *(const short8*)&Xbf[arow * 136 + krun + 32];   // h k32..63
    const short8 a2 = *(const short8*)&Xbf[arow * 136 + krun + 64];   // p k0..31
    const short8 a3 = *(const short8*)&Xbf[arow * 136 + krun + 96];   // p k32..63
    const int nodeb = (wid << 4) + ((lane >> 4) << 2);

    // ---- WK phase (K=128): sigmaQ -> SQf (LDS), sigmaK -> P2.y ----
#pragma unroll
    for (int dt = 0; dt < 4; ++dt) {
        const int dcol = (dt << 4) + (lane & 15);
        short8 b0 = *(const short8*)&Wbf[dcol * 136 + krun];
        short8 b1 = *(const short8*)&Wbf[dcol * 136 + krun + 32];
        short8 b2 = *(const short8*)&Wbf[dcol * 136 + krun + 64];
        short8 b3 = *(const short8*)&Wbf[dcol * 136 + krun + 96];
        float bias = bK[dcol];
        float4v acc = {bias, bias, bias, bias};
        acc = __builtin_amdgcn_mfma_f32_16x16x32_bf16(a0, b0, acc, 0, 0, 0);
        acc = __builtin_amdgcn_mfma_f32_16x16x32_bf16(a1, b1, acc, 0, 0, 0);
        acc = __builtin_amdgcn_mfma_f32_16x16x32_bf16(a2, b2, acc, 0, 0, 0);
        acc = __builtin_amdgcn_mfma_f32_16x16x32_bf16(a3, b3, acc, 0, 0, 0);
#pragma unroll
        for (int r = 0; r < 4; ++r) {
            int node = nodeb + r;
            float aq = acc[r];
            SQf[node * 68 + dcol] = expf(tanhf(aq));
            if (node < nrow) {
                size_t o = (size_t)(n0 + node) * 64 + dcol;
                P2[o].y = expf(1.f / (1.f + expf(-aq)));
            }
        }
    }
    __syncthreads();

    // ---- stage WB1|WB2 ----
    {
        const float* srcp = (s_ < 2) ? (WB1 + (size_t)r_ * 64 + s_ * 32)
                                     : (WB2 + (size_t)r_ * 64 + (s_ - 2) * 32);
        const float4* s4 = (const float4*)srcp;
        uint4* dst = (uint4*)&Wbf[r_ * 136 + s_ * 32];
        dst[0] = pack8(s4[0], s4[1]); dst[1] = pack8(s4[2], s4[3]);
        dst[2] = pack8(s4[4], s4[5]); dst[3] = pack8(s4[6], s4[7]);
    }
    __syncthreads();

    // ---- WB phase (K=64, input h): P1u = {B1h, sigmaQ}, B2h -> P2.x ----
#pragma unroll
    for (int dt = 0; dt < 4; ++dt) {
        const int dcol = (dt << 4) + (lane & 15);
        short8 c0 = *(const short8*)&Wbf[dcol * 136 + krun];
        short8 c1 = *(const short8*)&Wbf[dcol * 136 + krun + 32];
        short8 d0 = *(const short8*)&Wbf[dcol * 136 + krun + 64];
        short8 d1 = *(const short8*)&Wbf[dcol * 136 + krun + 96];
        float bb1 = bB1[dcol], bb2 = bB2[dcol];
        float4v acc1 = {bb1, bb1, bb1, bb1};
        float4v acc2 = {bb2, bb2, bb2, bb2};
        acc1 = __builtin_amdgcn_mfma_f32_16x16x32_bf16(a0, c0, acc1, 0, 0, 0);
        acc1 = __builtin_amdgcn_mfma_f32_16x16x32_bf16(a1, c1, acc1, 0, 0, 0);
        acc2 = __builtin_amdgcn_mfma_f32_16x16x32_bf16(a0, d0, acc2, 0, 0, 0);
        acc2 = __builtin_amdgcn_mfma_f32_16x16x32_bf16(a1, d1, acc2, 0, 0, 0);
#pragma unroll
        for (int r = 0; r < 4; ++r) {
            int node = nodeb + r;
            if (node < nrow) {
                size_t o = (size_t)(n0 + node) * 64 + dcol;
                P1u[o] = f2bf_bits(acc1[r]) | (f2bf_bits(SQf[node * 68 + dcol]) << 16);
                P2[o].x = acc2[r];
            }
        }
    }
    __syncthreads();

    // ---- stage WV ----
    {
        const float4* s4 = (const float4*)(WV + (size_t)r_ * 128 + s_ * 32);
        uint4* dst = (uint4*)&Wbf[r_ * 136 + s_ * 32];
        dst[0] = pack8(s4[0], s4[1]); dst[1] = pack8(s4[2], s4[3]);
        dst[2] = pack8(s4[4], s4[5]); dst[3] = pack8(s4[6], s4[7]);
    }
    __syncthreads();

    // ---- WV phase (K=128): vh -> Vf LDS stash ----
#pragma unroll
    for (int dt = 0; dt < 4; ++dt) {
        const int dcol = (dt << 4) + (lane & 15);
        short8 b0 = *(const short8*)&Wbf[dcol * 136 + krun];
        short8 b1 = *(const short8*)&Wbf[dcol * 136 + krun + 32];
        short8 b2 = *(const short8*)&Wbf[dcol * 136 + krun + 64];
        short8 b3 = *(const short8*)&Wbf[dcol * 136 + krun + 96];
        float bias = bV[dcol];
        float4v acc = {bias, bias, bias, bias};
        acc = __builtin_amdgcn_mfma_f32_16x16x32_bf16(a0, b0, acc, 0, 0, 0);
        acc = __builtin_amdgcn_mfma_f32_16x16x32_bf16(a1, b1, acc, 0, 0, 0);
        acc = __builtin_amdgcn_mfma_f32_16x16x32_bf16(a2, b2, acc, 0, 0, 0);
        acc = __builtin_amdgcn_mfma_f32_16x16x32_bf16(a3, b3, acc, 0, 0, 0);
#pragma unroll
        for (int r = 0; r < 4; ++r) {
            int node = nodeb + r;
            Vf[node * 68 + dcol] = acc[r];
        }
    }
    __syncthreads();

    // ---- stage WC1|WC2 ----
    {
        const float* srcp = (s_ < 2) ? (WC1 + (size_t)r_ * 64 + s_ * 32)
                                     : (WC2 + (size_t)r_ * 64 + (s_ - 2) * 32);
        const float4* s4 = (const float4*)srcp;
        uint4* dst = (uint4*)&Wbf[r_ * 136 + s_ * 32];
        dst[0] = pack8(s4[0], s4[1]); dst[1] = pack8(s4[2], s4[3]);
        dst[2] = pack8(s4[4], s4[5]); dst[3] = pack8(s4[6], s4[7]);
    }
    __syncthreads();

    // ---- WC phase (K=64, input p): C1p -> C1pOut, pack P3u = {vh, C2p} ----
#pragma unroll
    for (int dt = 0; dt < 4; ++dt) {
        const int dcol = (dt << 4) + (lane & 15);
        short8 c0 = *(const short8*)&Wbf[dcol * 136 + krun];
        short8 c1 = *(const short8*)&Wbf[dcol * 136 + krun + 32];
        short8 d0 = *(const short8*)&Wbf[dcol * 136 + krun + 64];
        short8 d1 = *(const short8*)&Wbf[dcol * 136 + krun + 96];
        float bc1 = bC1[dcol], bc2 = bC2[dcol];
        float4v acc1 = {bc1, bc1, bc1, bc1};
        float4v acc2 = {bc2, bc2, bc2, bc2};
        acc1 = __builtin_amdgcn_mfma_f32_16x16x32_bf16(a2, c0, acc1, 0, 0, 0);
        acc1 = __builtin_amdgcn_mfma_f32_16x16x32_bf16(a3, c1, acc1, 0, 0, 0);
        acc2 = __builtin_amdgcn_mfma_f32_16x16x32_bf16(a2, d0, acc2, 0, 0, 0);
        acc2 = __builtin_amdgcn_mfma_f32_16x16x32_bf16(a3, d1, acc2, 0, 0, 0);
#pragma unroll
        for (int r = 0; r < 4; ++r) {
            int node = nodeb + r;
            if (node < nrow) {
                size_t o = (size_t)(n0 + node) * 64 + dcol;
                C1pOut[o] = acc1[r];
                float vh = Vf[node * 68 + dcol];
                P3u[o] = f2bf_bits(vh) | (f2bf_bits(acc2[r]) << 16);
            }
        }
    }
}

// ---------------------------------------------------------------------------
// dst-bucketing pipeline (int atomics only; verified R4-R14).
// ---------------------------------------------------------------------------
__global__ void hist_kernel(const int* __restrict__ dst, int* __restrict__ cnt, int E) {
    int i = blockIdx.x * blockDim.x + threadIdx.x;
    if (i < E) atomicAdd(&cnt[dst[i]], 1);
}

__global__ void chunksum_kernel(const int* __restrict__ cnt, int* __restrict__ csum, int N) {
    __shared__ int sc[256];
    int t = threadIdx.x;
    int i = blockIdx.x * 256 + t;
    sc[t] = (i < N) ? cnt[i] : 0;
    __syncthreads();
    for (int off = 128; off > 0; off >>= 1) {
        if (t < off) sc[t] += sc[t + off];
        __syncthreads();
    }
    if (t == 0) csum[blockIdx.x] = sc[0];
}

__global__ void scanchunk_kernel(int* __restrict__ csum, int nch) {
    __shared__ int sc[256];
    int t = threadIdx.x;
    int v = (t < nch) ? csum[t] : 0;
    sc[t] = v;
    __syncthreads();
    for (int off = 1; off < 256; off <<= 1) {
        int y = (t >= off) ? sc[t - off] : 0;
        __syncthreads();
        sc[t] += y;
        __syncthreads();
    }
    if (t < nch) csum[t] = sc[t] - v;   // exclusive prefix
}

__global__ void offsets_kernel(const int* __restrict__ cnt, const int* __restrict__ csum,
                               int* __restrict__ offs, int N) {
    __shared__ int sc[256];
    int t = threadIdx.x;
    int i = blockIdx.x * 256 + t;
    int v = (i < N) ? cnt[i] : 0;
    sc[t] = v;
    __syncthreads();
    for (int off = 1; off < 256; off <<= 1) {
        int y = (t >= off) ? sc[t - off] : 0;
        __syncthreads();
        sc[t] += y;
        __syncthreads();
    }
    if (i < N) offs[i] = csum[blockIdx.x] + sc[t] - v;  // global exclusive prefix
}

__global__ void scatter_kernel(const int* __restrict__ dst, int* __restrict__ offs,
                               int* __restrict__ bucket, int E) {
    int i = blockIdx.x * blockDim.x + threadIdx.x;
    if (i < E) {
        int pos = atomicAdd(&offs[dst[i]], 1);
        bucket[pos] = i;
    }
}

// ---------------------------------------------------------------------------
// Kernel B: he_b3 MFMA (verified R13/R14). Only change: (256,4) -- LDS is
// 18.4KB/block so 4 blocks/CU fit; R13 ran just 2 (launch_bounds-capped).
// ---------------------------------------------------------------------------
__global__ void __launch_bounds__(256, 4)
he_b3_mfma(const float* __restrict__ e,
           const float* __restrict__ WB3, const float* __restrict__ bB3,
           float* __restrict__ he_out, int E)
{
    __shared__ __align__(16) unsigned short Ebf[64 * 72];
    __shared__ __align__(16) unsigned short Wbf[64 * 72];

    const int t = threadIdx.x;
    const int lane = t & 63;
    const int wid = t >> 6;

    const int e0 = blockIdx.x << 6;
    const int nrow = min(64, E - e0);

    {
        const int r = t >> 2, s = t & 3;
        const float4* src = (const float4*)(WB3 + (size_t)r * 64 + s * 16);
        float4 v0 = src[0], v1 = src[1], v2 = src[2], v3 = src[3];
        *(uint4*)(&Wbf[r * 72 + s * 16]) = pack8(v0, v1);
        *(uint4*)(&Wbf[r * 72 + s * 16 + 8]) = pack8(v2, v3);
    }
    {
        const int r = t >> 2, s = t & 3;
        uint4 w0 = make_uint4(0, 0, 0, 0), w1 = make_uint4(0, 0, 0, 0);
        if (r < nrow) {
            const float4* src = (const float4*)(e + (size_t)(e0 + r) * 64 + s * 16);
            float4 v0 = src[0], v1 = src[1], v2 = src[2], v3 = src[3];
            w0 = pack8(v0, v1);
            w1 = pack8(v2, v3);
        }
        *(uint4*)(&Ebf[r * 72 + s * 16]) = w0;
        *(uint4*)(&Ebf[r * 72 + s * 16 + 8]) = w1;
    }
    __syncthreads();

    const int arow = (wid << 4) + (lane & 15);
    const int krun = (lane >> 4) << 3;
    short8 a0 = *(const short8*)(&Ebf[arow * 72 + krun]);
    short8 a1 = *(const short8*)(&Ebf[arow * 72 + krun + 32]);

    const int erow0 = e0 + (wid << 4) + ((lane >> 4) << 2);

#pragma unroll
    for (int dt = 0; dt < 4; ++dt) {
        const int d0 = dt << 4;
        const int dcol = d0 + (lane & 15);
        short8 b0 = *(const short8*)(&Wbf[dcol * 72 + krun]);
        short8 b1 = *(const short8*)(&Wbf[dcol * 72 + krun + 32]);
        float bias = bB3[dcol];
        float4v acc = {bias, bias, bias, bias};
        acc = __builtin_amdgcn_mfma_f32_16x16x32_bf16(a0, b0, acc, 0, 0, 0);
        acc = __builtin_amdgcn_mfma_f32_16x16x32_bf16(a1, b1, acc, 0, 0, 0);
#pragma unroll
        for (int r = 0; r < 4; ++r) {
            int er = erow0 + r;
            if (er < E) he_out[(size_t)er * 64 + dcol] = acc[r];
        }
    }
}

// ---------------------------------------------------------------------------
// Kernel C: MERGED edge finish + gather + finalize (verified R10-R14).
// Changes: P1 gather is now bf16-packed u32; __launch_bounds__(256,8)
// (VGPR=28 measured at (256,3) -- far under the 64 cap, so no spill risk;
// more waves = more outstanding gather misses).
// ---------------------------------------------------------------------------
__global__ void __launch_bounds__(256, 8)
edge_gather_finalize(const int* __restrict__ bucket, const int* __restrict__ offs_end,
                     const int* __restrict__ cnt, const int* __restrict__ src,
                     const unsigned int* __restrict__ P1u, const float2* __restrict__ P2,
                     const unsigned int* __restrict__ P3u,
                     const float* __restrict__ ln_g, const float* __restrict__ ln_b,
                     float* __restrict__ he_eout, float* __restrict__ h_out,
                     float* __restrict__ p_out, int N)
{
    const int lane = threadIdx.x & 63;
    const int wid = threadIdx.x >> 6;
    const int wpb = blockDim.x >> 6;
    const float lg = ln_g[lane], lb = ln_b[lane];

    for (int n = blockIdx.x * wpb + wid; n < N; n += gridDim.x * wpb) {
        const int end = offs_end[n];
        const int deg = cnt[n];
        const int start = end - deg;
        const size_t o = (size_t)n * D + lane;

        const float2 p2n = P2[o];   // {B2h, sigmaK}, hoisted per node

        float asig = 0.f, av = 0.f, ap = 0.f;

        int k = start;
        for (; k + 3 < end; k += 4) {
            int eid[4], s[4];
#pragma unroll
            for (int i = 0; i < 4; ++i)
                eid[i] = __builtin_amdgcn_readfirstlane(bucket[k + i]);
#pragma unroll
            for (int i = 0; i < 4; ++i)
                s[i] = __builtin_amdgcn_readfirstlane(src[eid[i]]);

            unsigned int p1[4], p3[4]; float hb[4];
#pragma unroll
            for (int i = 0; i < 4; ++i) {
                p1[i] = P1u[(size_t)s[i] * D + lane];       // bf16 {B1h, sigmaQ}
                p3[i] = P3u[(size_t)s[i] * D + lane];       // bf16 {vh, C2p}
                hb[i] = he_eout[(size_t)eid[i] * D + lane]; // B3e partial
            }

            float sg[4], pr[4];
#pragma unroll
            for (int i = 0; i < 4; ++i) {
                float he = hb[i] + bf_lo(p1[i]) + p2n.x;
                he_eout[(size_t)eid[i] * D + lane] = fmaxf(he, 0.f);
                sg[i] = 1.f / (1.f + expf(-he));
                pr[i] = bf_hi(p1[i]) * p2n.y;
            }
#pragma unroll
            for (int off = 32; off > 0; off >>= 1) {
#pragma unroll
                for (int i = 0; i < 4; ++i) pr[i] += __shfl_xor(pr[i], off);
            }
#pragma unroll
            for (int i = 0; i < 4; ++i) {
                asig += sg[i];
                av   += sg[i] * pr[i] * bf_lo(p3[i]);
                ap   += sg[i] * bf_hi(p3[i]);
            }
        }
        for (; k < end; ++k) {
            int e0 = __builtin_amdgcn_readfirstlane(bucket[k]);
            int s0 = __builtin_amdgcn_readfirstlane(src[e0]);
            size_t eo0 = (size_t)e0 * D + lane;
            unsigned int p10 = P1u[(size_t)s0 * D + lane];
            unsigned int p30 = P3u[(size_t)s0 * D + lane];
            float he0 = he_eout[eo0] + bf_lo(p10) + p2n.x;
            he_eout[eo0] = fmaxf(he0, 0.f);
            float sg0 = 1.f / (1.f + expf(-he0));
            float pr0 = bf_hi(p10) * p2n.y;
#pragma unroll
            for (int off = 32; off > 0; off >>= 1) pr0 += __shfl_xor(pr0, off);
            asig += sg0;
            av   += sg0 * pr0 * bf_lo(p30);
            ap   += sg0 * bf_hi(p30);
        }

        // fused epilogue (verified R9-R14)
        float denom = asig + EPS;
        float vh = bf_lo(P3u[o]);
        float hv = vh + av / denom;
        hv = fmaxf(hv, 0.f);
        float su = hv;
#pragma unroll
        for (int off = 32; off > 0; off >>= 1) su += __shfl_xor(su, off);
        float mu = su * (1.f / 64.f);
        float dv = hv - mu;
        float s2 = dv * dv;
#pragma unroll
        for (int off = 32; off > 0; off >>= 1) s2 += __shfl_xor(s2, off);
        float var = s2 * (1.f / 64.f);
        h_out[o] = dv * rsqrtf(var + LN_EPS) * lg + lb;

        float pv = p_out[o] + ap / denom;   // p_out holds C1p
        p_out[o] = tanhf(pv);
    }
}

extern "C" void kernel_launch(void* const* d_in, const int* in_sizes, int n_in,
                              void* d_out, int out_size, void* d_ws, size_t ws_size,
                              hipStream_t stream) {
    const float* h    = (const float*)d_in[0];
    const float* e    = (const float*)d_in[1];
    const float* p    = (const float*)d_in[2];
    const float* WK   = (const float*)d_in[3];
    const float* bK   = (const float*)d_in[4];
    const float* WV   = (const float*)d_in[5];
    const float* bV   = (const float*)d_in[6];
    const float* WB1  = (const float*)d_in[7];
    const float* bB1  = (const float*)d_in[8];
    const float* WB2  = (const float*)d_in[9];
    const float* bB2  = (const float*)d_in[10];
    const float* WB3  = (const float*)d_in[11];
    const float* bB3  = (const float*)d_in[12];
    const float* WC1  = (const float*)d_in[13];
    const float* bC1  = (const float*)d_in[14];
    const float* WC2  = (const float*)d_in[15];
    const float* bC2  = (const float*)d_in[16];
    const float* ln_g = (const float*)d_in[17];
    const float* ln_b = (const float*)d_in[18];
    const int*   src  = (const int*)d_in[19];
    const int*   dst  = (const int*)d_in[20];

    const int N = in_sizes[0] / D;
    const int E = in_sizes[1] / D;
    const size_t ND = (size_t)N * D;

    float* out   = (float*)d_out;
    float* h_out = out;
    float* e_out = out + ND;                  // B3e partial, then relu(he)
    float* p_out = out + ND + (size_t)E * D;  // C1p, then tanh(...)

    // ws: P1u ND u32 + P2 2ND f32 + P3u ND u32
    //   + cnt N + offs N + bucket E + csum (int)  ~= 55 MB
    float*        ws    = (float*)d_ws;
    unsigned int* P1u   = (unsigned int*)(ws);          // ND u32
    float2*       P2    = (float2*)(ws + ND);           // 2*ND floats
    unsigned int* P3u   = (unsigned int*)(ws + 3 * ND); // ND u32
    int*          cnt   = (int*)(ws + 4 * ND);          // N ints
    int*          offs  = cnt + N;                      // N ints
    int*          bucket= offs + N;                     // E ints
    int*          csum  = bucket + E;                   // nchunk ints (<=256)

    const int nchunk = (N + 255) / 256;

    hipMemsetAsync(cnt, 0, (size_t)N * sizeof(int), stream);

    node_linears_mfma<<<(N + 63) / 64, 256, 0, stream>>>(
        h, p, WK, bK, WV, bV, WB1, bB1, WB2, bB2, WC1, bC1, WC2, bC2,
        P1u, P2, P3u, p_out, N);

    hist_kernel<<<(E + 255) / 256, 256, 0, stream>>>(dst, cnt, E);
    chunksum_kernel<<<nchunk, 256, 0, stream>>>(cnt, csum, N);
    scanchunk_kernel<<<1, 256, 0, stream>>>(csum, nchunk);
    offsets_kernel<<<nchunk, 256, 0, stream>>>(cnt, csum, offs, N);
    scatter_kernel<<<(E + 255) / 256, 256, 0, stream>>>(dst, offs, bucket, E);

    he_b3_mfma<<<(E + 63) / 64, 256, 0, stream>>>(e, WB3, bB3, e_out, E);

    edge_gather_finalize<<<(N + 3) / 4, 256, 0, stream>>>(
        bucket, offs, cnt, src, P1u, P2, P3u, ln_g, ln_b,
        e_out, h_out, p_out, N);
}

// Round 16
// 367.482 us; speedup vs baseline: 16.5405x; 1.0539x over previous
//
#include <hip/hip_runtime.h>
#include <math.h>

#define D 64
#define EPS 1e-12f
#define LN_EPS 1e-5f

typedef __attribute__((ext_vector_type(8))) short short8;
typedef __attribute__((ext_vector_type(4))) float float4v;

// bf16 round-to-nearest-even packing helpers
__device__ __forceinline__ unsigned int f2bf_bits(float x) {
    unsigned int u = __float_as_uint(x);
    return (u + 0x7fffu + ((u >> 16) & 1u)) >> 16;
}
__device__ __forceinline__ float bf_lo(unsigned int p) {  // low 16 bits -> float
    return __uint_as_float(p << 16);
}
__device__ __forceinline__ float bf_hi(unsigned int p) {  // high 16 bits -> float
    return __uint_as_float(p & 0xffff0000u);
}
__device__ __forceinline__ float bf_u16(unsigned short u) {
    return __uint_as_float(((unsigned int)u) << 16);
}
__device__ __forceinline__ uint4 pack8(float4 u, float4 v) {
    uint4 w;
    w.x = f2bf_bits(u.x) | (f2bf_bits(u.y) << 16);
    w.y = f2bf_bits(u.z) | (f2bf_bits(u.w) << 16);
    w.z = f2bf_bits(v.x) | (f2bf_bits(v.y) << 16);
    w.w = f2bf_bits(v.z) | (f2bf_bits(v.w) << 16);
    return w;
}

// ---------------------------------------------------------------------------
// Kernel A: node linears on the matrix pipe (verified R14/R15, verbatim).
// P1u = bf16 {B1h, sigmaQ}; P2 = f32 {B2h, sigmaK}; P3u = bf16 {vh, C2p};
// C1p -> p_out region.
// ---------------------------------------------------------------------------
__global__ void __launch_bounds__(256, 2)
node_linears_mfma(const float* __restrict__ h, const float* __restrict__ p,
                  const float* __restrict__ WK, const float* __restrict__ bK,
                  const float* __restrict__ WV, const float* __restrict__ bV,
                  const float* __restrict__ WB1, const float* __restrict__ bB1,
                  const float* __restrict__ WB2, const float* __restrict__ bB2,
                  const float* __restrict__ WC1, const float* __restrict__ bC1,
                  const float* __restrict__ WC2, const float* __restrict__ bC2,
                  unsigned int* __restrict__ P1u, float2* __restrict__ P2,
                  unsigned int* __restrict__ P3u, float* __restrict__ C1pOut,
                  int N)
{
    __shared__ __align__(16) unsigned short Xbf[64 * 136];
    __shared__ __align__(16) unsigned short Wbf[64 * 136];
    __shared__ float Vf[64 * 68];
    __shared__ float SQf[64 * 68];

    const int t = threadIdx.x;
    const int lane = t & 63;
    const int wid = t >> 6;
    const int n0 = blockIdx.x << 6;
    const int nrow = min(64, N - n0);

    const int r_ = t >> 2, s_ = t & 3;   // staging: row r_, 32-col segment s_

    // ---- stage X (h|p) and WK ----
    {
        uint4 w0 = {0,0,0,0}, w1 = {0,0,0,0}, w2 = {0,0,0,0}, w3 = {0,0,0,0};
        if (r_ < nrow) {
            const float* srcp = (s_ < 2) ? (h + (size_t)(n0 + r_) * 64 + s_ * 32)
                                         : (p + (size_t)(n0 + r_) * 64 + (s_ - 2) * 32);
            const float4* s4 = (const float4*)srcp;
            w0 = pack8(s4[0], s4[1]); w1 = pack8(s4[2], s4[3]);
            w2 = pack8(s4[4], s4[5]); w3 = pack8(s4[6], s4[7]);
        }
        uint4* dst = (uint4*)&Xbf[r_ * 136 + s_ * 32];
        dst[0] = w0; dst[1] = w1; dst[2] = w2; dst[3] = w3;
    }
    {
        const float4* s4 = (const float4*)(WK + (size_t)r_ * 128 + s_ * 32);
        uint4* dst = (uint4*)&Wbf[r_ * 136 + s_ * 32];
        dst[0] = pack8(s4[0], s4[1]); dst[1] = pack8(s4[2], s4[3]);
        dst[2] = pack8(s4[4], s4[5]); dst[3] = pack8(s4[6], s4[7]);
    }
    __syncthreads();

    // ---- A fragments (held in VGPRs across all phases) ----
    const int arow = (wid << 4) + (lane & 15);
    const int krun = (lane >> 4) << 3;
    const short8 a0 = *(const short8*)&Xbf[arow * 136 + krun];        // h k0..31
    const short8 a1 = *(const short8*)&Xbf[arow * 136 + krun + 32];   // h k32..63
    const short8 a2 = *(const short8*)&Xbf[arow * 136 + krun + 64];   // p k0..31
    const short8 a3 = *(const short8*)&Xbf[arow * 136 + krun + 96];   // p k32..63
    const int nodeb = (wid << 4) + ((lane >> 4) << 2);

    // ---- WK phase (K=128): sigmaQ -> SQf (LDS), sigmaK -> P2.y ----
#pragma unroll
    for (int dt = 0; dt < 4; ++dt) {
        const int dcol = (dt << 4) + (lane & 15);
        short8 b0 = *(const short8*)&Wbf[dcol * 136 + krun];
        short8 b1 = *(const short8*)&Wbf[dcol * 136 + krun + 32];
        short8 b2 = *(const short8*)&Wbf[dcol * 136 + krun + 64];
        short8 b3 = *(const short8*)&Wbf[dcol * 136 + krun + 96];
        float bias = bK[dcol];
        float4v acc = {bias, bias, bias, bias};
        acc = __builtin_amdgcn_mfma_f32_16x16x32_bf16(a0, b0, acc, 0, 0, 0);
        acc = __builtin_amdgcn_mfma_f32_16x16x32_bf16(a1, b1, acc, 0, 0, 0);
        acc = __builtin_amdgcn_mfma_f32_16x16x32_bf16(a2, b2, acc, 0, 0, 0);
        acc = __builtin_amdgcn_mfma_f32_16x16x32_bf16(a3, b3, acc, 0, 0, 0);
#pragma unroll
        for (int r = 0; r < 4; ++r) {
            int node = nodeb + r;
            float aq = acc[r];
            SQf[node * 68 + dcol] = expf(tanhf(aq));
            if (node < nrow) {
                size_t o = (size_t)(n0 + node) * 64 + dcol;
                P2[o].y = expf(1.f / (1.f + expf(-aq)));
            }
        }
    }
    __syncthreads();

    // ---- stage WB1|WB2 ----
    {
        const float* srcp = (s_ < 2) ? (WB1 + (size_t)r_ * 64 + s_ * 32)
                                     : (WB2 + (size_t)r_ * 64 + (s_ - 2) * 32);
        const float4* s4 = (const float4*)srcp;
        uint4* dst = (uint4*)&Wbf[r_ * 136 + s_ * 32];
        dst[0] = pack8(s4[0], s4[1]); dst[1] = pack8(s4[2], s4[3]);
        dst[2] = pack8(s4[4], s4[5]); dst[3] = pack8(s4[6], s4[7]);
    }
    __syncthreads();

    // ---- WB phase (K=64, input h): P1u = {B1h, sigmaQ}, B2h -> P2.x ----
#pragma unroll
    for (int dt = 0; dt < 4; ++dt) {
        const int dcol = (dt << 4) + (lane & 15);
        short8 c0 = *(const short8*)&Wbf[dcol * 136 + krun];
        short8 c1 = *(const short8*)&Wbf[dcol * 136 + krun + 32];
        short8 d0 = *(const short8*)&Wbf[dcol * 136 + krun + 64];
        short8 d1 = *(const short8*)&Wbf[dcol * 136 + krun + 96];
        float bb1 = bB1[dcol], bb2 = bB2[dcol];
        float4v acc1 = {bb1, bb1, bb1, bb1};
        float4v acc2 = {bb2, bb2, bb2, bb2};
        acc1 = __builtin_amdgcn_mfma_f32_16x16x32_bf16(a0, c0, acc1, 0, 0, 0);
        acc1 = __builtin_amdgcn_mfma_f32_16x16x32_bf16(a1, c1, acc1, 0, 0, 0);
        acc2 = __builtin_amdgcn_mfma_f32_16x16x32_bf16(a0, d0, acc2, 0, 0, 0);
        acc2 = __builtin_amdgcn_mfma_f32_16x16x32_bf16(a1, d1, acc2, 0, 0, 0);
#pragma unroll
        for (int r = 0; r < 4; ++r) {
            int node = nodeb + r;
            if (node < nrow) {
                size_t o = (size_t)(n0 + node) * 64 + dcol;
                P1u[o] = f2bf_bits(acc1[r]) | (f2bf_bits(SQf[node * 68 + dcol]) << 16);
                P2[o].x = acc2[r];
            }
        }
    }
    __syncthreads();

    // ---- stage WV ----
    {
        const float4* s4 = (const float4*)(WV + (size_t)r_ * 128 + s_ * 32);
        uint4* dst = (uint4*)&Wbf[r_ * 136 + s_ * 32];
        dst[0] = pack8(s4[0], s4[1]); dst[1] = pack8(s4[2], s4[3]);
        dst[2] = pack8(s4[4], s4[5]); dst[3] = pack8(s4[6], s4[7]);
    }
    __syncthreads();

    // ---- WV phase (K=128): vh -> Vf LDS stash ----
#pragma unroll
    for (int dt = 0; dt < 4; ++dt) {
        const int dcol = (dt << 4) + (lane & 15);
        short8 b0 = *(const short8*)&Wbf[dcol * 136 + krun];
        short8 b1 = *(const short8*)&Wbf[dcol * 136 + krun + 32];
        short8 b2 = *(const short8*)&Wbf[dcol * 136 + krun + 64];
        short8 b3 = *(const short8*)&Wbf[dcol * 136 + krun + 96];
        float bias = bV[dcol];
        float4v acc = {bias, bias, bias, bias};
        acc = __builtin_amdgcn_mfma_f32_16x16x32_bf16(a0, b0, acc, 0, 0, 0);
        acc = __builtin_amdgcn_mfma_f32_16x16x32_bf16(a1, b1, acc, 0, 0, 0);
        acc = __builtin_amdgcn_mfma_f32_16x16x32_bf16(a2, b2, acc, 0, 0, 0);
        acc = __builtin_amdgcn_mfma_f32_16x16x32_bf16(a3, b3, acc, 0, 0, 0);
#pragma unroll
        for (int r = 0; r < 4; ++r) {
            int node = nodeb + r;
            Vf[node * 68 + dcol] = acc[r];
        }
    }
    __syncthreads();

    // ---- stage WC1|WC2 ----
    {
        const float* srcp = (s_ < 2) ? (WC1 + (size_t)r_ * 64 + s_ * 32)
                                     : (WC2 + (size_t)r_ * 64 + (s_ - 2) * 32);
        const float4* s4 = (const float4*)srcp;
        uint4* dst = (uint4*)&Wbf[r_ * 136 + s_ * 32];
        dst[0] = pack8(s4[0], s4[1]); dst[1] = pack8(s4[2], s4[3]);
        dst[2] = pack8(s4[4], s4[5]); dst[3] = pack8(s4[6], s4[7]);
    }
    __syncthreads();

    // ---- WC phase (K=64, input p): C1p -> C1pOut, pack P3u = {vh, C2p} ----
#pragma unroll
    for (int dt = 0; dt < 4; ++dt) {
        const int dcol = (dt << 4) + (lane & 15);
        short8 c0 = *(const short8*)&Wbf[dcol * 136 + krun];
        short8 c1 = *(const short8*)&Wbf[dcol * 136 + krun + 32];
        short8 d0 = *(const short8*)&Wbf[dcol * 136 + krun + 64];
        short8 d1 = *(const short8*)&Wbf[dcol * 136 + krun + 96];
        float bc1 = bC1[dcol], bc2 = bC2[dcol];
        float4v acc1 = {bc1, bc1, bc1, bc1};
        float4v acc2 = {bc2, bc2, bc2, bc2};
        acc1 = __builtin_amdgcn_mfma_f32_16x16x32_bf16(a2, c0, acc1, 0, 0, 0);
        acc1 = __builtin_amdgcn_mfma_f32_16x16x32_bf16(a3, c1, acc1, 0, 0, 0);
        acc2 = __builtin_amdgcn_mfma_f32_16x16x32_bf16(a2, d0, acc2, 0, 0, 0);
        acc2 = __builtin_amdgcn_mfma_f32_16x16x32_bf16(a3, d1, acc2, 0, 0, 0);
#pragma unroll
        for (int r = 0; r < 4; ++r) {
            int node = nodeb + r;
            if (node < nrow) {
                size_t o = (size_t)(n0 + node) * 64 + dcol;
                C1pOut[o] = acc1[r];
                float vh = Vf[node * 68 + dcol];
                P3u[o] = f2bf_bits(vh) | (f2bf_bits(acc2[r]) << 16);
            }
        }
    }
}

// ---------------------------------------------------------------------------
// dst-bucketing pipeline (int atomics only; verified R4-R15).
// ---------------------------------------------------------------------------
__global__ void hist_kernel(const int* __restrict__ dst, int* __restrict__ cnt, int E) {
    int i = blockIdx.x * blockDim.x + threadIdx.x;
    if (i < E) atomicAdd(&cnt[dst[i]], 1);
}

__global__ void chunksum_kernel(const int* __restrict__ cnt, int* __restrict__ csum, int N) {
    __shared__ int sc[256];
    int t = threadIdx.x;
    int i = blockIdx.x * 256 + t;
    sc[t] = (i < N) ? cnt[i] : 0;
    __syncthreads();
    for (int off = 128; off > 0; off >>= 1) {
        if (t < off) sc[t] += sc[t + off];
        __syncthreads();
    }
    if (t == 0) csum[blockIdx.x] = sc[0];
}

__global__ void scanchunk_kernel(int* __restrict__ csum, int nch) {
    __shared__ int sc[256];
    int t = threadIdx.x;
    int v = (t < nch) ? csum[t] : 0;
    sc[t] = v;
    __syncthreads();
    for (int off = 1; off < 256; off <<= 1) {
        int y = (t >= off) ? sc[t - off] : 0;
        __syncthreads();
        sc[t] += y;
        __syncthreads();
    }
    if (t < nch) csum[t] = sc[t] - v;   // exclusive prefix
}

__global__ void offsets_kernel(const int* __restrict__ cnt, const int* __restrict__ csum,
                               int* __restrict__ offs, int N) {
    __shared__ int sc[256];
    int t = threadIdx.x;
    int i = blockIdx.x * 256 + t;
    int v = (i < N) ? cnt[i] : 0;
    sc[t] = v;
    __syncthreads();
    for (int off = 1; off < 256; off <<= 1) {
        int y = (t >= off) ? sc[t - off] : 0;
        __syncthreads();
        sc[t] += y;
        __syncthreads();
    }
    if (i < N) offs[i] = csum[blockIdx.x] + sc[t] - v;  // global exclusive prefix
}

__global__ void scatter_kernel(const int* __restrict__ dst, int* __restrict__ offs,
                               int* __restrict__ bucket, int E) {
    int i = blockIdx.x * blockDim.x + threadIdx.x;
    if (i < E) {
        int pos = atomicAdd(&offs[dst[i]], 1);
        bucket[pos] = i;
    }
}

// ---------------------------------------------------------------------------
// Kernel B: he_b3 MFMA (fragment recipe verified R13-R15). Change vs R15:
// the B3e partial is stored as BF16 into bytes 128..255 of each edge's own
// 256B e_out slot (u16 at slot[eid]+128+2*d) -- halves this kernel's write
// AND EGF's he gather. EGF reads the u16 then overwrites the full slot with
// f32 relu(he): per-edge self-overlap only, read-before-write in-wave.
// ---------------------------------------------------------------------------
__global__ void __launch_bounds__(256, 4)
he_b3_mfma(const float* __restrict__ e,
           const float* __restrict__ WB3, const float* __restrict__ bB3,
           unsigned short* __restrict__ he_u16, int E)
{
    __shared__ __align__(16) unsigned short Ebf[64 * 72];
    __shared__ __align__(16) unsigned short Wbf[64 * 72];

    const int t = threadIdx.x;
    const int lane = t & 63;
    const int wid = t >> 6;

    const int e0 = blockIdx.x << 6;
    const int nrow = min(64, E - e0);

    {
        const int r = t >> 2, s = t & 3;
        const float4* src = (const float4*)(WB3 + (size_t)r * 64 + s * 16);
        float4 v0 = src[0], v1 = src[1], v2 = src[2], v3 = src[3];
        *(uint4*)(&Wbf[r * 72 + s * 16]) = pack8(v0, v1);
        *(uint4*)(&Wbf[r * 72 + s * 16 + 8]) = pack8(v2, v3);
    }
    {
        const int r = t >> 2, s = t & 3;
        uint4 w0 = make_uint4(0, 0, 0, 0), w1 = make_uint4(0, 0, 0, 0);
        if (r < nrow) {
            const float4* src = (const float4*)(e + (size_t)(e0 + r) * 64 + s * 16);
            float4 v0 = src[0], v1 = src[1], v2 = src[2], v3 = src[3];
            w0 = pack8(v0, v1);
            w1 = pack8(v2, v3);
        }
        *(uint4*)(&Ebf[r * 72 + s * 16]) = w0;
        *(uint4*)(&Ebf[r * 72 + s * 16 + 8]) = w1;
    }
    __syncthreads();

    const int arow = (wid << 4) + (lane & 15);
    const int krun = (lane >> 4) << 3;
    short8 a0 = *(const short8*)(&Ebf[arow * 72 + krun]);
    short8 a1 = *(const short8*)(&Ebf[arow * 72 + krun + 32]);

    const int erow0 = e0 + (wid << 4) + ((lane >> 4) << 2);

#pragma unroll
    for (int dt = 0; dt < 4; ++dt) {
        const int d0 = dt << 4;
        const int dcol = d0 + (lane & 15);
        short8 b0 = *(const short8*)(&Wbf[dcol * 72 + krun]);
        short8 b1 = *(const short8*)(&Wbf[dcol * 72 + krun + 32]);
        float bias = bB3[dcol];
        float4v acc = {bias, bias, bias, bias};
        acc = __builtin_amdgcn_mfma_f32_16x16x32_bf16(a0, b0, acc, 0, 0, 0);
        acc = __builtin_amdgcn_mfma_f32_16x16x32_bf16(a1, b1, acc, 0, 0, 0);
#pragma unroll
        for (int r = 0; r < 4; ++r) {
            int er = erow0 + r;
            if (er < E)
                he_u16[(size_t)er * 128 + 64 + dcol] = (unsigned short)f2bf_bits(acc[r]);
        }
    }
}

// ---------------------------------------------------------------------------
// Kernel C: MERGED edge finish + gather + finalize (verified R10-R15).
// Change vs R15: hb is read as bf16 u16 from the upper half of the edge's
// e_out slot (he_u16[eid*128+64+lane]) -- 128B coalesced -- then the full
// 256B slot is overwritten with f32 relu(he).
// ---------------------------------------------------------------------------
__global__ void __launch_bounds__(256, 8)
edge_gather_finalize(const int* __restrict__ bucket, const int* __restrict__ offs_end,
                     const int* __restrict__ cnt, const int* __restrict__ src,
                     const unsigned int* __restrict__ P1u, const float2* __restrict__ P2,
                     const unsigned int* __restrict__ P3u,
                     const float* __restrict__ ln_g, const float* __restrict__ ln_b,
                     float* __restrict__ he_eout, float* __restrict__ h_out,
                     float* __restrict__ p_out, int N)
{
    const unsigned short* he16 = (const unsigned short*)he_eout;
    const int lane = threadIdx.x & 63;
    const int wid = threadIdx.x >> 6;
    const int wpb = blockDim.x >> 6;
    const float lg = ln_g[lane], lb = ln_b[lane];

    for (int n = blockIdx.x * wpb + wid; n < N; n += gridDim.x * wpb) {
        const int end = offs_end[n];
        const int deg = cnt[n];
        const int start = end - deg;
        const size_t o = (size_t)n * D + lane;

        const float2 p2n = P2[o];   // {B2h, sigmaK}, hoisted per node

        float asig = 0.f, av = 0.f, ap = 0.f;

        int k = start;
        for (; k + 3 < end; k += 4) {
            int eid[4], s[4];
#pragma unroll
            for (int i = 0; i < 4; ++i)
                eid[i] = __builtin_amdgcn_readfirstlane(bucket[k + i]);
#pragma unroll
            for (int i = 0; i < 4; ++i)
                s[i] = __builtin_amdgcn_readfirstlane(src[eid[i]]);

            unsigned int p1[4], p3[4]; float hb[4];
#pragma unroll
            for (int i = 0; i < 4; ++i) {
                p1[i] = P1u[(size_t)s[i] * D + lane];       // bf16 {B1h, sigmaQ}
                p3[i] = P3u[(size_t)s[i] * D + lane];       // bf16 {vh, C2p}
                hb[i] = bf_u16(he16[(size_t)eid[i] * 128 + 64 + lane]); // B3e partial
            }

            float sg[4], pr[4];
#pragma unroll
            for (int i = 0; i < 4; ++i) {
                float he = hb[i] + bf_lo(p1[i]) + p2n.x;
                he_eout[(size_t)eid[i] * D + lane] = fmaxf(he, 0.f);
                sg[i] = 1.f / (1.f + expf(-he));
                pr[i] = bf_hi(p1[i]) * p2n.y;
            }
#pragma unroll
            for (int off = 32; off > 0; off >>= 1) {
#pragma unroll
                for (int i = 0; i < 4; ++i) pr[i] += __shfl_xor(pr[i], off);
            }
#pragma unroll
            for (int i = 0; i < 4; ++i) {
                asig += sg[i];
                av   += sg[i] * pr[i] * bf_lo(p3[i]);
                ap   += sg[i] * bf_hi(p3[i]);
            }
        }
        for (; k < end; ++k) {
            int e0 = __builtin_amdgcn_readfirstlane(bucket[k]);
            int s0 = __builtin_amdgcn_readfirstlane(src[e0]);
            size_t eo0 = (size_t)e0 * D + lane;
            unsigned int p10 = P1u[(size_t)s0 * D + lane];
            unsigned int p30 = P3u[(size_t)s0 * D + lane];
            float hb0 = bf_u16(he16[(size_t)e0 * 128 + 64 + lane]);
            float he0 = hb0 + bf_lo(p10) + p2n.x;
            he_eout[eo0] = fmaxf(he0, 0.f);
            float sg0 = 1.f / (1.f + expf(-he0));
            float pr0 = bf_hi(p10) * p2n.y;
#pragma unroll
            for (int off = 32; off > 0; off >>= 1) pr0 += __shfl_xor(pr0, off);
            asig += sg0;
            av   += sg0 * pr0 * bf_lo(p30);
            ap   += sg0 * bf_hi(p30);
        }

        // fused epilogue (verified R9-R15)
        float denom = asig + EPS;
        float vh = bf_lo(P3u[o]);
        float hv = vh + av / denom;
        hv = fmaxf(hv, 0.f);
        float su = hv;
#pragma unroll
        for (int off = 32; off > 0; off >>= 1) su += __shfl_xor(su, off);
        float mu = su * (1.f / 64.f);
        float dv = hv - mu;
        float s2 = dv * dv;
#pragma unroll
        for (int off = 32; off > 0; off >>= 1) s2 += __shfl_xor(s2, off);
        float var = s2 * (1.f / 64.f);
        h_out[o] = dv * rsqrtf(var + LN_EPS) * lg + lb;

        float pv = p_out[o] + ap / denom;   // p_out holds C1p
        p_out[o] = tanhf(pv);
    }
}

extern "C" void kernel_launch(void* const* d_in, const int* in_sizes, int n_in,
                              void* d_out, int out_size, void* d_ws, size_t ws_size,
                              hipStream_t stream) {
    const float* h    = (const float*)d_in[0];
    const float* e    = (const float*)d_in[1];
    const float* p    = (const float*)d_in[2];
    const float* WK   = (const float*)d_in[3];
    const float* bK   = (const float*)d_in[4];
    const float* WV   = (const float*)d_in[5];
    const float* bV   = (const float*)d_in[6];
    const float* WB1  = (const float*)d_in[7];
    const float* bB1  = (const float*)d_in[8];
    const float* WB2  = (const float*)d_in[9];
    const float* bB2  = (const float*)d_in[10];
    const float* WB3  = (const float*)d_in[11];
    const float* bB3  = (const float*)d_in[12];
    const float* WC1  = (const float*)d_in[13];
    const float* bC1  = (const float*)d_in[14];
    const float* WC2  = (const float*)d_in[15];
    const float* bC2  = (const float*)d_in[16];
    const float* ln_g = (const float*)d_in[17];
    const float* ln_b = (const float*)d_in[18];
    const int*   src  = (const int*)d_in[19];
    const int*   dst  = (const int*)d_in[20];

    const int N = in_sizes[0] / D;
    const int E = in_sizes[1] / D;
    const size_t ND = (size_t)N * D;

    float* out   = (float*)d_out;
    float* h_out = out;
    float* e_out = out + ND;                  // bf16 B3e in slot upper halves, then f32 relu(he)
    float* p_out = out + ND + (size_t)E * D;  // C1p, then tanh(...)

    // ws: P1u ND u32 + P2 2ND f32 + P3u ND u32
    //   + cnt N + offs N + bucket E + csum (int)  ~= 55 MB
    float*        ws    = (float*)d_ws;
    unsigned int* P1u   = (unsigned int*)(ws);          // ND u32
    float2*       P2    = (float2*)(ws + ND);           // 2*ND floats
    unsigned int* P3u   = (unsigned int*)(ws + 3 * ND); // ND u32
    int*          cnt   = (int*)(ws + 4 * ND);          // N ints
    int*          offs  = cnt + N;                      // N ints
    int*          bucket= offs + N;                     // E ints
    int*          csum  = bucket + E;                   // nchunk ints (<=256)

    const int nchunk = (N + 255) / 256;

    hipMemsetAsync(cnt, 0, (size_t)N * sizeof(int), stream);

    node_linears_mfma<<<(N + 63) / 64, 256, 0, stream>>>(
        h, p, WK, bK, WV, bV, WB1, bB1, WB2, bB2, WC1, bC1, WC2, bC2,
        P1u, P2, P3u, p_out, N);

    hist_kernel<<<(E + 255) / 256, 256, 0, stream>>>(dst, cnt, E);
    chunksum_kernel<<<nchunk, 256, 0, stream>>>(cnt, csum, N);
    scanchunk_kernel<<<1, 256, 0, stream>>>(csum, nchunk);
    offsets_kernel<<<nchunk, 256, 0, stream>>>(cnt, csum, offs, N);
    scatter_kernel<<<(E + 255) / 256, 256, 0, stream>>>(dst, offs, bucket, E);

    he_b3_mfma<<<(E + 63) / 64, 256, 0, stream>>>(
        e, WB3, bB3, (unsigned short*)e_out, E);

    edge_gather_finalize<<<(N + 3) / 4, 256, 0, stream>>>(
        bucket, offs, cnt, src, P1u, P2, P3u, ln_g, ln_b,
        e_out, h_out, p_out, N);
}

// Round 17
// 362.969 us; speedup vs baseline: 16.7462x; 1.0124x over previous
//
#include <hip/hip_runtime.h>
#include <math.h>

#define D 64
#define EPS 1e-12f
#define LN_EPS 1e-5f

typedef __attribute__((ext_vector_type(8))) short short8;
typedef __attribute__((ext_vector_type(4))) float float4v;

// bf16 round-to-nearest-even packing helpers
__device__ __forceinline__ unsigned int f2bf_bits(float x) {
    unsigned int u = __float_as_uint(x);
    return (u + 0x7fffu + ((u >> 16) & 1u)) >> 16;
}
__device__ __forceinline__ float bf_lo(unsigned int p) {  // low 16 bits -> float
    return __uint_as_float(p << 16);
}
__device__ __forceinline__ float bf_hi(unsigned int p) {  // high 16 bits -> float
    return __uint_as_float(p & 0xffff0000u);
}
__device__ __forceinline__ float bf_u16(unsigned short u) {
    return __uint_as_float(((unsigned int)u) << 16);
}
__device__ __forceinline__ uint4 pack8(float4 u, float4 v) {
    uint4 w;
    w.x = f2bf_bits(u.x) | (f2bf_bits(u.y) << 16);
    w.y = f2bf_bits(u.z) | (f2bf_bits(u.w) << 16);
    w.z = f2bf_bits(v.x) | (f2bf_bits(v.y) << 16);
    w.w = f2bf_bits(v.z) | (f2bf_bits(v.w) << 16);
    return w;
}

// ---------------------------------------------------------------------------
// Kernel A: node linears on the matrix pipe (fragment recipe verified
// R13-R16). Outputs now:
//   P13[n*64+d] = uint2 { p1 = bf16{B1h,sigmaQ}, p3 = bf16{vh,C2p} }
//   P2u[n*64+d] = bf16 {B2h, sigmaK}
//   C1p -> p_out region
// SQu (reuse of the old SQf LDS) carries {sigmaQ,sigmaK} out of WK and
// p1 out of WB -- LDS footprint unchanged (69.6 KB).
// ---------------------------------------------------------------------------
__global__ void __launch_bounds__(256, 2)
node_linears_mfma(const float* __restrict__ h, const float* __restrict__ p,
                  const float* __restrict__ WK, const float* __restrict__ bK,
                  const float* __restrict__ WV, const float* __restrict__ bV,
                  const float* __restrict__ WB1, const float* __restrict__ bB1,
                  const float* __restrict__ WB2, const float* __restrict__ bB2,
                  const float* __restrict__ WC1, const float* __restrict__ bC1,
                  const float* __restrict__ WC2, const float* __restrict__ bC2,
                  uint2* __restrict__ P13, unsigned int* __restrict__ P2u,
                  float* __restrict__ C1pOut, int N)
{
    __shared__ __align__(16) unsigned short Xbf[64 * 136];
    __shared__ __align__(16) unsigned short Wbf[64 * 136];
    __shared__ float Vf[64 * 68];
    __shared__ unsigned int SQu[64 * 68];

    const int t = threadIdx.x;
    const int lane = t & 63;
    const int wid = t >> 6;
    const int n0 = blockIdx.x << 6;
    const int nrow = min(64, N - n0);

    const int r_ = t >> 2, s_ = t & 3;   // staging: row r_, 32-col segment s_

    // ---- stage X (h|p) and WK ----
    {
        uint4 w0 = {0,0,0,0}, w1 = {0,0,0,0}, w2 = {0,0,0,0}, w3 = {0,0,0,0};
        if (r_ < nrow) {
            const float* srcp = (s_ < 2) ? (h + (size_t)(n0 + r_) * 64 + s_ * 32)
                                         : (p + (size_t)(n0 + r_) * 64 + (s_ - 2) * 32);
            const float4* s4 = (const float4*)srcp;
            w0 = pack8(s4[0], s4[1]); w1 = pack8(s4[2], s4[3]);
            w2 = pack8(s4[4], s4[5]); w3 = pack8(s4[6], s4[7]);
        }
        uint4* dst = (uint4*)&Xbf[r_ * 136 + s_ * 32];
        dst[0] = w0; dst[1] = w1; dst[2] = w2; dst[3] = w3;
    }
    {
        const float4* s4 = (const float4*)(WK + (size_t)r_ * 128 + s_ * 32);
        uint4* dst = (uint4*)&Wbf[r_ * 136 + s_ * 32];
        dst[0] = pack8(s4[0], s4[1]); dst[1] = pack8(s4[2], s4[3]);
        dst[2] = pack8(s4[4], s4[5]); dst[3] = pack8(s4[6], s4[7]);
    }
    __syncthreads();

    // ---- A fragments (held in VGPRs across all phases) ----
    const int arow = (wid << 4) + (lane & 15);
    const int krun = (lane >> 4) << 3;
    const short8 a0 = *(const short8*)&Xbf[arow * 136 + krun];        // h k0..31
    const short8 a1 = *(const short8*)&Xbf[arow * 136 + krun + 32];   // h k32..63
    const short8 a2 = *(const short8*)&Xbf[arow * 136 + krun + 64];   // p k0..31
    const short8 a3 = *(const short8*)&Xbf[arow * 136 + krun + 96];   // p k32..63
    const int nodeb = (wid << 4) + ((lane >> 4) << 2);

    // ---- WK phase (K=128): SQu = bf16 {sigmaQ, sigmaK} ----
#pragma unroll
    for (int dt = 0; dt < 4; ++dt) {
        const int dcol = (dt << 4) + (lane & 15);
        short8 b0 = *(const short8*)&Wbf[dcol * 136 + krun];
        short8 b1 = *(const short8*)&Wbf[dcol * 136 + krun + 32];
        short8 b2 = *(const short8*)&Wbf[dcol * 136 + krun + 64];
        short8 b3 = *(const short8*)&Wbf[dcol * 136 + krun + 96];
        float bias = bK[dcol];
        float4v acc = {bias, bias, bias, bias};
        acc = __builtin_amdgcn_mfma_f32_16x16x32_bf16(a0, b0, acc, 0, 0, 0);
        acc = __builtin_amdgcn_mfma_f32_16x16x32_bf16(a1, b1, acc, 0, 0, 0);
        acc = __builtin_amdgcn_mfma_f32_16x16x32_bf16(a2, b2, acc, 0, 0, 0);
        acc = __builtin_amdgcn_mfma_f32_16x16x32_bf16(a3, b3, acc, 0, 0, 0);
#pragma unroll
        for (int r = 0; r < 4; ++r) {
            int node = nodeb + r;
            float aq = acc[r];
            float sq = expf(tanhf(aq));
            float sk = expf(1.f / (1.f + expf(-aq)));
            SQu[node * 68 + dcol] = f2bf_bits(sq) | (f2bf_bits(sk) << 16);
        }
    }
    __syncthreads();

    // ---- stage WB1|WB2 ----
    {
        const float* srcp = (s_ < 2) ? (WB1 + (size_t)r_ * 64 + s_ * 32)
                                     : (WB2 + (size_t)r_ * 64 + (s_ - 2) * 32);
        const float4* s4 = (const float4*)srcp;
        uint4* dst = (uint4*)&Wbf[r_ * 136 + s_ * 32];
        dst[0] = pack8(s4[0], s4[1]); dst[1] = pack8(s4[2], s4[3]);
        dst[2] = pack8(s4[4], s4[5]); dst[3] = pack8(s4[6], s4[7]);
    }
    __syncthreads();

    // ---- WB phase (K=64, input h): P2u = {B2h, sigmaK}; SQu <- p1 ----
#pragma unroll
    for (int dt = 0; dt < 4; ++dt) {
        const int dcol = (dt << 4) + (lane & 15);
        short8 c0 = *(const short8*)&Wbf[dcol * 136 + krun];
        short8 c1 = *(const short8*)&Wbf[dcol * 136 + krun + 32];
        short8 d0 = *(const short8*)&Wbf[dcol * 136 + krun + 64];
        short8 d1 = *(const short8*)&Wbf[dcol * 136 + krun + 96];
        float bb1 = bB1[dcol], bb2 = bB2[dcol];
        float4v acc1 = {bb1, bb1, bb1, bb1};
        float4v acc2 = {bb2, bb2, bb2, bb2};
        acc1 = __builtin_amdgcn_mfma_f32_16x16x32_bf16(a0, c0, acc1, 0, 0, 0);
        acc1 = __builtin_amdgcn_mfma_f32_16x16x32_bf16(a1, c1, acc1, 0, 0, 0);
        acc2 = __builtin_amdgcn_mfma_f32_16x16x32_bf16(a0, d0, acc2, 0, 0, 0);
        acc2 = __builtin_amdgcn_mfma_f32_16x16x32_bf16(a1, d1, acc2, 0, 0, 0);
#pragma unroll
        for (int r = 0; r < 4; ++r) {
            int node = nodeb + r;
            unsigned int sq = SQu[node * 68 + dcol];     // {sigmaQ, sigmaK}
            unsigned int p1 = f2bf_bits(acc1[r]) | ((sq & 0xFFFFu) << 16);
            SQu[node * 68 + dcol] = p1;                  // stash for WC
            if (node < nrow) {
                size_t o = (size_t)(n0 + node) * 64 + dcol;
                P2u[o] = f2bf_bits(acc2[r]) | (sq & 0xFFFF0000u);
            }
        }
    }
    __syncthreads();

    // ---- stage WV ----
    {
        const float4* s4 = (const float4*)(WV + (size_t)r_ * 128 + s_ * 32);
        uint4* dst = (uint4*)&Wbf[r_ * 136 + s_ * 32];
        dst[0] = pack8(s4[0], s4[1]); dst[1] = pack8(s4[2], s4[3]);
        dst[2] = pack8(s4[4], s4[5]); dst[3] = pack8(s4[6], s4[7]);
    }
    __syncthreads();

    // ---- WV phase (K=128): vh -> Vf LDS stash ----
#pragma unroll
    for (int dt = 0; dt < 4; ++dt) {
        const int dcol = (dt << 4) + (lane & 15);
        short8 b0 = *(const short8*)&Wbf[dcol * 136 + krun];
        short8 b1 = *(const short8*)&Wbf[dcol * 136 + krun + 32];
        short8 b2 = *(const short8*)&Wbf[dcol * 136 + krun + 64];
        short8 b3 = *(const short8*)&Wbf[dcol * 136 + krun + 96];
        float bias = bV[dcol];
        float4v acc = {bias, bias, bias, bias};
        acc = __builtin_amdgcn_mfma_f32_16x16x32_bf16(a0, b0, acc, 0, 0, 0);
        acc = __builtin_amdgcn_mfma_f32_16x16x32_bf16(a1, b1, acc, 0, 0, 0);
        acc = __builtin_amdgcn_mfma_f32_16x16x32_bf16(a2, b2, acc, 0, 0, 0);
        acc = __builtin_amdgcn_mfma_f32_16x16x32_bf16(a3, b3, acc, 0, 0, 0);
#pragma unroll
        for (int r = 0; r < 4; ++r) {
            int node = nodeb + r;
            Vf[node * 68 + dcol] = acc[r];
        }
    }
    __syncthreads();

    // ---- stage WC1|WC2 ----
    {
        const float* srcp = (s_ < 2) ? (WC1 + (size_t)r_ * 64 + s_ * 32)
                                     : (WC2 + (size_t)r_ * 64 + (s_ - 2) * 32);
        const float4* s4 = (const float4*)srcp;
        uint4* dst = (uint4*)&Wbf[r_ * 136 + s_ * 32];
        dst[0] = pack8(s4[0], s4[1]); dst[1] = pack8(s4[2], s4[3]);
        dst[2] = pack8(s4[4], s4[5]); dst[3] = pack8(s4[6], s4[7]);
    }
    __syncthreads();

    // ---- WC phase (K=64, input p): C1p -> C1pOut, P13 = {p1, p3} ----
#pragma unroll
    for (int dt = 0; dt < 4; ++dt) {
        const int dcol = (dt << 4) + (lane & 15);
        short8 c0 = *(const short8*)&Wbf[dcol * 136 + krun];
        short8 c1 = *(const short8*)&Wbf[dcol * 136 + krun + 32];
        short8 d0 = *(const short8*)&Wbf[dcol * 136 + krun + 64];
        short8 d1 = *(const short8*)&Wbf[dcol * 136 + krun + 96];
        float bc1 = bC1[dcol], bc2 = bC2[dcol];
        float4v acc1 = {bc1, bc1, bc1, bc1};
        float4v acc2 = {bc2, bc2, bc2, bc2};
        acc1 = __builtin_amdgcn_mfma_f32_16x16x32_bf16(a2, c0, acc1, 0, 0, 0);
        acc1 = __builtin_amdgcn_mfma_f32_16x16x32_bf16(a3, c1, acc1, 0, 0, 0);
        acc2 = __builtin_amdgcn_mfma_f32_16x16x32_bf16(a2, d0, acc2, 0, 0, 0);
        acc2 = __builtin_amdgcn_mfma_f32_16x16x32_bf16(a3, d1, acc2, 0, 0, 0);
#pragma unroll
        for (int r = 0; r < 4; ++r) {
            int node = nodeb + r;
            if (node < nrow) {
                size_t o = (size_t)(n0 + node) * 64 + dcol;
                C1pOut[o] = acc1[r];
                float vh = Vf[node * 68 + dcol];
                unsigned int p3 = f2bf_bits(vh) | (f2bf_bits(acc2[r]) << 16);
                P13[o] = make_uint2(SQu[node * 68 + dcol], p3);
            }
        }
    }
}

// ---------------------------------------------------------------------------
// dst-bucketing pipeline (int atomics only; verified R4-R16).
// ---------------------------------------------------------------------------
__global__ void hist_kernel(const int* __restrict__ dst, int* __restrict__ cnt, int E) {
    int i = blockIdx.x * blockDim.x + threadIdx.x;
    if (i < E) atomicAdd(&cnt[dst[i]], 1);
}

__global__ void chunksum_kernel(const int* __restrict__ cnt, int* __restrict__ csum, int N) {
    __shared__ int sc[256];
    int t = threadIdx.x;
    int i = blockIdx.x * 256 + t;
    sc[t] = (i < N) ? cnt[i] : 0;
    __syncthreads();
    for (int off = 128; off > 0; off >>= 1) {
        if (t < off) sc[t] += sc[t + off];
        __syncthreads();
    }
    if (t == 0) csum[blockIdx.x] = sc[0];
}

__global__ void scanchunk_kernel(int* __restrict__ csum, int nch) {
    __shared__ int sc[256];
    int t = threadIdx.x;
    int v = (t < nch) ? csum[t] : 0;
    sc[t] = v;
    __syncthreads();
    for (int off = 1; off < 256; off <<= 1) {
        int y = (t >= off) ? sc[t - off] : 0;
        __syncthreads();
        sc[t] += y;
        __syncthreads();
    }
    if (t < nch) csum[t] = sc[t] - v;   // exclusive prefix
}

__global__ void offsets_kernel(const int* __restrict__ cnt, const int* __restrict__ csum,
                               int* __restrict__ offs, int N) {
    __shared__ int sc[256];
    int t = threadIdx.x;
    int i = blockIdx.x * 256 + t;
    int v = (i < N) ? cnt[i] : 0;
    sc[t] = v;
    __syncthreads();
    for (int off = 1; off < 256; off <<= 1) {
        int y = (t >= off) ? sc[t - off] : 0;
        __syncthreads();
        sc[t] += y;
        __syncthreads();
    }
    if (i < N) offs[i] = csum[blockIdx.x] + sc[t] - v;  // global exclusive prefix
}

__global__ void scatter_kernel(const int* __restrict__ dst, int* __restrict__ offs,
                               int* __restrict__ bucket, int E) {
    int i = blockIdx.x * blockDim.x + threadIdx.x;
    if (i < E) {
        int pos = atomicAdd(&offs[dst[i]], 1);
        bucket[pos] = i;
    }
}

// ---------------------------------------------------------------------------
// Kernel B: he_b3 MFMA (verified R13-R16, verbatim). bf16 B3e partial into
// bytes 128..255 of each edge's 256B e_out slot.
// ---------------------------------------------------------------------------
__global__ void __launch_bounds__(256, 4)
he_b3_mfma(const float* __restrict__ e,
           const float* __restrict__ WB3, const float* __restrict__ bB3,
           unsigned short* __restrict__ he_u16, int E)
{
    __shared__ __align__(16) unsigned short Ebf[64 * 72];
    __shared__ __align__(16) unsigned short Wbf[64 * 72];

    const int t = threadIdx.x;
    const int lane = t & 63;
    const int wid = t >> 6;

    const int e0 = blockIdx.x << 6;
    const int nrow = min(64, E - e0);

    {
        const int r = t >> 2, s = t & 3;
        const float4* src = (const float4*)(WB3 + (size_t)r * 64 + s * 16);
        float4 v0 = src[0], v1 = src[1], v2 = src[2], v3 = src[3];
        *(uint4*)(&Wbf[r * 72 + s * 16]) = pack8(v0, v1);
        *(uint4*)(&Wbf[r * 72 + s * 16 + 8]) = pack8(v2, v3);
    }
    {
        const int r = t >> 2, s = t & 3;
        uint4 w0 = make_uint4(0, 0, 0, 0), w1 = make_uint4(0, 0, 0, 0);
        if (r < nrow) {
            const float4* src = (const float4*)(e + (size_t)(e0 + r) * 64 + s * 16);
            float4 v0 = src[0], v1 = src[1], v2 = src[2], v3 = src[3];
            w0 = pack8(v0, v1);
            w1 = pack8(v2, v3);
        }
        *(uint4*)(&Ebf[r * 72 + s * 16]) = w0;
        *(uint4*)(&Ebf[r * 72 + s * 16 + 8]) = w1;
    }
    __syncthreads();

    const int arow = (wid << 4) + (lane & 15);
    const int krun = (lane >> 4) << 3;
    short8 a0 = *(const short8*)(&Ebf[arow * 72 + krun]);
    short8 a1 = *(const short8*)(&Ebf[arow * 72 + krun + 32]);

    const int erow0 = e0 + (wid << 4) + ((lane >> 4) << 2);

#pragma unroll
    for (int dt = 0; dt < 4; ++dt) {
        const int d0 = dt << 4;
        const int dcol = d0 + (lane & 15);
        short8 b0 = *(const short8*)(&Wbf[dcol * 72 + krun]);
        short8 b1 = *(const short8*)(&Wbf[dcol * 72 + krun + 32]);
        float bias = bB3[dcol];
        float4v acc = {bias, bias, bias, bias};
        acc = __builtin_amdgcn_mfma_f32_16x16x32_bf16(a0, b0, acc, 0, 0, 0);
        acc = __builtin_amdgcn_mfma_f32_16x16x32_bf16(a1, b1, acc, 0, 0, 0);
#pragma unroll
        for (int r = 0; r < 4; ++r) {
            int er = erow0 + r;
            if (er < E)
                he_u16[(size_t)er * 128 + 64 + dcol] = (unsigned short)f2bf_bits(acc[r]);
        }
    }
}

// ---------------------------------------------------------------------------
// Kernel C: MERGED edge finish + gather + finalize (verified R10-R16).
// Changes vs R16: single uint2 P13 gather per edge (was two u32 gathers);
// P2 hoist is bf16-packed u32.
// ---------------------------------------------------------------------------
__global__ void __launch_bounds__(256, 8)
edge_gather_finalize(const int* __restrict__ bucket, const int* __restrict__ offs_end,
                     const int* __restrict__ cnt, const int* __restrict__ src,
                     const uint2* __restrict__ P13, const unsigned int* __restrict__ P2u,
                     const float* __restrict__ ln_g, const float* __restrict__ ln_b,
                     float* __restrict__ he_eout, float* __restrict__ h_out,
                     float* __restrict__ p_out, int N)
{
    const unsigned short* he16 = (const unsigned short*)he_eout;
    const int lane = threadIdx.x & 63;
    const int wid = threadIdx.x >> 6;
    const int wpb = blockDim.x >> 6;
    const float lg = ln_g[lane], lb = ln_b[lane];

    for (int n = blockIdx.x * wpb + wid; n < N; n += gridDim.x * wpb) {
        const int end = offs_end[n];
        const int deg = cnt[n];
        const int start = end - deg;
        const size_t o = (size_t)n * D + lane;

        const unsigned int p2n = P2u[o];   // bf16 {B2h, sigmaK}, per-node hoist
        const float b2n = bf_lo(p2n);
        const float skn = bf_hi(p2n);

        float asig = 0.f, av = 0.f, ap = 0.f;

        int k = start;
        for (; k + 3 < end; k += 4) {
            int eid[4], s[4];
#pragma unroll
            for (int i = 0; i < 4; ++i)
                eid[i] = __builtin_amdgcn_readfirstlane(bucket[k + i]);
#pragma unroll
            for (int i = 0; i < 4; ++i)
                s[i] = __builtin_amdgcn_readfirstlane(src[eid[i]]);

            uint2 q[4]; float hb[4];
#pragma unroll
            for (int i = 0; i < 4; ++i) {
                q[i]  = P13[(size_t)s[i] * D + lane];   // {p1, p3}
                hb[i] = bf_u16(he16[(size_t)eid[i] * 128 + 64 + lane]);
            }

            float sg[4], pr[4];
#pragma unroll
            for (int i = 0; i < 4; ++i) {
                float he = hb[i] + bf_lo(q[i].x) + b2n;
                he_eout[(size_t)eid[i] * D + lane] = fmaxf(he, 0.f);
                sg[i] = 1.f / (1.f + expf(-he));
                pr[i] = bf_hi(q[i].x) * skn;
            }
#pragma unroll
            for (int off = 32; off > 0; off >>= 1) {
#pragma unroll
                for (int i = 0; i < 4; ++i) pr[i] += __shfl_xor(pr[i], off);
            }
#pragma unroll
            for (int i = 0; i < 4; ++i) {
                asig += sg[i];
                av   += sg[i] * pr[i] * bf_lo(q[i].y);
                ap   += sg[i] * bf_hi(q[i].y);
            }
        }
        for (; k < end; ++k) {
            int e0 = __builtin_amdgcn_readfirstlane(bucket[k]);
            int s0 = __builtin_amdgcn_readfirstlane(src[e0]);
            size_t eo0 = (size_t)e0 * D + lane;
            uint2 q0 = P13[(size_t)s0 * D + lane];
            float hb0 = bf_u16(he16[(size_t)e0 * 128 + 64 + lane]);
            float he0 = hb0 + bf_lo(q0.x) + b2n;
            he_eout[eo0] = fmaxf(he0, 0.f);
            float sg0 = 1.f / (1.f + expf(-he0));
            float pr0 = bf_hi(q0.x) * skn;
#pragma unroll
            for (int off = 32; off > 0; off >>= 1) pr0 += __shfl_xor(pr0, off);
            asig += sg0;
            av   += sg0 * pr0 * bf_lo(q0.y);
            ap   += sg0 * bf_hi(q0.y);
        }

        // fused epilogue (verified R9-R16)
        float denom = asig + EPS;
        float vh = bf_lo(P13[o].y);
        float hv = vh + av / denom;
        hv = fmaxf(hv, 0.f);
        float su = hv;
#pragma unroll
        for (int off = 32; off > 0; off >>= 1) su += __shfl_xor(su, off);
        float mu = su * (1.f / 64.f);
        float dv = hv - mu;
        float s2 = dv * dv;
#pragma unroll
        for (int off = 32; off > 0; off >>= 1) s2 += __shfl_xor(s2, off);
        float var = s2 * (1.f / 64.f);
        h_out[o] = dv * rsqrtf(var + LN_EPS) * lg + lb;

        float pv = p_out[o] + ap / denom;   // p_out holds C1p
        p_out[o] = tanhf(pv);
    }
}

extern "C" void kernel_launch(void* const* d_in, const int* in_sizes, int n_in,
                              void* d_out, int out_size, void* d_ws, size_t ws_size,
                              hipStream_t stream) {
    const float* h    = (const float*)d_in[0];
    const float* e    = (const float*)d_in[1];
    const float* p    = (const float*)d_in[2];
    const float* WK   = (const float*)d_in[3];
    const float* bK   = (const float*)d_in[4];
    const float* WV   = (const float*)d_in[5];
    const float* bV   = (const float*)d_in[6];
    const float* WB1  = (const float*)d_in[7];
    const float* bB1  = (const float*)d_in[8];
    const float* WB2  = (const float*)d_in[9];
    const float* bB2  = (const float*)d_in[10];
    const float* WB3  = (const float*)d_in[11];
    const float* bB3  = (const float*)d_in[12];
    const float* WC1  = (const float*)d_in[13];
    const float* bC1  = (const float*)d_in[14];
    const float* WC2  = (const float*)d_in[15];
    const float* bC2  = (const float*)d_in[16];
    const float* ln_g = (const float*)d_in[17];
    const float* ln_b = (const float*)d_in[18];
    const int*   src  = (const int*)d_in[19];
    const int*   dst  = (const int*)d_in[20];

    const int N = in_sizes[0] / D;
    const int E = in_sizes[1] / D;
    const size_t ND = (size_t)N * D;

    float* out   = (float*)d_out;
    float* h_out = out;
    float* e_out = out + ND;                  // bf16 B3e in slot upper halves, then f32 relu(he)
    float* p_out = out + ND + (size_t)E * D;  // C1p, then tanh(...)

    // ws: P13 ND uint2 + P2u ND u32 + cnt N + offs N + bucket E + csum  ~= 42 MB
    float*        ws    = (float*)d_ws;
    uint2*        P13   = (uint2*)(ws);                 // 2*ND u32
    unsigned int* P2u   = (unsigned int*)(ws + 2 * ND); // ND u32
    int*          cnt   = (int*)(ws + 3 * ND);          // N ints
    int*          offs  = cnt + N;                      // N ints
    int*          bucket= offs + N;                     // E ints
    int*          csum  = bucket + E;                   // nchunk ints (<=256)

    const int nchunk = (N + 255) / 256;

    hipMemsetAsync(cnt, 0, (size_t)N * sizeof(int), stream);

    node_linears_mfma<<<(N + 63) / 64, 256, 0, stream>>>(
        h, p, WK, bK, WV, bV, WB1, bB1, WB2, bB2, WC1, bC1, WC2, bC2,
        P13, P2u, p_out, N);

    hist_kernel<<<(E + 255) / 256, 256, 0, stream>>>(dst, cnt, E);
    chunksum_kernel<<<nchunk, 256, 0, stream>>>(cnt, csum, N);
    scanchunk_kernel<<<1, 256, 0, stream>>>(csum, nchunk);
    offsets_kernel<<<nchunk, 256, 0, stream>>>(cnt, csum, offs, N);
    scatter_kernel<<<(E + 255) / 256, 256, 0, stream>>>(dst, offs, bucket, E);

    he_b3_mfma<<<(E + 63) / 64, 256, 0, stream>>>(
        e, WB3, bB3, (unsigned short*)e_out, E);

    edge_gather_finalize<<<(N + 3) / 4, 256, 0, stream>>>(
        bucket, offs, cnt, src, P13, P2u, ln_g, ln_b,
        e_out, h_out, p_out, N);
}

// Round 18
// 352.156 us; speedup vs baseline: 17.2604x; 1.0307x over previous
//
#include <hip/hip_runtime.h>
#include <math.h>

#define D 64
#define EPS 1e-12f
#define LN_EPS 1e-5f

typedef __attribute__((ext_vector_type(8))) short short8;
typedef __attribute__((ext_vector_type(4))) float float4v;

// bf16 round-to-nearest-even packing helpers
__device__ __forceinline__ unsigned int f2bf_bits(float x) {
    unsigned int u = __float_as_uint(x);
    return (u + 0x7fffu + ((u >> 16) & 1u)) >> 16;
}
__device__ __forceinline__ float bf_lo(unsigned int p) {  // low 16 bits -> float
    return __uint_as_float(p << 16);
}
__device__ __forceinline__ float bf_hi(unsigned int p) {  // high 16 bits -> float
    return __uint_as_float(p & 0xffff0000u);
}
__device__ __forceinline__ float bf_u16(unsigned short u) {
    return __uint_as_float(((unsigned int)u) << 16);
}
__device__ __forceinline__ uint4 pack8(float4 u, float4 v) {
    uint4 w;
    w.x = f2bf_bits(u.x) | (f2bf_bits(u.y) << 16);
    w.y = f2bf_bits(u.z) | (f2bf_bits(u.w) << 16);
    w.z = f2bf_bits(v.x) | (f2bf_bits(v.y) << 16);
    w.w = f2bf_bits(v.z) | (f2bf_bits(v.w) << 16);
    return w;
}

// ---------------------------------------------------------------------------
// Kernel A: node linears on the matrix pipe (verified R13-R17, verbatim).
//   P13[n*64+d] = uint2 { p1 = bf16{B1h,sigmaQ}, p3 = bf16{vh,C2p} }
//   P2u[n*64+d] = bf16 {B2h, sigmaK}
//   C1p -> p_out region
// ---------------------------------------------------------------------------
__global__ void __launch_bounds__(256, 2)
node_linears_mfma(const float* __restrict__ h, const float* __restrict__ p,
                  const float* __restrict__ WK, const float* __restrict__ bK,
                  const float* __restrict__ WV, const float* __restrict__ bV,
                  const float* __restrict__ WB1, const float* __restrict__ bB1,
                  const float* __restrict__ WB2, const float* __restrict__ bB2,
                  const float* __restrict__ WC1, const float* __restrict__ bC1,
                  const float* __restrict__ WC2, const float* __restrict__ bC2,
                  uint2* __restrict__ P13, unsigned int* __restrict__ P2u,
                  float* __restrict__ C1pOut, int N)
{
    __shared__ __align__(16) unsigned short Xbf[64 * 136];
    __shared__ __align__(16) unsigned short Wbf[64 * 136];
    __shared__ float Vf[64 * 68];
    __shared__ unsigned int SQu[64 * 68];

    const int t = threadIdx.x;
    const int lane = t & 63;
    const int wid = t >> 6;
    const int n0 = blockIdx.x << 6;
    const int nrow = min(64, N - n0);

    const int r_ = t >> 2, s_ = t & 3;   // staging: row r_, 32-col segment s_

    // ---- stage X (h|p) and WK ----
    {
        uint4 w0 = {0,0,0,0}, w1 = {0,0,0,0}, w2 = {0,0,0,0}, w3 = {0,0,0,0};
        if (r_ < nrow) {
            const float* srcp = (s_ < 2) ? (h + (size_t)(n0 + r_) * 64 + s_ * 32)
                                         : (p + (size_t)(n0 + r_) * 64 + (s_ - 2) * 32);
            const float4* s4 = (const float4*)srcp;
            w0 = pack8(s4[0], s4[1]); w1 = pack8(s4[2], s4[3]);
            w2 = pack8(s4[4], s4[5]); w3 = pack8(s4[6], s4[7]);
        }
        uint4* dst = (uint4*)&Xbf[r_ * 136 + s_ * 32];
        dst[0] = w0; dst[1] = w1; dst[2] = w2; dst[3] = w3;
    }
    {
        const float4* s4 = (const float4*)(WK + (size_t)r_ * 128 + s_ * 32);
        uint4* dst = (uint4*)&Wbf[r_ * 136 + s_ * 32];
        dst[0] = pack8(s4[0], s4[1]); dst[1] = pack8(s4[2], s4[3]);
        dst[2] = pack8(s4[4], s4[5]); dst[3] = pack8(s4[6], s4[7]);
    }
    __syncthreads();

    // ---- A fragments (held in VGPRs across all phases) ----
    const int arow = (wid << 4) + (lane & 15);
    const int krun = (lane >> 4) << 3;
    const short8 a0 = *(const short8*)&Xbf[arow * 136 + krun];        // h k0..31
    const short8 a1 = *(const short8*)&Xbf[arow * 136 + krun + 32];   // h k32..63
    const short8 a2 = *(const short8*)&Xbf[arow * 136 + krun + 64];   // p k0..31
    const short8 a3 = *(const short8*)&Xbf[arow * 136 + krun + 96];   // p k32..63
    const int nodeb = (wid << 4) + ((lane >> 4) << 2);

    // ---- WK phase (K=128): SQu = bf16 {sigmaQ, sigmaK} ----
#pragma unroll
    for (int dt = 0; dt < 4; ++dt) {
        const int dcol = (dt << 4) + (lane & 15);
        short8 b0 = *(const short8*)&Wbf[dcol * 136 + krun];
        short8 b1 = *(const short8*)&Wbf[dcol * 136 + krun + 32];
        short8 b2 = *(const short8*)&Wbf[dcol * 136 + krun + 64];
        short8 b3 = *(const short8*)&Wbf[dcol * 136 + krun + 96];
        float bias = bK[dcol];
        float4v acc = {bias, bias, bias, bias};
        acc = __builtin_amdgcn_mfma_f32_16x16x32_bf16(a0, b0, acc, 0, 0, 0);
        acc = __builtin_amdgcn_mfma_f32_16x16x32_bf16(a1, b1, acc, 0, 0, 0);
        acc = __builtin_amdgcn_mfma_f32_16x16x32_bf16(a2, b2, acc, 0, 0, 0);
        acc = __builtin_amdgcn_mfma_f32_16x16x32_bf16(a3, b3, acc, 0, 0, 0);
#pragma unroll
        for (int r = 0; r < 4; ++r) {
            int node = nodeb + r;
            float aq = acc[r];
            float sq = expf(tanhf(aq));
            float sk = expf(1.f / (1.f + expf(-aq)));
            SQu[node * 68 + dcol] = f2bf_bits(sq) | (f2bf_bits(sk) << 16);
        }
    }
    __syncthreads();

    // ---- stage WB1|WB2 ----
    {
        const float* srcp = (s_ < 2) ? (WB1 + (size_t)r_ * 64 + s_ * 32)
                                     : (WB2 + (size_t)r_ * 64 + (s_ - 2) * 32);
        const float4* s4 = (const float4*)srcp;
        uint4* dst = (uint4*)&Wbf[r_ * 136 + s_ * 32];
        dst[0] = pack8(s4[0], s4[1]); dst[1] = pack8(s4[2], s4[3]);
        dst[2] = pack8(s4[4], s4[5]); dst[3] = pack8(s4[6], s4[7]);
    }
    __syncthreads();

    // ---- WB phase (K=64, input h): P2u = {B2h, sigmaK}; SQu <- p1 ----
#pragma unroll
    for (int dt = 0; dt < 4; ++dt) {
        const int dcol = (dt << 4) + (lane & 15);
        short8 c0 = *(const short8*)&Wbf[dcol * 136 + krun];
        short8 c1 = *(const short8*)&Wbf[dcol * 136 + krun + 32];
        short8 d0 = *(const short8*)&Wbf[dcol * 136 + krun + 64];
        short8 d1 = *(const short8*)&Wbf[dcol * 136 + krun + 96];
        float bb1 = bB1[dcol], bb2 = bB2[dcol];
        float4v acc1 = {bb1, bb1, bb1, bb1};
        float4v acc2 = {bb2, bb2, bb2, bb2};
        acc1 = __builtin_amdgcn_mfma_f32_16x16x32_bf16(a0, c0, acc1, 0, 0, 0);
        acc1 = __builtin_amdgcn_mfma_f32_16x16x32_bf16(a1, c1, acc1, 0, 0, 0);
        acc2 = __builtin_amdgcn_mfma_f32_16x16x32_bf16(a0, d0, acc2, 0, 0, 0);
        acc2 = __builtin_amdgcn_mfma_f32_16x16x32_bf16(a1, d1, acc2, 0, 0, 0);
#pragma unroll
        for (int r = 0; r < 4; ++r) {
            int node = nodeb + r;
            unsigned int sq = SQu[node * 68 + dcol];     // {sigmaQ, sigmaK}
            unsigned int p1 = f2bf_bits(acc1[r]) | ((sq & 0xFFFFu) << 16);
            SQu[node * 68 + dcol] = p1;                  // stash for WC
            if (node < nrow) {
                size_t o = (size_t)(n0 + node) * 64 + dcol;
                P2u[o] = f2bf_bits(acc2[r]) | (sq & 0xFFFF0000u);
            }
        }
    }
    __syncthreads();

    // ---- stage WV ----
    {
        const float4* s4 = (const float4*)(WV + (size_t)r_ * 128 + s_ * 32);
        uint4* dst = (uint4*)&Wbf[r_ * 136 + s_ * 32];
        dst[0] = pack8(s4[0], s4[1]); dst[1] = pack8(s4[2], s4[3]);
        dst[2] = pack8(s4[4], s4[5]); dst[3] = pack8(s4[6], s4[7]);
    }
    __syncthreads();

    // ---- WV phase (K=128): vh -> Vf LDS stash ----
#pragma unroll
    for (int dt = 0; dt < 4; ++dt) {
        const int dcol = (dt << 4) + (lane & 15);
        short8 b0 = *(const short8*)&Wbf[dcol * 136 + krun];
        short8 b1 = *(const short8*)&Wbf[dcol * 136 + krun + 32];
        short8 b2 = *(const short8*)&Wbf[dcol * 136 + krun + 64];
        short8 b3 = *(const short8*)&Wbf[dcol * 136 + krun + 96];
        float bias = bV[dcol];
        float4v acc = {bias, bias, bias, bias};
        acc = __builtin_amdgcn_mfma_f32_16x16x32_bf16(a0, b0, acc, 0, 0, 0);
        acc = __builtin_amdgcn_mfma_f32_16x16x32_bf16(a1, b1, acc, 0, 0, 0);
        acc = __builtin_amdgcn_mfma_f32_16x16x32_bf16(a2, b2, acc, 0, 0, 0);
        acc = __builtin_amdgcn_mfma_f32_16x16x32_bf16(a3, b3, acc, 0, 0, 0);
#pragma unroll
        for (int r = 0; r < 4; ++r) {
            int node = nodeb + r;
            Vf[node * 68 + dcol] = acc[r];
        }
    }
    __syncthreads();

    // ---- stage WC1|WC2 ----
    {
        const float* srcp = (s_ < 2) ? (WC1 + (size_t)r_ * 64 + s_ * 32)
                                     : (WC2 + (size_t)r_ * 64 + (s_ - 2) * 32);
        const float4* s4 = (const float4*)srcp;
        uint4* dst = (uint4*)&Wbf[r_ * 136 + s_ * 32];
        dst[0] = pack8(s4[0], s4[1]); dst[1] = pack8(s4[2], s4[3]);
        dst[2] = pack8(s4[4], s4[5]); dst[3] = pack8(s4[6], s4[7]);
    }
    __syncthreads();

    // ---- WC phase (K=64, input p): C1p -> C1pOut, P13 = {p1, p3} ----
#pragma unroll
    for (int dt = 0; dt < 4; ++dt) {
        const int dcol = (dt << 4) + (lane & 15);
        short8 c0 = *(const short8*)&Wbf[dcol * 136 + krun];
        short8 c1 = *(const short8*)&Wbf[dcol * 136 + krun + 32];
        short8 d0 = *(const short8*)&Wbf[dcol * 136 + krun + 64];
        short8 d1 = *(const short8*)&Wbf[dcol * 136 + krun + 96];
        float bc1 = bC1[dcol], bc2 = bC2[dcol];
        float4v acc1 = {bc1, bc1, bc1, bc1};
        float4v acc2 = {bc2, bc2, bc2, bc2};
        acc1 = __builtin_amdgcn_mfma_f32_16x16x32_bf16(a2, c0, acc1, 0, 0, 0);
        acc1 = __builtin_amdgcn_mfma_f32_16x16x32_bf16(a3, c1, acc1, 0, 0, 0);
        acc2 = __builtin_amdgcn_mfma_f32_16x16x32_bf16(a2, d0, acc2, 0, 0, 0);
        acc2 = __builtin_amdgcn_mfma_f32_16x16x32_bf16(a3, d1, acc2, 0, 0, 0);
#pragma unroll
        for (int r = 0; r < 4; ++r) {
            int node = nodeb + r;
            if (node < nrow) {
                size_t o = (size_t)(n0 + node) * 64 + dcol;
                C1pOut[o] = acc1[r];
                float vh = Vf[node * 68 + dcol];
                unsigned int p3 = f2bf_bits(vh) | (f2bf_bits(acc2[r]) << 16);
                P13[o] = make_uint2(SQu[node * 68 + dcol], p3);
            }
        }
    }
}

// ---------------------------------------------------------------------------
// dst-bucketing pipeline (int atomics only; verified R4-R17).
// ---------------------------------------------------------------------------
__global__ void hist_kernel(const int* __restrict__ dst, int* __restrict__ cnt, int E) {
    int i = blockIdx.x * blockDim.x + threadIdx.x;
    if (i < E) atomicAdd(&cnt[dst[i]], 1);
}

__global__ void chunksum_kernel(const int* __restrict__ cnt, int* __restrict__ csum, int N) {
    __shared__ int sc[256];
    int t = threadIdx.x;
    int i = blockIdx.x * 256 + t;
    sc[t] = (i < N) ? cnt[i] : 0;
    __syncthreads();
    for (int off = 128; off > 0; off >>= 1) {
        if (t < off) sc[t] += sc[t + off];
        __syncthreads();
    }
    if (t == 0) csum[blockIdx.x] = sc[0];
}

__global__ void scanchunk_kernel(int* __restrict__ csum, int nch) {
    __shared__ int sc[256];
    int t = threadIdx.x;
    int v = (t < nch) ? csum[t] : 0;
    sc[t] = v;
    __syncthreads();
    for (int off = 1; off < 256; off <<= 1) {
        int y = (t >= off) ? sc[t - off] : 0;
        __syncthreads();
        sc[t] += y;
        __syncthreads();
    }
    if (t < nch) csum[t] = sc[t] - v;   // exclusive prefix
}

__global__ void offsets_kernel(const int* __restrict__ cnt, const int* __restrict__ csum,
                               int* __restrict__ offs, int N) {
    __shared__ int sc[256];
    int t = threadIdx.x;
    int i = blockIdx.x * 256 + t;
    int v = (i < N) ? cnt[i] : 0;
    sc[t] = v;
    __syncthreads();
    for (int off = 1; off < 256; off <<= 1) {
        int y = (t >= off) ? sc[t - off] : 0;
        __syncthreads();
        sc[t] += y;
        __syncthreads();
    }
    if (i < N) offs[i] = csum[blockIdx.x] + sc[t] - v;  // global exclusive prefix
}

__global__ void scatter_kernel(const int* __restrict__ dst, int* __restrict__ offs,
                               int* __restrict__ bucket, int E) {
    int i = blockIdx.x * blockDim.x + threadIdx.x;
    if (i < E) {
        int pos = atomicAdd(&offs[dst[i]], 1);
        bucket[pos] = i;
    }
}

// ---------------------------------------------------------------------------
// Kernel B: he_b3 MFMA (verified R13-R17, verbatim). bf16 B3e partial into
// bytes 128..255 of each edge's 256B e_out slot.
// ---------------------------------------------------------------------------
__global__ void __launch_bounds__(256, 4)
he_b3_mfma(const float* __restrict__ e,
           const float* __restrict__ WB3, const float* __restrict__ bB3,
           unsigned short* __restrict__ he_u16, int E)
{
    __shared__ __align__(16) unsigned short Ebf[64 * 72];
    __shared__ __align__(16) unsigned short Wbf[64 * 72];

    const int t = threadIdx.x;
    const int lane = t & 63;
    const int wid = t >> 6;

    const int e0 = blockIdx.x << 6;
    const int nrow = min(64, E - e0);

    {
        const int r = t >> 2, s = t & 3;
        const float4* src = (const float4*)(WB3 + (size_t)r * 64 + s * 16);
        float4 v0 = src[0], v1 = src[1], v2 = src[2], v3 = src[3];
        *(uint4*)(&Wbf[r * 72 + s * 16]) = pack8(v0, v1);
        *(uint4*)(&Wbf[r * 72 + s * 16 + 8]) = pack8(v2, v3);
    }
    {
        const int r = t >> 2, s = t & 3;
        uint4 w0 = make_uint4(0, 0, 0, 0), w1 = make_uint4(0, 0, 0, 0);
        if (r < nrow) {
            const float4* src = (const float4*)(e + (size_t)(e0 + r) * 64 + s * 16);
            float4 v0 = src[0], v1 = src[1], v2 = src[2], v3 = src[3];
            w0 = pack8(v0, v1);
            w1 = pack8(v2, v3);
        }
        *(uint4*)(&Ebf[r * 72 + s * 16]) = w0;
        *(uint4*)(&Ebf[r * 72 + s * 16 + 8]) = w1;
    }
    __syncthreads();

    const int arow = (wid << 4) + (lane & 15);
    const int krun = (lane >> 4) << 3;
    short8 a0 = *(const short8*)(&Ebf[arow * 72 + krun]);
    short8 a1 = *(const short8*)(&Ebf[arow * 72 + krun + 32]);

    const int erow0 = e0 + (wid << 4) + ((lane >> 4) << 2);

#pragma unroll
    for (int dt = 0; dt < 4; ++dt) {
        const int d0 = dt << 4;
        const int dcol = d0 + (lane & 15);
        short8 b0 = *(const short8*)(&Wbf[dcol * 72 + krun]);
        short8 b1 = *(const short8*)(&Wbf[dcol * 72 + krun + 32]);
        float bias = bB3[dcol];
        float4v acc = {bias, bias, bias, bias};
        acc = __builtin_amdgcn_mfma_f32_16x16x32_bf16(a0, b0, acc, 0, 0, 0);
        acc = __builtin_amdgcn_mfma_f32_16x16x32_bf16(a1, b1, acc, 0, 0, 0);
#pragma unroll
        for (int r = 0; r < 4; ++r) {
            int er = erow0 + r;
            if (er < E)
                he_u16[(size_t)er * 128 + 64 + dcol] = (unsigned short)f2bf_bits(acc[r]);
        }
    }
}

// ---------------------------------------------------------------------------
// Kernel C: MERGED edge finish + gather + finalize (verified R10-R17).
// Change vs R17: NONTEMPORAL stores for all streaming outputs (e_out relu,
// h_out, p_out) and nontemporal loads for read-once streams (he16, C1p).
// Rationale: EGF's 225MB of streaming writes were evicting the P13/P2u/he16
// working set from L2/L3 (~140MB of re-fetch in FETCH_SIZE). Gather tables
// stay default-cached.
// ---------------------------------------------------------------------------
__global__ void __launch_bounds__(256, 8)
edge_gather_finalize(const int* __restrict__ bucket, const int* __restrict__ offs_end,
                     const int* __restrict__ cnt, const int* __restrict__ src,
                     const uint2* __restrict__ P13, const unsigned int* __restrict__ P2u,
                     const float* __restrict__ ln_g, const float* __restrict__ ln_b,
                     float* __restrict__ he_eout, float* __restrict__ h_out,
                     float* __restrict__ p_out, int N)
{
    const unsigned short* he16 = (const unsigned short*)he_eout;
    const int lane = threadIdx.x & 63;
    const int wid = threadIdx.x >> 6;
    const int wpb = blockDim.x >> 6;
    const float lg = ln_g[lane], lb = ln_b[lane];

    for (int n = blockIdx.x * wpb + wid; n < N; n += gridDim.x * wpb) {
        const int end = offs_end[n];
        const int deg = cnt[n];
        const int start = end - deg;
        const size_t o = (size_t)n * D + lane;

        const unsigned int p2n = P2u[o];   // bf16 {B2h, sigmaK}, per-node hoist
        const float b2n = bf_lo(p2n);
        const float skn = bf_hi(p2n);

        float asig = 0.f, av = 0.f, ap = 0.f;

        int k = start;
        for (; k + 3 < end; k += 4) {
            int eid[4], s[4];
#pragma unroll
            for (int i = 0; i < 4; ++i)
                eid[i] = __builtin_amdgcn_readfirstlane(bucket[k + i]);
#pragma unroll
            for (int i = 0; i < 4; ++i)
                s[i] = __builtin_amdgcn_readfirstlane(src[eid[i]]);

            uint2 q[4]; float hb[4];
#pragma unroll
            for (int i = 0; i < 4; ++i) {
                q[i]  = P13[(size_t)s[i] * D + lane];   // {p1, p3}
                hb[i] = bf_u16(__builtin_nontemporal_load(
                            &he16[(size_t)eid[i] * 128 + 64 + lane]));
            }

            float sg[4], pr[4];
#pragma unroll
            for (int i = 0; i < 4; ++i) {
                float he = hb[i] + bf_lo(q[i].x) + b2n;
                __builtin_nontemporal_store(fmaxf(he, 0.f),
                                            &he_eout[(size_t)eid[i] * D + lane]);
                sg[i] = 1.f / (1.f + expf(-he));
                pr[i] = bf_hi(q[i].x) * skn;
            }
#pragma unroll
            for (int off = 32; off > 0; off >>= 1) {
#pragma unroll
                for (int i = 0; i < 4; ++i) pr[i] += __shfl_xor(pr[i], off);
            }
#pragma unroll
            for (int i = 0; i < 4; ++i) {
                asig += sg[i];
                av   += sg[i] * pr[i] * bf_lo(q[i].y);
                ap   += sg[i] * bf_hi(q[i].y);
            }
        }
        for (; k < end; ++k) {
            int e0 = __builtin_amdgcn_readfirstlane(bucket[k]);
            int s0 = __builtin_amdgcn_readfirstlane(src[e0]);
            size_t eo0 = (size_t)e0 * D + lane;
            uint2 q0 = P13[(size_t)s0 * D + lane];
            float hb0 = bf_u16(__builtin_nontemporal_load(
                            &he16[(size_t)e0 * 128 + 64 + lane]));
            float he0 = hb0 + bf_lo(q0.x) + b2n;
            __builtin_nontemporal_store(fmaxf(he0, 0.f), &he_eout[eo0]);
            float sg0 = 1.f / (1.f + expf(-he0));
            float pr0 = bf_hi(q0.x) * skn;
#pragma unroll
            for (int off = 32; off > 0; off >>= 1) pr0 += __shfl_xor(pr0, off);
            asig += sg0;
            av   += sg0 * pr0 * bf_lo(q0.y);
            ap   += sg0 * bf_hi(q0.y);
        }

        // fused epilogue (verified R9-R17)
        float denom = asig + EPS;
        float vh = bf_lo(P13[o].y);
        float hv = vh + av / denom;
        hv = fmaxf(hv, 0.f);
        float su = hv;
#pragma unroll
        for (int off = 32; off > 0; off >>= 1) su += __shfl_xor(su, off);
        float mu = su * (1.f / 64.f);
        float dv = hv - mu;
        float s2 = dv * dv;
#pragma unroll
        for (int off = 32; off > 0; off >>= 1) s2 += __shfl_xor(s2, off);
        float var = s2 * (1.f / 64.f);
        __builtin_nontemporal_store(dv * rsqrtf(var + LN_EPS) * lg + lb, &h_out[o]);

        float c1 = __builtin_nontemporal_load(&p_out[o]);   // p_out holds C1p
        float pv = c1 + ap / denom;
        __builtin_nontemporal_store(tanhf(pv), &p_out[o]);
    }
}

extern "C" void kernel_launch(void* const* d_in, const int* in_sizes, int n_in,
                              void* d_out, int out_size, void* d_ws, size_t ws_size,
                              hipStream_t stream) {
    const float* h    = (const float*)d_in[0];
    const float* e    = (const float*)d_in[1];
    const float* p    = (const float*)d_in[2];
    const float* WK   = (const float*)d_in[3];
    const float* bK   = (const float*)d_in[4];
    const float* WV   = (const float*)d_in[5];
    const float* bV   = (const float*)d_in[6];
    const float* WB1  = (const float*)d_in[7];
    const float* bB1  = (const float*)d_in[8];
    const float* WB2  = (const float*)d_in[9];
    const float* bB2  = (const float*)d_in[10];
    const float* WB3  = (const float*)d_in[11];
    const float* bB3  = (const float*)d_in[12];
    const float* WC1  = (const float*)d_in[13];
    const float* bC1  = (const float*)d_in[14];
    const float* WC2  = (const float*)d_in[15];
    const float* bC2  = (const float*)d_in[16];
    const float* ln_g = (const float*)d_in[17];
    const float* ln_b = (const float*)d_in[18];
    const int*   src  = (const int*)d_in[19];
    const int*   dst  = (const int*)d_in[20];

    const int N = in_sizes[0] / D;
    const int E = in_sizes[1] / D;
    const size_t ND = (size_t)N * D;

    float* out   = (float*)d_out;
    float* h_out = out;
    float* e_out = out + ND;                  // bf16 B3e in slot upper halves, then f32 relu(he)
    float* p_out = out + ND + (size_t)E * D;  // C1p, then tanh(...)

    // ws: P13 ND uint2 + P2u ND u32 + cnt N + offs N + bucket E + csum  ~= 42 MB
    float*        ws    = (float*)d_ws;
    uint2*        P13   = (uint2*)(ws);                 // 2*ND u32
    unsigned int* P2u   = (unsigned int*)(ws + 2 * ND); // ND u32
    int*          cnt   = (int*)(ws + 3 * ND);          // N ints
    int*          offs  = cnt + N;                      // N ints
    int*          bucket= offs + N;                     // E ints
    int*          csum  = bucket + E;                   // nchunk ints (<=256)

    const int nchunk = (N + 255) / 256;

    hipMemsetAsync(cnt, 0, (size_t)N * sizeof(int), stream);

    node_linears_mfma<<<(N + 63) / 64, 256, 0, stream>>>(
        h, p, WK, bK, WV, bV, WB1, bB1, WB2, bB2, WC1, bC1, WC2, bC2,
        P13, P2u, p_out, N);

    hist_kernel<<<(E + 255) / 256, 256, 0, stream>>>(dst, cnt, E);
    chunksum_kernel<<<nchunk, 256, 0, stream>>>(cnt, csum, N);
    scanchunk_kernel<<<1, 256, 0, stream>>>(csum, nchunk);
    offsets_kernel<<<nchunk, 256, 0, stream>>>(cnt, csum, offs, N);
    scatter_kernel<<<(E + 255) / 256, 256, 0, stream>>>(dst, offs, bucket, E);

    he_b3_mfma<<<(E + 63) / 64, 256, 0, stream>>>(
        e, WB3, bB3, (unsigned short*)e_out, E);

    edge_gather_finalize<<<(N + 3) / 4, 256, 0, stream>>>(
        bucket, offs, cnt, src, P13, P2u, ln_g, ln_b,
        e_out, h_out, p_out, N);
}